// Round 5
// baseline (3701.949 us; speedup 1.0000x reference)
//
#include <hip/hip_runtime.h>
#include <math.h>

#define DD 512
#define SS 1024
#define BB 4
#define HH 8
#define DFF 2048
#define LL 4
#define NT 4096           // BB*SS
#define EPSF 1e-5f

// ---------------- workspace layout (float elements) ----------------
#define O_X0    ((size_t)0)            // 2,097,152  emb+pe
#define O_X1    ((size_t)2097152)      // 2,097,152  conv out / current x
#define O_HSEQ  ((size_t)4194304)      // (unused this version)
#define O_CTX   ((size_t)6293504)      // 2,097,152 (ctx)
#define O_QKV   ((size_t)8390656)      // 6,291,456
#define O_BIG   ((size_t)14682112)     // 16,777,216 (lstm gates 8.39M low half /
                                       //   h-pack u32 entries upper half / scores 16M / ffh 8M)
#define O_BSUM  ((size_t)31459328)     // 2048

typedef __attribute__((ext_vector_type(8))) _Float16 f16x8;
typedef __attribute__((ext_vector_type(4))) _Float16 f16x4;
typedef __attribute__((ext_vector_type(4))) float    f32x4;

// fast transcendentals: v_exp_f32 / v_rcp_f32 based (~1e-7 rel, saturating-safe)
__device__ __forceinline__ float fsig(float x){
  return __builtin_amdgcn_rcpf(1.0f + __expf(-x));
}
__device__ __forceinline__ float ftanh(float x){
  return 1.0f - 2.0f*__builtin_amdgcn_rcpf(1.0f + __expf(2.0f*x));
}
struct h2 { _Float16 hi, lo; };
__device__ __forceinline__ h2 split2(float v){
  h2 r; r.hi = (_Float16)v; r.lo = (_Float16)(v - (float)r.hi); return r;
}
union f16u { unsigned short u; _Float16 f; };
__device__ __forceinline__ float f16bits_to_f32(unsigned short b){
  f16u t; t.u = b; return (float)t.f;
}
__device__ __forceinline__ unsigned short f32_to_f16bits(float v){
  f16u t; t.f = (_Float16)v; return t.u;
}

// ---------------- embedding + sinusoidal PE ----------------
__global__ void k_embed(const int* __restrict__ src, const float* __restrict__ emb,
                        float* __restrict__ x){
  int idx = blockIdx.x*256 + threadIdx.x;
  if (idx >= NT*DD) return;
  int d = idx & (DD-1);
  int n = idx >> 9;          // b*SS + s
  int s = n & (SS-1);
  int tok = src[n];
  int i2 = d & ~1;
  float div = expf(-(float)i2 * (9.210340371976184f/512.0f));  // ln(10000)/512
  float ang = (float)s * div;
  float pe = (d & 1) ? cosf(ang) : sinf(ang);
  x[idx] = emb[(size_t)tok*DD + d]*22.62741699796952f + pe;    // sqrt(512)
}

// ---------------- depthwise conv k=3 + BN(eval) + ReLU ----------------
__global__ void k_conv(const float* __restrict__ x, const float* __restrict__ cw,
                       const float* __restrict__ cb, const float* __restrict__ bg,
                       const float* __restrict__ bb, const float* __restrict__ bm,
                       const float* __restrict__ bv, float* __restrict__ y){
  int idx = blockIdx.x*256 + threadIdx.x;
  if (idx >= NT*DD) return;
  int d = idx & (DD-1);
  int n = idx >> 9;
  int s = n & (SS-1);
  float acc = cb[d];
  if (s > 0)     acc += x[idx - DD]*cw[d*3+0];
  acc += x[idx]*cw[d*3+1];
  if (s < SS-1)  acc += x[idx + DD]*cw[d*3+2];
  float v = (acc - bm[d])*rsqrtf(bv[d]+EPSF)*bg[d] + bb[d];
  y[idx] = fmaxf(v, 0.0f);
}

__global__ void k_bsum(const float* a, const float* b, float* o, int n){
  int i = blockIdx.x*256 + threadIdx.x;
  if (i < n) o[i] = a[i] + b[i];
}

// ---------------- MFMA split-f16 GEMM: C[M,N] = A[M,K] @ W[N,K]^T + bias ----------------
#define BKP 40   // padded K stride in halves
template<int ACT>
__global__ __launch_bounds__(256) void k_gemm_mfma(const float* __restrict__ A,
                                                   const float* __restrict__ W,
                                                   const float* __restrict__ bias,
                                                   float* __restrict__ C,
                                                   int M, int N, int K){
  __shared__ _Float16 Ah[128][BKP];
  __shared__ _Float16 Al[128][BKP];
  __shared__ _Float16 Wh[128][BKP];
  __shared__ _Float16 Wl[128][BKP];
  const int tid = threadIdx.x;
  const int nbx = N >> 7;
  const int bx = blockIdx.x % nbx;
  const int by = blockIdx.x / nbx;
  const int m0 = by << 7, n0 = bx << 7;
  const int lane = tid & 63;
  const int wid  = tid >> 6;
  const int wr = wid >> 1, wc = wid & 1;
  const int fm = lane & 15, fg = lane >> 4;

  f32x4 acc[4][4];
  #pragma unroll
  for (int i=0;i<4;i++)
    #pragma unroll
    for (int j=0;j<4;j++) acc[i][j] = (f32x4){0.0f,0.0f,0.0f,0.0f};

  for (int k0 = 0; k0 < K; k0 += 32){
    #pragma unroll
    for (int e = 0; e < 4; ++e){
      int lin = e*256 + tid;
      int rr = lin >> 3;
      int k4 = (lin & 7) << 2;
      float4 av = *reinterpret_cast<const float4*>(A + (size_t)(m0+rr)*K + k0 + k4);
      float4 wv = *reinterpret_cast<const float4*>(W + (size_t)(n0+rr)*K + k0 + k4);
      f16x4 ahv, alv, whv, wlv;
      h2 t;
      t = split2(av.x); ahv[0]=t.hi; alv[0]=t.lo;
      t = split2(av.y); ahv[1]=t.hi; alv[1]=t.lo;
      t = split2(av.z); ahv[2]=t.hi; alv[2]=t.lo;
      t = split2(av.w); ahv[3]=t.hi; alv[3]=t.lo;
      *reinterpret_cast<f16x4*>(&Ah[rr][k4]) = ahv;
      *reinterpret_cast<f16x4*>(&Al[rr][k4]) = alv;
      t = split2(wv.x); whv[0]=t.hi; wlv[0]=t.lo;
      t = split2(wv.y); whv[1]=t.hi; wlv[1]=t.lo;
      t = split2(wv.z); whv[2]=t.hi; wlv[2]=t.lo;
      t = split2(wv.w); whv[3]=t.hi; wlv[3]=t.lo;
      *reinterpret_cast<f16x4*>(&Wh[rr][k4]) = whv;
      *reinterpret_cast<f16x4*>(&Wl[rr][k4]) = wlv;
    }
    __syncthreads();
    f16x8 a_h[4], a_l[4], w_h[4], w_l[4];
    #pragma unroll
    for (int i=0;i<4;i++){
      int row = wr*64 + i*16 + fm;
      a_h[i] = *reinterpret_cast<const f16x8*>(&Ah[row][fg*8]);
      a_l[i] = *reinterpret_cast<const f16x8*>(&Al[row][fg*8]);
    }
    #pragma unroll
    for (int j=0;j<4;j++){
      int row = wc*64 + j*16 + fm;
      w_h[j] = *reinterpret_cast<const f16x8*>(&Wh[row][fg*8]);
      w_l[j] = *reinterpret_cast<const f16x8*>(&Wl[row][fg*8]);
    }
    #pragma unroll
    for (int i=0;i<4;i++)
      #pragma unroll
      for (int j=0;j<4;j++){
        acc[i][j] = __builtin_amdgcn_mfma_f32_16x16x32_f16(a_h[i], w_h[j], acc[i][j], 0, 0, 0);
        acc[i][j] = __builtin_amdgcn_mfma_f32_16x16x32_f16(a_h[i], w_l[j], acc[i][j], 0, 0, 0);
        acc[i][j] = __builtin_amdgcn_mfma_f32_16x16x32_f16(a_l[i], w_h[j], acc[i][j], 0, 0, 0);
      }
    __syncthreads();
  }
  #pragma unroll
  for (int i=0;i<4;i++){
    #pragma unroll
    for (int r=0;r<4;r++){
      int row = m0 + wr*64 + i*16 + fg*4 + r;
      #pragma unroll
      for (int j=0;j<4;j++){
        int col = n0 + wc*64 + j*16 + fm;
        float v = acc[i][j][r] + bias[col];
        if (ACT == 1) v = 0.5f*v*(1.0f + erff(v*0.70710678118654752f));  // exact gelu
        C[(size_t)row*N + col] = v;
      }
    }
  }
}

// ---------------- MFMA attention scores: sc = (Q*scale) @ K^T (128x128 tiles) ----------------
#define SPAD 72
__global__ __launch_bounds__(256) void k_scores_mfma(const float* __restrict__ qkv,
                                                     float* __restrict__ sc, int bbase){
  __shared__ _Float16 Qh[128][SPAD], Ql[128][SPAD];
  __shared__ _Float16 Kh[128][SPAD], Kl[128][SPAD];
  const int tid = threadIdx.x;
  const int kt = blockIdx.x & 7;
  const int qt = (blockIdx.x >> 3) & 7;
  const int h  = (blockIdx.x >> 6) & 7;
  const int hb = (blockIdx.x >> 9) & 1;
  const int b  = bbase + hb;
  const int q0 = qt*128, k0 = kt*128;
  #pragma unroll
  for (int e=0;e<8;e++){
    int lin = e*256 + tid;
    int rr = lin >> 4;
    int c4 = (lin & 15) << 2;
    float4 qv = *reinterpret_cast<const float4*>(qkv + (size_t)(b*SS + q0+rr)*1536 + h*64 + c4);
    float4 kv = *reinterpret_cast<const float4*>(qkv + (size_t)(b*SS + k0+rr)*1536 + DD + h*64 + c4);
    qv.x *= 0.125f; qv.y *= 0.125f; qv.z *= 0.125f; qv.w *= 0.125f;
    f16x4 qh, ql, kh, kl;
    h2 t;
    t = split2(qv.x); qh[0]=t.hi; ql[0]=t.lo;
    t = split2(qv.y); qh[1]=t.hi; ql[1]=t.lo;
    t = split2(qv.z); qh[2]=t.hi; ql[2]=t.lo;
    t = split2(qv.w); qh[3]=t.hi; ql[3]=t.lo;
    t = split2(kv.x); kh[0]=t.hi; kl[0]=t.lo;
    t = split2(kv.y); kh[1]=t.hi; kl[1]=t.lo;
    t = split2(kv.z); kh[2]=t.hi; kl[2]=t.lo;
    t = split2(kv.w); kh[3]=t.hi; kl[3]=t.lo;
    *reinterpret_cast<f16x4*>(&Qh[rr][c4]) = qh;
    *reinterpret_cast<f16x4*>(&Ql[rr][c4]) = ql;
    *reinterpret_cast<f16x4*>(&Kh[rr][c4]) = kh;
    *reinterpret_cast<f16x4*>(&Kl[rr][c4]) = kl;
  }
  __syncthreads();
  const int lane = tid & 63, wid = tid >> 6;
  const int wr = wid >> 1, wc = wid & 1;
  const int fm = lane & 15, fg = lane >> 4;
  f32x4 acc[4][4];
  #pragma unroll
  for (int i=0;i<4;i++)
    #pragma unroll
    for (int j=0;j<4;j++) acc[i][j] = (f32x4){0.0f,0.0f,0.0f,0.0f};
  #pragma unroll
  for (int ks=0; ks<2; ks++){
    f16x8 ah[4], al[4], bh[4], bl[4];
    #pragma unroll
    for (int i=0;i<4;i++){
      int row = wr*64 + i*16 + fm;
      ah[i] = *reinterpret_cast<const f16x8*>(&Qh[row][ks*32 + fg*8]);
      al[i] = *reinterpret_cast<const f16x8*>(&Ql[row][ks*32 + fg*8]);
    }
    #pragma unroll
    for (int j=0;j<4;j++){
      int row = wc*64 + j*16 + fm;
      bh[j] = *reinterpret_cast<const f16x8*>(&Kh[row][ks*32 + fg*8]);
      bl[j] = *reinterpret_cast<const f16x8*>(&Kl[row][ks*32 + fg*8]);
    }
    #pragma unroll
    for (int i=0;i<4;i++)
      #pragma unroll
      for (int j=0;j<4;j++){
        acc[i][j] = __builtin_amdgcn_mfma_f32_16x16x32_f16(ah[i], bh[j], acc[i][j], 0, 0, 0);
        acc[i][j] = __builtin_amdgcn_mfma_f32_16x16x32_f16(ah[i], bl[j], acc[i][j], 0, 0, 0);
        acc[i][j] = __builtin_amdgcn_mfma_f32_16x16x32_f16(al[i], bh[j], acc[i][j], 0, 0, 0);
      }
  }
  float* out = sc + (size_t)(hb*HH + h)*SS*SS;
  #pragma unroll
  for (int i=0;i<4;i++){
    #pragma unroll
    for (int r=0;r<4;r++){
      int row = q0 + wr*64 + i*16 + fg*4 + r;
      #pragma unroll
      for (int j=0;j<4;j++){
        int col = k0 + wc*64 + j*16 + fm;
        out[(size_t)row*SS + col] = acc[i][j][r];
      }
    }
  }
}

// ---------------- MFMA PV: ctx[:, h*64..] = P @ V (128q x 64d tiles, BK=64) ----------------
__global__ __launch_bounds__(256) void k_pv_mfma(const float* __restrict__ sc,
                                                 const float* __restrict__ qkv,
                                                 float* __restrict__ ctx, int bbase){
  __shared__ _Float16 Ph[128][SPAD], Pl[128][SPAD];
  __shared__ _Float16 Vh[64][SPAD],  Vl[64][SPAD];
  const int tid = threadIdx.x;
  const int qt = blockIdx.x & 7;
  const int h  = (blockIdx.x >> 3) & 7;
  const int hb = (blockIdx.x >> 6) & 1;
  const int b  = bbase + hb;
  const int q0 = qt*128;
  const float* P = sc + (size_t)(hb*HH + h)*SS*SS;
  const int lane = tid & 63, wid = tid >> 6;
  const int wr = wid >> 1, wc = wid & 1;      // wave tile: 64 rows x 32 cols
  const int fm = lane & 15, fg = lane >> 4;
  f32x4 acc[4][2];
  #pragma unroll
  for (int i=0;i<4;i++){ acc[i][0] = (f32x4){0,0,0,0}; acc[i][1] = (f32x4){0,0,0,0}; }

  for (int kk0=0; kk0<SS; kk0+=64){
    #pragma unroll
    for (int e=0;e<8;e++){
      int lin = e*256 + tid;
      int rr = lin >> 4;
      int c4 = (lin & 15) << 2;
      float4 pv = *reinterpret_cast<const float4*>(P + (size_t)(q0+rr)*SS + kk0 + c4);
      f16x4 ph, pl;
      h2 t;
      t = split2(pv.x); ph[0]=t.hi; pl[0]=t.lo;
      t = split2(pv.y); ph[1]=t.hi; pl[1]=t.lo;
      t = split2(pv.z); ph[2]=t.hi; pl[2]=t.lo;
      t = split2(pv.w); ph[3]=t.hi; pl[3]=t.lo;
      *reinterpret_cast<f16x4*>(&Ph[rr][c4]) = ph;
      *reinterpret_cast<f16x4*>(&Pl[rr][c4]) = pl;
    }
    // stage V transposed: Vh[d][k] = V[kk0+k][d]
    #pragma unroll
    for (int e=0;e<16;e++){
      int lin = e*256 + tid;
      int d = lin & 63;
      int k = lin >> 6;
      float v = qkv[(size_t)(b*SS + kk0+k)*1536 + 1024 + h*64 + d];
      _Float16 hi = (_Float16)v;
      Vh[d][k] = hi;
      Vl[d][k] = (_Float16)(v - (float)hi);
    }
    __syncthreads();
    #pragma unroll
    for (int ks=0; ks<2; ks++){
      f16x8 ah[4], al[4], bh[2], bl[2];
      #pragma unroll
      for (int i=0;i<4;i++){
        int row = wr*64 + i*16 + fm;
        ah[i] = *reinterpret_cast<const f16x8*>(&Ph[row][ks*32 + fg*8]);
        al[i] = *reinterpret_cast<const f16x8*>(&Pl[row][ks*32 + fg*8]);
      }
      #pragma unroll
      for (int j=0;j<2;j++){
        int row = wc*32 + j*16 + fm;
        bh[j] = *reinterpret_cast<const f16x8*>(&Vh[row][ks*32 + fg*8]);
        bl[j] = *reinterpret_cast<const f16x8*>(&Vl[row][ks*32 + fg*8]);
      }
      #pragma unroll
      for (int i=0;i<4;i++)
        #pragma unroll
        for (int j=0;j<2;j++){
          acc[i][j] = __builtin_amdgcn_mfma_f32_16x16x32_f16(ah[i], bh[j], acc[i][j], 0, 0, 0);
          acc[i][j] = __builtin_amdgcn_mfma_f32_16x16x32_f16(ah[i], bl[j], acc[i][j], 0, 0, 0);
          acc[i][j] = __builtin_amdgcn_mfma_f32_16x16x32_f16(al[i], bh[j], acc[i][j], 0, 0, 0);
        }
    }
    __syncthreads();
  }
  #pragma unroll
  for (int i=0;i<4;i++){
    #pragma unroll
    for (int r=0;r<4;r++){
      int row = q0 + wr*64 + i*16 + fg*4 + r;
      #pragma unroll
      for (int j=0;j<2;j++){
        int col = wc*32 + j*16 + fm;
        ctx[(size_t)(b*SS + row)*DD + h*64 + col] = acc[i][j][r];
      }
    }
  }
}

// ---------------- persistent LSTM: 256 blocks = 4 batches x 64 chunks(8 dims) ----------------
// Dataflow sync via self-tagged 32-bit entries {f16(h)<<16 | tag16}, stored with
// relaxed agent-scope atomics. Reader: ONE 64-bit atomic load per thread covers
// its 2 dims (each 32-bit half self-validating -> tearing harmless). Poll is
// 3-deep pipelined (3 same-address loads in flight; consume the oldest) with no
// s_sleep -> sampling period ~ latency/3. gemv reads staged h via ds_read_b128
// from a ks-major padded layout hsh[8][68] (8 ks-groups hit disjoint 4-bank
// chunks -> conflict-free).
__global__ __launch_bounds__(256) void k_lstm(const float* __restrict__ gates_in,
                                              const float* __restrict__ w_hh,
                                              unsigned int* __restrict__ hpk){
  __shared__ float hsh[8][68];
  __shared__ float gl[32];
  const int b = blockIdx.x >> 6;
  const int chunk = blockIdx.x & 63;
  const int d0 = chunk*8;
  const int tid = threadIdx.x;
  const int r = tid >> 3;        // 0..31 : local row = gate*8 + di
  const int ks = tid & 7;        // interleaved k-slice
  const int gate = r >> 3;
  const int di = r & 7;
  float w[64];
  {
    const float* wrow = w_hh + (size_t)(gate*DD + d0 + di)*DD;
    #pragma unroll
    for (int j=0;j<64;j++) w[j] = wrow[j*8 + ks];
  }
  float c = 0.0f;
  const float* gbase = gates_in + (size_t)(b*SS)*(4*DD) + gate*DD + d0 + di;
  for (int t=0; t<SS; ++t){
    float gv = 0.0f;
    if (ks == 0) gv = gbase[(size_t)t*(4*DD)];
    // poll: one 64-bit load covering dims {2*tid, 2*tid+1}
    const unsigned long long* hp =
      (const unsigned long long*)(hpk + (size_t)(t*BB + b)*DD) + tid;
    const unsigned int tg = (unsigned int)t & 0xffffu;
    unsigned long long p = __hip_atomic_load(hp, __ATOMIC_RELAXED, __HIP_MEMORY_SCOPE_AGENT);
    if ((((unsigned int)p & 0xffffu) != tg) || (((unsigned int)(p>>32) & 0xffffu) != tg)){
      unsigned long long q1 = __hip_atomic_load(hp, __ATOMIC_RELAXED, __HIP_MEMORY_SCOPE_AGENT);
      unsigned long long q2 = __hip_atomic_load(hp, __ATOMIC_RELAXED, __HIP_MEMORY_SCOPE_AGENT);
      while ((((unsigned int)p & 0xffffu) != tg) || (((unsigned int)(p>>32) & 0xffffu) != tg)){
        p = q1; q1 = q2;
        q2 = __hip_atomic_load(hp, __ATOMIC_RELAXED, __HIP_MEMORY_SCOPE_AGENT);
      }
    }
    {
      unsigned int e0 = (unsigned int)p, e1 = (unsigned int)(p >> 32);
      int dd = tid*2;
      int kr = dd & 7, jj = dd >> 3;     // kr even, pair goes to rows kr, kr+1
      hsh[kr][jj]   = f16bits_to_f32((unsigned short)(e0 >> 16));
      hsh[kr+1][jj] = f16bits_to_f32((unsigned short)(e1 >> 16));
    }
    __syncthreads();
    float a0=0.0f, a1=0.0f, a2=0.0f, a3=0.0f;
    #pragma unroll
    for (int j=0;j<64;j+=4){
      float4 hv = *reinterpret_cast<const float4*>(&hsh[ks][j]);
      a0 += w[j+0]*hv.x;
      a1 += w[j+1]*hv.y;
      a2 += w[j+2]*hv.z;
      a3 += w[j+3]*hv.w;
    }
    float acc = (a0+a1)+(a2+a3);
    acc += __shfl_down(acc, 4, 8);
    acc += __shfl_down(acc, 2, 8);
    acc += __shfl_down(acc, 1, 8);
    if (ks == 0){
      float v = acc + gv;
      gl[r] = (gate == 2) ? ftanh(v) : fsig(v);   // pre-activated gate
    }
    __syncthreads();
    if (tid < 8){
      float gi = gl[tid];
      float gf = gl[8 + tid];
      float gg = gl[16 + tid];
      float go = gl[24 + tid];
      c = gf*c + gi*gg;
      float h = go*ftanh(c);
      unsigned int entry = ((unsigned int)f32_to_f16bits(h) << 16)
                         | ((unsigned int)(t+1) & 0xffffu);
      unsigned int partner = __shfl_down(entry, 1);
      if ((tid & 1) == 0){
        unsigned long long pk = ((unsigned long long)partner << 32) | (unsigned long long)entry;
        __hip_atomic_store(
          (unsigned long long*)(hpk + (size_t)((t+1)*BB + b)*DD + d0) + (tid >> 1),
          pk, __ATOMIC_RELAXED, __HIP_MEMORY_SCOPE_AGENT);
      }
    }
  }
}

__global__ void k_resid(float* __restrict__ x, const unsigned int* __restrict__ hpk){
  int idx = blockIdx.x*256 + threadIdx.x;
  if (idx >= NT*DD) return;
  int d = idx & (DD-1);
  int n = idx >> 9;
  int s = n & (SS-1);
  int b = n >> 10;
  unsigned int e = hpk[(size_t)((s+1)*BB + b)*DD + d];
  x[idx] += f16bits_to_f32((unsigned short)(e >> 16));
}

__device__ __forceinline__ float blockReduce(float v, float* red, int tid, int isMax){
  #pragma unroll
  for (int o=32;o>0;o>>=1){
    float t = __shfl_xor(v, o);
    v = isMax ? fmaxf(v, t) : v + t;
  }
  if ((tid & 63) == 0) red[tid >> 6] = v;
  __syncthreads();
  float r = red[0];
  #pragma unroll
  for (int i=1;i<4;i++) r = isMax ? fmaxf(r, red[i]) : r + red[i];
  __syncthreads();
  return r;
}

// softmax rows in place + accumulate head-average into d_out attn region
__global__ __launch_bounds__(256) void k_softmax(float* __restrict__ sc,
                                                 float* __restrict__ attn_out,
                                                 int l, int bbase){
  __shared__ float avg[SS];
  __shared__ float red[8];
  const int tid = threadIdx.x;
  const int q  = blockIdx.x & (SS-1);
  const int hb = blockIdx.x >> 10;
  const int b = bbase + hb;
  for (int j=tid;j<SS;j+=256) avg[j] = 0.0f;
  __syncthreads();
  for (int h=0;h<HH;h++){
    float* row = sc + (size_t)(hb*HH + h)*SS*SS + (size_t)q*SS;
    float v[4];
    float m = -1e30f;
    #pragma unroll
    for (int j=0;j<4;j++){ v[j] = row[tid + j*256]; m = fmaxf(m, v[j]); }
    m = blockReduce(m, red, tid, 1);
    float s = 0.0f;
    #pragma unroll
    for (int j=0;j<4;j++){ v[j] = __expf(v[j] - m); s += v[j]; }
    s = blockReduce(s, red, tid, 0);
    float inv = __builtin_amdgcn_rcpf(s);
    #pragma unroll
    for (int j=0;j<4;j++){
      float p = v[j]*inv;
      row[tid + j*256] = p;
      avg[tid + j*256] += p;
    }
    __syncthreads();
  }
  float* ao = attn_out + (size_t)((l*BB + b)*SS + q)*SS;
  for (int j=tid;j<SS;j+=256) ao[j] = avg[j]*0.125f;
}

// ---------------- LayerNorm: out = LN(x (+ y)) * g + b ----------------
__global__ __launch_bounds__(64) void k_ln(const float* __restrict__ x,
                                           const float* __restrict__ y,
                                           const float* __restrict__ g,
                                           const float* __restrict__ bta,
                                           float* __restrict__ out){
  const int n = blockIdx.x;
  const int tid = threadIdx.x;
  float v[8];
  float s = 0.0f, sq = 0.0f;
  #pragma unroll
  for (int j=0;j<8;j++){
    int d = j*64 + tid;
    float a = x[(size_t)n*DD + d];
    if (y) a += y[(size_t)n*DD + d];
    v[j] = a; s += a; sq += a*a;
  }
  #pragma unroll
  for (int o=32;o>0;o>>=1){ s += __shfl_xor(s, o); sq += __shfl_xor(sq, o); }
  float mean = s*(1.0f/DD);
  float var = sq*(1.0f/DD) - mean*mean;
  float rstd = rsqrtf(var + EPSF);
  #pragma unroll
  for (int j=0;j<8;j++){
    int d = j*64 + tid;
    out[(size_t)n*DD + d] = (v[j]-mean)*rstd*g[d] + bta[d];
  }
}

extern "C" void kernel_launch(void* const* d_in, const int* in_sizes, int n_in,
                              void* d_out, int out_size, void* d_ws, size_t ws_size,
                              hipStream_t stream){
  const int*   src    = (const int*)  d_in[0];
  const float* emb    = (const float*)d_in[1];
  const float* conv_w = (const float*)d_in[2];
  const float* conv_b = (const float*)d_in[3];
  const float* bn_g   = (const float*)d_in[4];
  const float* bn_b   = (const float*)d_in[5];
  const float* bn_m   = (const float*)d_in[6];
  const float* bn_v   = (const float*)d_in[7];
  const float* w_ih   = (const float*)d_in[8];
  const float* w_hh   = (const float*)d_in[9];
  const float* b_ih   = (const float*)d_in[10];
  const float* b_hh   = (const float*)d_in[11];
  const float* in_w   = (const float*)d_in[12];
  const float* in_b   = (const float*)d_in[13];
  const float* out_w  = (const float*)d_in[14];
  const float* out_b  = (const float*)d_in[15];
  const float* ln1_g  = (const float*)d_in[16];
  const float* ln1_b  = (const float*)d_in[17];
  const float* w1     = (const float*)d_in[18];
  const float* b1     = (const float*)d_in[19];
  const float* w2     = (const float*)d_in[20];
  const float* b2     = (const float*)d_in[21];
  const float* ln2_g  = (const float*)d_in[22];
  const float* ln2_b  = (const float*)d_in[23];
  const float* fin_g  = (const float*)d_in[24];
  const float* fin_b  = (const float*)d_in[25];

  float* ws    = (float*)d_ws;
  float* x0    = ws + O_X0;
  float* x1    = ws + O_X1;
  float* ctx   = ws + O_CTX;
  float* qkv   = ws + O_QKV;
  float* big   = ws + O_BIG;     // gates (low 8.39M) / scores / ffh
  float* bsum  = ws + O_BSUM;
  // self-tagged u32 h-entries in the upper half of BIG (gates use the low
  // 8,388,608 floats; scores reuse full BIG only after k_resid consumed h).
  unsigned int* hpk = (unsigned int*)(big + 8388608);

  float* outx  = (float*)d_out;            // [B,S,D]
  float* attn  = outx + (size_t)NT*DD;     // [L,B,S,S]

  // zero tags (+ h(0)=0): tag 0 == expected tag at t=0
  hipMemsetAsync(hpk, 0, (size_t)(SS+1)*BB*DD*sizeof(unsigned int), stream);

  const int eb = (NT*DD)/256;
  k_embed<<<eb, 256, 0, stream>>>(src, emb, x0);
  k_conv <<<eb, 256, 0, stream>>>(x0, conv_w, conv_b, bn_g, bn_b, bn_m, bn_v, x1);
  k_bsum <<<8, 256, 0, stream>>>(b_ih, b_hh, bsum, 4*DD);

  // LSTM input precompute: gates = x1 @ w_ih^T + (b_ih + b_hh)
  k_gemm_mfma<0><<<(NT/128)*((4*DD)/128), 256, 0, stream>>>(
      x1, w_ih, bsum, big, NT, 4*DD, DD);
  k_lstm<<<256, 256, 0, stream>>>(big, w_hh, hpk);
  k_resid<<<eb, 256, 0, stream>>>(x1, hpk);

  float* cur = x1;
  float* tmp = x0;
  for (int l=0; l<LL; ++l){
    // qkv = cur @ in_w[l]^T + in_b[l]
    k_gemm_mfma<0><<<(NT/128)*(1536/128), 256, 0, stream>>>(
        cur, in_w + (size_t)l*1536*DD, in_b + (size_t)l*1536, qkv, NT, 1536, DD);
    for (int bb2=0; bb2<2; ++bb2){
      int bbase = bb2*2;
      k_scores_mfma<<<1024, 256, 0, stream>>>(qkv, big, bbase);
      k_softmax    <<<2048, 256, 0, stream>>>(big, attn, l, bbase);
      k_pv_mfma    <<<128,  256, 0, stream>>>(big, qkv, ctx, bbase);
    }
    // proj: tmp = ctx @ out_w[l]^T + out_b[l]
    k_gemm_mfma<0><<<(NT/128)*(DD/128), 256, 0, stream>>>(
        ctx, out_w + (size_t)l*DD*DD, out_b + (size_t)l*DD, tmp, NT, DD, DD);
    k_ln<<<NT, 64, 0, stream>>>(cur, tmp, ln1_g + l*DD, ln1_b + l*DD, cur);
    // ffh = gelu(cur @ w1[l]^T + b1[l])
    k_gemm_mfma<1><<<(NT/128)*(DFF/128), 256, 0, stream>>>(
        cur, w1 + (size_t)l*DFF*DD, b1 + (size_t)l*DFF, big, NT, DFF, DD);
    // tmp = ffh @ w2[l]^T + b2[l]
    k_gemm_mfma<0><<<(NT/128)*(DD/128), 256, 0, stream>>>(
        big, w2 + (size_t)l*DD*DFF, b2 + (size_t)l*DD, tmp, NT, DD, DFF);
    k_ln<<<NT, 64, 0, stream>>>(cur, tmp, ln2_g + l*DD, ln2_b + l*DD, cur);
  }
  k_ln<<<NT, 64, 0, stream>>>(cur, nullptr, fin_g, fin_b, outx);
}

// Round 6
// 3288.355 us; speedup vs baseline: 1.1258x; 1.1258x over previous
//
#include <hip/hip_runtime.h>
#include <math.h>

#define DD 512
#define SS 1024
#define BB 4
#define HH 8
#define DFF 2048
#define LL 4
#define NT 4096           // BB*SS
#define EPSF 1e-5f

// ---------------- workspace layout (float elements) ----------------
#define O_X0    ((size_t)0)            // 2,097,152  emb+pe
#define O_X1    ((size_t)2097152)      // 2,097,152  conv out / current x
#define O_HSEQ  ((size_t)4194304)      // (unused this version)
#define O_CTX   ((size_t)6293504)      // 2,097,152 (ctx)
#define O_QKV   ((size_t)8390656)      // 6,291,456
#define O_BIG   ((size_t)14682112)     // 16,777,216 (lstm gates 8.39M low half /
                                       //   h-pack pairs upper half / scores 16M / ffh 8M)
#define O_BSUM  ((size_t)31459328)     // 2048

typedef __attribute__((ext_vector_type(8))) _Float16 f16x8;
typedef __attribute__((ext_vector_type(4))) _Float16 f16x4;
typedef __attribute__((ext_vector_type(4))) float    f32x4;

// fast transcendentals: v_exp_f32 / v_rcp_f32 based (~1e-7 rel, saturating-safe)
__device__ __forceinline__ float fsig(float x){
  return __builtin_amdgcn_rcpf(1.0f + __expf(-x));
}
__device__ __forceinline__ float ftanh(float x){
  return 1.0f - 2.0f*__builtin_amdgcn_rcpf(1.0f + __expf(2.0f*x));
}
struct h2 { _Float16 hi, lo; };
__device__ __forceinline__ h2 split2(float v){
  h2 r; r.hi = (_Float16)v; r.lo = (_Float16)(v - (float)r.hi); return r;
}

// ---------------- embedding + sinusoidal PE ----------------
__global__ void k_embed(const int* __restrict__ src, const float* __restrict__ emb,
                        float* __restrict__ x){
  int idx = blockIdx.x*256 + threadIdx.x;
  if (idx >= NT*DD) return;
  int d = idx & (DD-1);
  int n = idx >> 9;          // b*SS + s
  int s = n & (SS-1);
  int tok = src[n];
  int i2 = d & ~1;
  float div = expf(-(float)i2 * (9.210340371976184f/512.0f));  // ln(10000)/512
  float ang = (float)s * div;
  float pe = (d & 1) ? cosf(ang) : sinf(ang);
  x[idx] = emb[(size_t)tok*DD + d]*22.62741699796952f + pe;    // sqrt(512)
}

// ---------------- depthwise conv k=3 + BN(eval) + ReLU ----------------
__global__ void k_conv(const float* __restrict__ x, const float* __restrict__ cw,
                       const float* __restrict__ cb, const float* __restrict__ bg,
                       const float* __restrict__ bb, const float* __restrict__ bm,
                       const float* __restrict__ bv, float* __restrict__ y){
  int idx = blockIdx.x*256 + threadIdx.x;
  if (idx >= NT*DD) return;
  int d = idx & (DD-1);
  int n = idx >> 9;
  int s = n & (SS-1);
  float acc = cb[d];
  if (s > 0)     acc += x[idx - DD]*cw[d*3+0];
  acc += x[idx]*cw[d*3+1];
  if (s < SS-1)  acc += x[idx + DD]*cw[d*3+2];
  float v = (acc - bm[d])*rsqrtf(bv[d]+EPSF)*bg[d] + bb[d];
  y[idx] = fmaxf(v, 0.0f);
}

__global__ void k_bsum(const float* a, const float* b, float* o, int n){
  int i = blockIdx.x*256 + threadIdx.x;
  if (i < n) o[i] = a[i] + b[i];
}

// ---------------- MFMA split-f16 GEMM: C[M,N] = A[M,K] @ W[N,K]^T + bias ----------------
// Register-prefetch pipelined: tile k+1's global loads issue right after the
// staging barrier, hiding HBM latency under the MFMA block.
#define BKP 40   // padded K stride in halves
template<int ACT>
__global__ __launch_bounds__(256) void k_gemm_mfma(const float* __restrict__ A,
                                                   const float* __restrict__ W,
                                                   const float* __restrict__ bias,
                                                   float* __restrict__ C,
                                                   int M, int N, int K){
  __shared__ _Float16 Ah[128][BKP];
  __shared__ _Float16 Al[128][BKP];
  __shared__ _Float16 Wh[128][BKP];
  __shared__ _Float16 Wl[128][BKP];
  const int tid = threadIdx.x;
  const int nbx = N >> 7;
  const int bx = blockIdx.x % nbx;
  const int by = blockIdx.x / nbx;
  const int m0 = by << 7, n0 = bx << 7;
  const int lane = tid & 63;
  const int wid  = tid >> 6;
  const int wr = wid >> 1, wc = wid & 1;
  const int fm = lane & 15, fg = lane >> 4;
  const int r0 = tid >> 3;              // staging row base (row = r0 + 32e)
  const int k4 = (tid & 7) << 2;        // staging k offset within tile
  const float* Abase = A + (size_t)(m0 + r0)*K + k4;
  const float* Wbase = W + (size_t)(n0 + r0)*K + k4;

  f32x4 acc[4][4];
  #pragma unroll
  for (int i=0;i<4;i++)
    #pragma unroll
    for (int j=0;j<4;j++) acc[i][j] = (f32x4){0.0f,0.0f,0.0f,0.0f};

  float4 ra[4], rw[4];
  #pragma unroll
  for (int e=0;e<4;e++){
    ra[e] = *reinterpret_cast<const float4*>(Abase + (size_t)(e*32)*K);
    rw[e] = *reinterpret_cast<const float4*>(Wbase + (size_t)(e*32)*K);
  }

  for (int k0 = 0; k0 < K; k0 += 32){
    #pragma unroll
    for (int e = 0; e < 4; ++e){
      int rr = r0 + e*32;
      f16x4 ahv, alv, whv, wlv;
      h2 t;
      t = split2(ra[e].x); ahv[0]=t.hi; alv[0]=t.lo;
      t = split2(ra[e].y); ahv[1]=t.hi; alv[1]=t.lo;
      t = split2(ra[e].z); ahv[2]=t.hi; alv[2]=t.lo;
      t = split2(ra[e].w); ahv[3]=t.hi; alv[3]=t.lo;
      *reinterpret_cast<f16x4*>(&Ah[rr][k4]) = ahv;
      *reinterpret_cast<f16x4*>(&Al[rr][k4]) = alv;
      t = split2(rw[e].x); whv[0]=t.hi; wlv[0]=t.lo;
      t = split2(rw[e].y); whv[1]=t.hi; wlv[1]=t.lo;
      t = split2(rw[e].z); whv[2]=t.hi; wlv[2]=t.lo;
      t = split2(rw[e].w); whv[3]=t.hi; wlv[3]=t.lo;
      *reinterpret_cast<f16x4*>(&Wh[rr][k4]) = whv;
      *reinterpret_cast<f16x4*>(&Wl[rr][k4]) = wlv;
    }
    __syncthreads();
    if (k0 + 32 < K){
      #pragma unroll
      for (int e=0;e<4;e++){
        ra[e] = *reinterpret_cast<const float4*>(Abase + (size_t)(e*32)*K + k0 + 32);
        rw[e] = *reinterpret_cast<const float4*>(Wbase + (size_t)(e*32)*K + k0 + 32);
      }
    }
    f16x8 a_h[4], a_l[4], w_h[4], w_l[4];
    #pragma unroll
    for (int i=0;i<4;i++){
      int row = wr*64 + i*16 + fm;
      a_h[i] = *reinterpret_cast<const f16x8*>(&Ah[row][fg*8]);
      a_l[i] = *reinterpret_cast<const f16x8*>(&Al[row][fg*8]);
    }
    #pragma unroll
    for (int j=0;j<4;j++){
      int row = wc*64 + j*16 + fm;
      w_h[j] = *reinterpret_cast<const f16x8*>(&Wh[row][fg*8]);
      w_l[j] = *reinterpret_cast<const f16x8*>(&Wl[row][fg*8]);
    }
    #pragma unroll
    for (int i=0;i<4;i++)
      #pragma unroll
      for (int j=0;j<4;j++){
        acc[i][j] = __builtin_amdgcn_mfma_f32_16x16x32_f16(a_h[i], w_h[j], acc[i][j], 0, 0, 0);
        acc[i][j] = __builtin_amdgcn_mfma_f32_16x16x32_f16(a_h[i], w_l[j], acc[i][j], 0, 0, 0);
        acc[i][j] = __builtin_amdgcn_mfma_f32_16x16x32_f16(a_l[i], w_h[j], acc[i][j], 0, 0, 0);
      }
    __syncthreads();
  }
  #pragma unroll
  for (int i=0;i<4;i++){
    #pragma unroll
    for (int r=0;r<4;r++){
      int row = m0 + wr*64 + i*16 + fg*4 + r;
      #pragma unroll
      for (int j=0;j<4;j++){
        int col = n0 + wc*64 + j*16 + fm;
        float v = acc[i][j][r] + bias[col];
        if (ACT == 1) v = 0.5f*v*(1.0f + erff(v*0.70710678118654752f));  // exact gelu
        C[(size_t)row*N + col] = v;
      }
    }
  }
}

// ---------------- MFMA attention scores: sc = (Q*scale) @ K^T (128x128 tiles) ----------------
#define SPAD 72
__global__ __launch_bounds__(256) void k_scores_mfma(const float* __restrict__ qkv,
                                                     float* __restrict__ sc, int bbase){
  __shared__ _Float16 Qh[128][SPAD], Ql[128][SPAD];
  __shared__ _Float16 Kh[128][SPAD], Kl[128][SPAD];
  const int tid = threadIdx.x;
  const int kt = blockIdx.x & 7;
  const int qt = (blockIdx.x >> 3) & 7;
  const int h  = (blockIdx.x >> 6) & 7;
  const int hb = (blockIdx.x >> 9) & 1;
  const int b  = bbase + hb;
  const int q0 = qt*128, k0 = kt*128;
  #pragma unroll
  for (int e=0;e<8;e++){
    int lin = e*256 + tid;
    int rr = lin >> 4;
    int c4 = (lin & 15) << 2;
    float4 qv = *reinterpret_cast<const float4*>(qkv + (size_t)(b*SS + q0+rr)*1536 + h*64 + c4);
    float4 kv = *reinterpret_cast<const float4*>(qkv + (size_t)(b*SS + k0+rr)*1536 + DD + h*64 + c4);
    qv.x *= 0.125f; qv.y *= 0.125f; qv.z *= 0.125f; qv.w *= 0.125f;
    f16x4 qh, ql, kh, kl;
    h2 t;
    t = split2(qv.x); qh[0]=t.hi; ql[0]=t.lo;
    t = split2(qv.y); qh[1]=t.hi; ql[1]=t.lo;
    t = split2(qv.z); qh[2]=t.hi; ql[2]=t.lo;
    t = split2(qv.w); qh[3]=t.hi; ql[3]=t.lo;
    t = split2(kv.x); kh[0]=t.hi; kl[0]=t.lo;
    t = split2(kv.y); kh[1]=t.hi; kl[1]=t.lo;
    t = split2(kv.z); kh[2]=t.hi; kl[2]=t.lo;
    t = split2(kv.w); kh[3]=t.hi; kl[3]=t.lo;
    *reinterpret_cast<f16x4*>(&Qh[rr][c4]) = qh;
    *reinterpret_cast<f16x4*>(&Ql[rr][c4]) = ql;
    *reinterpret_cast<f16x4*>(&Kh[rr][c4]) = kh;
    *reinterpret_cast<f16x4*>(&Kl[rr][c4]) = kl;
  }
  __syncthreads();
  const int lane = tid & 63, wid = tid >> 6;
  const int wr = wid >> 1, wc = wid & 1;
  const int fm = lane & 15, fg = lane >> 4;
  f32x4 acc[4][4];
  #pragma unroll
  for (int i=0;i<4;i++)
    #pragma unroll
    for (int j=0;j<4;j++) acc[i][j] = (f32x4){0.0f,0.0f,0.0f,0.0f};
  #pragma unroll
  for (int ks=0; ks<2; ks++){
    f16x8 ah[4], al[4], bh[4], bl[4];
    #pragma unroll
    for (int i=0;i<4;i++){
      int row = wr*64 + i*16 + fm;
      ah[i] = *reinterpret_cast<const f16x8*>(&Qh[row][ks*32 + fg*8]);
      al[i] = *reinterpret_cast<const f16x8*>(&Ql[row][ks*32 + fg*8]);
    }
    #pragma unroll
    for (int j=0;j<4;j++){
      int row = wc*64 + j*16 + fm;
      bh[j] = *reinterpret_cast<const f16x8*>(&Kh[row][ks*32 + fg*8]);
      bl[j] = *reinterpret_cast<const f16x8*>(&Kl[row][ks*32 + fg*8]);
    }
    #pragma unroll
    for (int i=0;i<4;i++)
      #pragma unroll
      for (int j=0;j<4;j++){
        acc[i][j] = __builtin_amdgcn_mfma_f32_16x16x32_f16(ah[i], bh[j], acc[i][j], 0, 0, 0);
        acc[i][j] = __builtin_amdgcn_mfma_f32_16x16x32_f16(ah[i], bl[j], acc[i][j], 0, 0, 0);
        acc[i][j] = __builtin_amdgcn_mfma_f32_16x16x32_f16(al[i], bh[j], acc[i][j], 0, 0, 0);
      }
  }
  float* out = sc + (size_t)(hb*HH + h)*SS*SS;
  #pragma unroll
  for (int i=0;i<4;i++){
    #pragma unroll
    for (int r=0;r<4;r++){
      int row = q0 + wr*64 + i*16 + fg*4 + r;
      #pragma unroll
      for (int j=0;j<4;j++){
        int col = k0 + wc*64 + j*16 + fm;
        out[(size_t)row*SS + col] = acc[i][j][r];
      }
    }
  }
}

// ---------------- MFMA PV: ctx[:, h*64..] = P @ V (128q x 64d tiles, BK=64) ----------------
// Register-prefetch pipelined like k_gemm_mfma.
__global__ __launch_bounds__(256) void k_pv_mfma(const float* __restrict__ sc,
                                                 const float* __restrict__ qkv,
                                                 float* __restrict__ ctx, int bbase){
  __shared__ _Float16 Ph[128][SPAD], Pl[128][SPAD];
  __shared__ _Float16 Vh[64][SPAD],  Vl[64][SPAD];
  const int tid = threadIdx.x;
  const int qt = blockIdx.x & 7;
  const int h  = (blockIdx.x >> 3) & 7;
  const int hb = (blockIdx.x >> 6) & 1;
  const int b  = bbase + hb;
  const int q0 = qt*128;
  const float* P = sc + (size_t)(hb*HH + h)*SS*SS;
  const int lane = tid & 63, wid = tid >> 6;
  const int wr = wid >> 1, wc = wid & 1;      // wave tile: 64 rows x 32 cols
  const int fm = lane & 15, fg = lane >> 4;
  const int pr0 = tid >> 4;                   // P staging: rows pr0 + 16e
  const int pc4 = (tid & 15) << 2;
  const int vd  = tid & 63;                   // V staging: dim
  const int vk0 = tid >> 6;                   // V staging: k = vk0 + 4e
  const float* Pbase = P + (size_t)(q0 + pr0)*SS + pc4;
  const float* Vbase = qkv + (size_t)(b*SS + vk0)*1536 + 1024 + h*64 + vd;
  f32x4 acc[4][2];
  #pragma unroll
  for (int i=0;i<4;i++){ acc[i][0] = (f32x4){0,0,0,0}; acc[i][1] = (f32x4){0,0,0,0}; }

  float4 rp[8];
  float  rv[16];
  #pragma unroll
  for (int e=0;e<8;e++)  rp[e] = *reinterpret_cast<const float4*>(Pbase + (size_t)(e*16)*SS);
  #pragma unroll
  for (int e=0;e<16;e++) rv[e] = Vbase[(size_t)(e*4)*1536];

  for (int kk0=0; kk0<SS; kk0+=64){
    #pragma unroll
    for (int e=0;e<8;e++){
      int rr = pr0 + e*16;
      f16x4 ph, pl;
      h2 t;
      t = split2(rp[e].x); ph[0]=t.hi; pl[0]=t.lo;
      t = split2(rp[e].y); ph[1]=t.hi; pl[1]=t.lo;
      t = split2(rp[e].z); ph[2]=t.hi; pl[2]=t.lo;
      t = split2(rp[e].w); ph[3]=t.hi; pl[3]=t.lo;
      *reinterpret_cast<f16x4*>(&Ph[rr][pc4]) = ph;
      *reinterpret_cast<f16x4*>(&Pl[rr][pc4]) = pl;
    }
    #pragma unroll
    for (int e=0;e<16;e++){
      int k = vk0 + e*4;
      float v = rv[e];
      _Float16 hi = (_Float16)v;
      Vh[vd][k] = hi;
      Vl[vd][k] = (_Float16)(v - (float)hi);
    }
    __syncthreads();
    if (kk0 + 64 < SS){
      #pragma unroll
      for (int e=0;e<8;e++)
        rp[e] = *reinterpret_cast<const float4*>(Pbase + (size_t)(e*16)*SS + kk0 + 64);
      #pragma unroll
      for (int e=0;e<16;e++)
        rv[e] = Vbase[(size_t)(kk0 + 64 + e*4)*1536];
    }
    #pragma unroll
    for (int ks=0; ks<2; ks++){
      f16x8 ah[4], al[4], bh[2], bl[2];
      #pragma unroll
      for (int i=0;i<4;i++){
        int row = wr*64 + i*16 + fm;
        ah[i] = *reinterpret_cast<const f16x8*>(&Ph[row][ks*32 + fg*8]);
        al[i] = *reinterpret_cast<const f16x8*>(&Pl[row][ks*32 + fg*8]);
      }
      #pragma unroll
      for (int j=0;j<2;j++){
        int row = wc*32 + j*16 + fm;
        bh[j] = *reinterpret_cast<const f16x8*>(&Vh[row][ks*32 + fg*8]);
        bl[j] = *reinterpret_cast<const f16x8*>(&Vl[row][ks*32 + fg*8]);
      }
      #pragma unroll
      for (int i=0;i<4;i++)
        #pragma unroll
        for (int j=0;j<2;j++){
          acc[i][j] = __builtin_amdgcn_mfma_f32_16x16x32_f16(ah[i], bh[j], acc[i][j], 0, 0, 0);
          acc[i][j] = __builtin_amdgcn_mfma_f32_16x16x32_f16(ah[i], bl[j], acc[i][j], 0, 0, 0);
          acc[i][j] = __builtin_amdgcn_mfma_f32_16x16x32_f16(al[i], bh[j], acc[i][j], 0, 0, 0);
        }
    }
    __syncthreads();
  }
  #pragma unroll
  for (int i=0;i<4;i++){
    #pragma unroll
    for (int r=0;r<4;r++){
      int row = q0 + wr*64 + i*16 + fg*4 + r;
      #pragma unroll
      for (int j=0;j<2;j++){
        int col = wc*32 + j*16 + fm;
        ctx[(size_t)(b*SS + row)*DD + h*64 + col] = acc[i][j][r];
      }
    }
  }
}

// ---------------- persistent LSTM: 256 blocks = 4 batches x 64 chunks(8 dims) ----------------
// Dataflow sync via packed 64-bit {tag|h} relaxed agent-scope atomics (R4-verified).
__global__ __launch_bounds__(256) void k_lstm(const float* __restrict__ gates_in,
                                              const float* __restrict__ w_hh,
                                              unsigned long long* __restrict__ hpack){
  __shared__ float hsh[DD];
  __shared__ float gl[32];
  const int b = blockIdx.x >> 6;
  const int chunk = blockIdx.x & 63;
  const int d0 = chunk*8;
  const int tid = threadIdx.x;
  const int r = tid >> 3;        // 0..31 : local row = gate*8 + di
  const int ks = tid & 7;        // interleaved k-slice
  const int gate = r >> 3;
  const int di = r & 7;
  float w[64];
  {
    const float* wrow = w_hh + (size_t)(gate*DD + d0 + di)*DD;
    #pragma unroll
    for (int j=0;j<64;j++) w[j] = wrow[j*8 + ks];
  }
  float c = 0.0f;
  const float* gbase = gates_in + (size_t)(b*SS)*(4*DD) + gate*DD + d0 + di;
  for (int t=0; t<SS; ++t){
    float gv = 0.0f;
    if (ks == 0) gv = gbase[(size_t)t*(4*DD)];
    unsigned long long* hp = hpack + (size_t)(t*BB + b)*DD;
    const unsigned long long exp_tag = (unsigned long long)t;
    unsigned long long p0 = __hip_atomic_load(hp + tid,       __ATOMIC_RELAXED, __HIP_MEMORY_SCOPE_AGENT);
    unsigned long long p1 = __hip_atomic_load(hp + tid + 256, __ATOMIC_RELAXED, __HIP_MEMORY_SCOPE_AGENT);
    while ((p0 >> 32) != exp_tag || (p1 >> 32) != exp_tag){
      __builtin_amdgcn_s_sleep(1);
      if ((p0 >> 32) != exp_tag)
        p0 = __hip_atomic_load(hp + tid,       __ATOMIC_RELAXED, __HIP_MEMORY_SCOPE_AGENT);
      if ((p1 >> 32) != exp_tag)
        p1 = __hip_atomic_load(hp + tid + 256, __ATOMIC_RELAXED, __HIP_MEMORY_SCOPE_AGENT);
    }
    union { unsigned int u; float f; } u0, u1;
    u0.u = (unsigned int)p0;
    u1.u = (unsigned int)p1;
    hsh[tid]       = u0.f;
    hsh[tid + 256] = u1.f;
    __syncthreads();
    float a0=0.0f, a1=0.0f, a2=0.0f, a3=0.0f;
    #pragma unroll
    for (int j=0;j<64;j+=4){
      a0 += w[j+0]*hsh[(j+0)*8 + ks];
      a1 += w[j+1]*hsh[(j+1)*8 + ks];
      a2 += w[j+2]*hsh[(j+2)*8 + ks];
      a3 += w[j+3]*hsh[(j+3)*8 + ks];
    }
    float acc = (a0+a1)+(a2+a3);
    acc += __shfl_down(acc, 4, 8);
    acc += __shfl_down(acc, 2, 8);
    acc += __shfl_down(acc, 1, 8);
    if (ks == 0){
      float v = acc + gv;
      gl[r] = (gate == 2) ? ftanh(v) : fsig(v);   // pre-activated gate
    }
    __syncthreads();
    if (tid < 8){
      float gi = gl[tid];
      float gf = gl[8 + tid];
      float gg = gl[16 + tid];
      float go = gl[24 + tid];
      c = gf*c + gi*gg;
      float h = go*ftanh(c);
      union { float f; unsigned int u; } hu; hu.f = h;
      unsigned long long pk = ((unsigned long long)(unsigned int)(t+1) << 32)
                            | (unsigned long long)hu.u;
      __hip_atomic_store(&hpack[(size_t)((t+1)*BB + b)*DD + d0 + tid], pk,
                         __ATOMIC_RELAXED, __HIP_MEMORY_SCOPE_AGENT);
    }
  }
}

__global__ void k_resid(float* __restrict__ x, const unsigned long long* __restrict__ hpack){
  int idx = blockIdx.x*256 + threadIdx.x;
  if (idx >= NT*DD) return;
  int d = idx & (DD-1);
  int n = idx >> 9;
  int s = n & (SS-1);
  int b = n >> 10;
  union { unsigned int u; float f; } hu;
  hu.u = (unsigned int)hpack[(size_t)((s+1)*BB + b)*DD + d];
  x[idx] += hu.f;
}

// softmax rows in place + accumulate head-average into d_out attn region
// wave-per-head: 4 waves x 2 heads, pure shfl reductions, ONE barrier per block.
__global__ __launch_bounds__(256) void k_softmax(float* __restrict__ sc,
                                                 float* __restrict__ attn_out,
                                                 int l, int bbase){
  __shared__ float avgw[4][SS];   // per-wave partial head sums (16 KB)
  const int tid = threadIdx.x;
  const int q  = blockIdx.x & (SS-1);
  const int hb = blockIdx.x >> 10;
  const int b = bbase + hb;
  const int wave = tid >> 6, lane = tid & 63;
  #pragma unroll
  for (int j=0;j<4;j++) avgw[wave][j*256 + (tid & 255) - wave*0 + 0] = 0.0f;  // placeholder
  // (rewritten clean below)
  #pragma unroll
  for (int j=0;j<16;j++) avgw[wave][j*64 + lane] = 0.0f;
  #pragma unroll
  for (int hi=0; hi<2; hi++){
    int h = wave + hi*4;
    float* row = sc + (size_t)(hb*HH + h)*SS*SS + (size_t)q*SS;
    float v[16];
    float m = -1e30f;
    #pragma unroll
    for (int j=0;j<16;j++){ v[j] = row[j*64 + lane]; m = fmaxf(m, v[j]); }
    #pragma unroll
    for (int o=32;o>0;o>>=1) m = fmaxf(m, __shfl_xor(m, o));
    float s = 0.0f;
    #pragma unroll
    for (int j=0;j<16;j++){ v[j] = __expf(v[j] - m); s += v[j]; }
    #pragma unroll
    for (int o=32;o>0;o>>=1) s += __shfl_xor(s, o);
    float inv = __builtin_amdgcn_rcpf(s);
    #pragma unroll
    for (int j=0;j<16;j++){
      float p = v[j]*inv;
      row[j*64 + lane] = p;
      avgw[wave][j*64 + lane] += p;
    }
  }
  __syncthreads();
  float* ao = attn_out + (size_t)((l*BB + b)*SS + q)*SS;
  for (int j=tid;j<SS;j+=256)
    ao[j] = (avgw[0][j]+avgw[1][j]+avgw[2][j]+avgw[3][j])*0.125f;
}

// ---------------- LayerNorm: out = LN(x (+ y)) * g + b ----------------
__global__ __launch_bounds__(64) void k_ln(const float* __restrict__ x,
                                           const float* __restrict__ y,
                                           const float* __restrict__ g,
                                           const float* __restrict__ bta,
                                           float* __restrict__ out){
  const int n = blockIdx.x;
  const int tid = threadIdx.x;
  float v[8];
  float s = 0.0f, sq = 0.0f;
  #pragma unroll
  for (int j=0;j<8;j++){
    int d = j*64 + tid;
    float a = x[(size_t)n*DD + d];
    if (y) a += y[(size_t)n*DD + d];
    v[j] = a; s += a; sq += a*a;
  }
  #pragma unroll
  for (int o=32;o>0;o>>=1){ s += __shfl_xor(s, o); sq += __shfl_xor(sq, o); }
  float mean = s*(1.0f/DD);
  float var = sq*(1.0f/DD) - mean*mean;
  float rstd = rsqrtf(var + EPSF);
  #pragma unroll
  for (int j=0;j<8;j++){
    int d = j*64 + tid;
    out[(size_t)n*DD + d] = (v[j]-mean)*rstd*g[d] + bta[d];
  }
}

extern "C" void kernel_launch(void* const* d_in, const int* in_sizes, int n_in,
                              void* d_out, int out_size, void* d_ws, size_t ws_size,
                              hipStream_t stream){
  const int*   src    = (const int*)  d_in[0];
  const float* emb    = (const float*)d_in[1];
  const float* conv_w = (const float*)d_in[2];
  const float* conv_b = (const float*)d_in[3];
  const float* bn_g   = (const float*)d_in[4];
  const float* bn_b   = (const float*)d_in[5];
  const float* bn_m   = (const float*)d_in[6];
  const float* bn_v   = (const float*)d_in[7];
  const float* w_ih   = (const float*)d_in[8];
  const float* w_hh   = (const float*)d_in[9];
  const float* b_ih   = (const float*)d_in[10];
  const float* b_hh   = (const float*)d_in[11];
  const float* in_w   = (const float*)d_in[12];
  const float* in_b   = (const float*)d_in[13];
  const float* out_w  = (const float*)d_in[14];
  const float* out_b  = (const float*)d_in[15];
  const float* ln1_g  = (const float*)d_in[16];
  const float* ln1_b  = (const float*)d_in[17];
  const float* w1     = (const float*)d_in[18];
  const float* b1     = (const float*)d_in[19];
  const float* w2     = (const float*)d_in[20];
  const float* b2     = (const float*)d_in[21];
  const float* ln2_g  = (const float*)d_in[22];
  const float* ln2_b  = (const float*)d_in[23];
  const float* fin_g  = (const float*)d_in[24];
  const float* fin_b  = (const float*)d_in[25];

  float* ws    = (float*)d_ws;
  float* x0    = ws + O_X0;
  float* x1    = ws + O_X1;
  float* ctx   = ws + O_CTX;
  float* qkv   = ws + O_QKV;
  float* big   = ws + O_BIG;     // gates (low 8.39M) / scores / ffh
  float* bsum  = ws + O_BSUM;
  unsigned long long* hpack = (unsigned long long*)(big + 8388608);

  float* outx  = (float*)d_out;            // [B,S,D]
  float* attn  = outx + (size_t)NT*DD;     // [L,B,S,S]

  hipMemsetAsync(hpack, 0, (size_t)(SS+1)*BB*DD*sizeof(unsigned long long), stream);

  const int eb = (NT*DD)/256;
  k_embed<<<eb, 256, 0, stream>>>(src, emb, x0);
  k_conv <<<eb, 256, 0, stream>>>(x0, conv_w, conv_b, bn_g, bn_b, bn_m, bn_v, x1);
  k_bsum <<<8, 256, 0, stream>>>(b_ih, b_hh, bsum, 4*DD);

  // LSTM input precompute: gates = x1 @ w_ih^T + (b_ih + b_hh)
  k_gemm_mfma<0><<<(NT/128)*((4*DD)/128), 256, 0, stream>>>(
      x1, w_ih, bsum, big, NT, 4*DD, DD);
  k_lstm<<<256, 256, 0, stream>>>(big, w_hh, hpack);
  k_resid<<<eb, 256, 0, stream>>>(x1, hpack);

  float* cur = x1;
  float* tmp = x0;
  for (int l=0; l<LL; ++l){
    // qkv = cur @ in_w[l]^T + in_b[l]
    k_gemm_mfma<0><<<(NT/128)*(1536/128), 256, 0, stream>>>(
        cur, in_w + (size_t)l*1536*DD, in_b + (size_t)l*1536, qkv, NT, 1536, DD);
    for (int bb2=0; bb2<2; ++bb2){
      int bbase = bb2*2;
      k_scores_mfma<<<1024, 256, 0, stream>>>(qkv, big, bbase);
      k_softmax    <<<2048, 256, 0, stream>>>(big, attn, l, bbase);
      k_pv_mfma    <<<128,  256, 0, stream>>>(big, qkv, ctx, bbase);
    }
    // proj: tmp = ctx @ out_w[l]^T + out_b[l]
    k_gemm_mfma<0><<<(NT/128)*(DD/128), 256, 0, stream>>>(
        ctx, out_w + (size_t)l*DD*DD, out_b + (size_t)l*DD, tmp, NT, DD, DD);
    k_ln<<<NT, 64, 0, stream>>>(cur, tmp, ln1_g + l*DD, ln1_b + l*DD, cur);
    // ffh = gelu(cur @ w1[l]^T + b1[l])
    k_gemm_mfma<1><<<(NT/128)*(DFF/128), 256, 0, stream>>>(
        cur, w1 + (size_t)l*DFF*DD, b1 + (size_t)l*DFF, big, NT, DFF, DD);
    // tmp = ffh @ w2[l]^T + b2[l]
    k_gemm_mfma<0><<<(NT/128)*(DD/128), 256, 0, stream>>>(
        big, w2 + (size_t)l*DD*DFF, b2 + (size_t)l*DD, tmp, NT, DD, DFF);
    k_ln<<<NT, 64, 0, stream>>>(cur, tmp, ln2_g + l*DD, ln2_b + l*DD, cur);
  }
  k_ln<<<NT, 64, 0, stream>>>(cur, nullptr, fin_g, fin_b, outx);
}

// Round 7
// 3222.195 us; speedup vs baseline: 1.1489x; 1.0205x over previous
//
#include <hip/hip_runtime.h>
#include <math.h>

#define DD 512
#define SS 1024
#define BB 4
#define HH 8
#define DFF 2048
#define LL 4
#define NT 4096           // BB*SS
#define EPSF 1e-5f

// ---------------- workspace layout (float elements) ----------------
#define O_X0    ((size_t)0)            // 2,097,152  emb+pe
#define O_X1    ((size_t)2097152)      // 2,097,152  conv out / current x
#define O_HSEQ  ((size_t)4194304)      // 2,099,200: packed activation scratch (+qbias tail)
#define O_CTX   ((size_t)6293504)      // 2,097,152 (ctx)
#define O_QKV   ((size_t)8390656)      // 6,291,456 (packed split-pairs)
#define O_BIG   ((size_t)14682112)     // 16,777,216 (gates 8.39M / hpack / scores / ffh / W-scratch)
#define O_BSUM  ((size_t)31459328)     // 2048

typedef unsigned int  u32;
typedef unsigned short u16;
typedef __attribute__((ext_vector_type(8))) _Float16 f16x8;
typedef __attribute__((ext_vector_type(4))) _Float16 f16x4;
typedef __attribute__((ext_vector_type(4))) float    f32x4;

// fast transcendentals: v_exp_f32 / v_rcp_f32 based (~1e-7 rel, saturating-safe)
__device__ __forceinline__ float fsig(float x){
  return __builtin_amdgcn_rcpf(1.0f + __expf(-x));
}
__device__ __forceinline__ float ftanh(float x){
  return 1.0f - 2.0f*__builtin_amdgcn_rcpf(1.0f + __expf(2.0f*x));
}
struct h2 { _Float16 hi, lo; };
__device__ __forceinline__ h2 split2(float v){
  h2 r; r.hi = (_Float16)v; r.lo = (_Float16)(v - (float)r.hi); return r;
}
union f16u { u16 u; _Float16 f; };
__device__ __forceinline__ float b2f(u16 b){ f16u t; t.u = b; return (float)t.f; }
__device__ __forceinline__ u16 f2b(_Float16 h){ f16u t; t.f = h; return t.u; }
// pack f32 -> {hi f16 (low16) | lo f16 (high16)}
__device__ __forceinline__ u32 pack2(float v){
  _Float16 hi = (_Float16)v;
  _Float16 lo = (_Float16)(v - (float)hi);
  return (u32)f2b(hi) | ((u32)f2b(lo) << 16);
}
__device__ __forceinline__ float unpack2f(u32 w){
  return b2f((u16)w) + b2f((u16)(w >> 16));
}

// ---------------- embedding + sinusoidal PE ----------------
__global__ void k_embed(const int* __restrict__ src, const float* __restrict__ emb,
                        float* __restrict__ x){
  int idx = blockIdx.x*256 + threadIdx.x;
  if (idx >= NT*DD) return;
  int d = idx & (DD-1);
  int n = idx >> 9;          // b*SS + s
  int s = n & (SS-1);
  int tok = src[n];
  int i2 = d & ~1;
  float div = expf(-(float)i2 * (9.210340371976184f/512.0f));  // ln(10000)/512
  float ang = (float)s * div;
  float pe = (d & 1) ? cosf(ang) : sinf(ang);
  x[idx] = emb[(size_t)tok*DD + d]*22.62741699796952f + pe;    // sqrt(512)
}

// ---------------- depthwise conv k=3 + BN(eval) + ReLU ----------------
__global__ void k_conv(const float* __restrict__ x, const float* __restrict__ cw,
                       const float* __restrict__ cb, const float* __restrict__ bg,
                       const float* __restrict__ bb, const float* __restrict__ bm,
                       const float* __restrict__ bv, float* __restrict__ y){
  int idx = blockIdx.x*256 + threadIdx.x;
  if (idx >= NT*DD) return;
  int d = idx & (DD-1);
  int n = idx >> 9;
  int s = n & (SS-1);
  float acc = cb[d];
  if (s > 0)     acc += x[idx - DD]*cw[d*3+0];
  acc += x[idx]*cw[d*3+1];
  if (s < SS-1)  acc += x[idx + DD]*cw[d*3+2];
  float v = (acc - bm[d])*rsqrtf(bv[d]+EPSF)*bg[d] + bb[d];
  y[idx] = fmaxf(v, 0.0f);
}

__global__ void k_bsum(const float* a, const float* b, float* o, int n){
  int i = blockIdx.x*256 + threadIdx.x;
  if (i < n) o[i] = a[i] + b[i];
}

// ---------------- weight pre-split: W f32 -> packed {hi|lo} u32 ----------------
// QSCALE: scale rows<512 by 0.125 (attention Q fold) and emit scaled bias copy.
template<int QSCALE>
__global__ void k_wsplit(const float* __restrict__ W, u32* __restrict__ Wp,
                         const float* __restrict__ bias_in, float* __restrict__ bias_out,
                         int total, int K){
  int i = blockIdx.x*1024 + threadIdx.x*4;
  if (i < total){
    float4 v = *reinterpret_cast<const float4*>(W + i);
    float s = 1.0f;
    if (QSCALE){ int row = i / K; if (row < 512) s = 0.125f; }
    uint4 o;
    o.x = pack2(v.x*s); o.y = pack2(v.y*s); o.z = pack2(v.z*s); o.w = pack2(v.w*s);
    *reinterpret_cast<uint4*>(Wp + i) = o;
  }
  if (QSCALE && blockIdx.x == 0){
    for (int j = threadIdx.x; j < 1536; j += 256){
      float bv = bias_in[j];
      bias_out[j] = (j < 512) ? bv*0.125f : bv;
    }
  }
}

// ---------------- activation pre-split: A f32 -> packed u32 ----------------
__global__ void k_asplit(const float* __restrict__ A, u32* __restrict__ Ap, int total){
  int i = blockIdx.x*1024 + threadIdx.x*4;
  if (i >= total) return;
  float4 v = *reinterpret_cast<const float4*>(A + i);
  uint4 o;
  o.x = pack2(v.x); o.y = pack2(v.y); o.z = pack2(v.z); o.w = pack2(v.w);
  *reinterpret_cast<uint4*>(Ap + i) = o;
}

// unpack helper for staging: 4 packed elems -> hi u32x2 + lo u32x2 (2 halves each)
__device__ __forceinline__ void unpk4(uint4 w, uint2& hi, uint2& lo){
  hi.x = (w.x & 0xffffu) | (w.y << 16);
  hi.y = (w.z & 0xffffu) | (w.w << 16);
  lo.x = (w.x >> 16) | (w.y & 0xffff0000u);
  lo.y = (w.z >> 16) | (w.w & 0xffff0000u);
}

// ---------------- MFMA split-f16 GEMM: C[M,N] = A[M,K] @ W[N,K]^T + bias ----------------
// W always pre-split packed; A either packed (APRE=1) or f32 (APRE=0).
// OSPLIT=1: C written as packed split-pairs.
#define BKP 40   // padded K stride in halves
template<int ACT, int APRE, int OSPLIT>
__global__ __launch_bounds__(256) void k_gemm_mfma(const void* __restrict__ Ain,
                                                   const u32* __restrict__ Wp,
                                                   const float* __restrict__ bias,
                                                   void* __restrict__ Cout,
                                                   int M, int N, int K){
  __shared__ _Float16 Ah[128][BKP];
  __shared__ _Float16 Al[128][BKP];
  __shared__ _Float16 Wh[128][BKP];
  __shared__ _Float16 Wl[128][BKP];
  const int tid = threadIdx.x;
  const int nbx = N >> 7;
  const int bx = blockIdx.x % nbx;
  const int by = blockIdx.x / nbx;
  const int m0 = by << 7, n0 = bx << 7;
  const int lane = tid & 63;
  const int wid  = tid >> 6;
  const int wr = wid >> 1, wc = wid & 1;
  const int fm = lane & 15, fg = lane >> 4;
  const int r0 = tid >> 3;              // staging row base (row = r0 + 32e)
  const int k4 = (tid & 7) << 2;        // staging k offset within tile
  const u32* Wbase = Wp + (size_t)(n0 + r0)*K + k4;

  f32x4 acc[4][4];
  #pragma unroll
  for (int i=0;i<4;i++)
    #pragma unroll
    for (int j=0;j<4;j++) acc[i][j] = (f32x4){0.0f,0.0f,0.0f,0.0f};

  uint4 rw[4];
  uint4 ra4[4];
  float4 raf[4];
  #pragma unroll
  for (int e=0;e<4;e++)
    rw[e] = *reinterpret_cast<const uint4*>(Wbase + (size_t)(e*32)*K);
  if constexpr (APRE){
    const u32* Abase = (const u32*)Ain + (size_t)(m0 + r0)*K + k4;
    #pragma unroll
    for (int e=0;e<4;e++)
      ra4[e] = *reinterpret_cast<const uint4*>(Abase + (size_t)(e*32)*K);
  } else {
    const float* Abase = (const float*)Ain + (size_t)(m0 + r0)*K + k4;
    #pragma unroll
    for (int e=0;e<4;e++)
      raf[e] = *reinterpret_cast<const float4*>(Abase + (size_t)(e*32)*K);
  }

  for (int k0 = 0; k0 < K; k0 += 32){
    #pragma unroll
    for (int e = 0; e < 4; ++e){
      int rr = r0 + e*32;
      uint2 hi, lo;
      unpk4(rw[e], hi, lo);
      *reinterpret_cast<uint2*>(&Wh[rr][k4]) = hi;
      *reinterpret_cast<uint2*>(&Wl[rr][k4]) = lo;
      if constexpr (APRE){
        unpk4(ra4[e], hi, lo);
        *reinterpret_cast<uint2*>(&Ah[rr][k4]) = hi;
        *reinterpret_cast<uint2*>(&Al[rr][k4]) = lo;
      } else {
        f16x4 ahv, alv;
        h2 t;
        t = split2(raf[e].x); ahv[0]=t.hi; alv[0]=t.lo;
        t = split2(raf[e].y); ahv[1]=t.hi; alv[1]=t.lo;
        t = split2(raf[e].z); ahv[2]=t.hi; alv[2]=t.lo;
        t = split2(raf[e].w); ahv[3]=t.hi; alv[3]=t.lo;
        *reinterpret_cast<f16x4*>(&Ah[rr][k4]) = ahv;
        *reinterpret_cast<f16x4*>(&Al[rr][k4]) = alv;
      }
    }
    __syncthreads();
    if (k0 + 32 < K){
      #pragma unroll
      for (int e=0;e<4;e++)
        rw[e] = *reinterpret_cast<const uint4*>(Wbase + (size_t)(e*32)*K + k0 + 32);
      if constexpr (APRE){
        const u32* Abase = (const u32*)Ain + (size_t)(m0 + r0)*K + k4;
        #pragma unroll
        for (int e=0;e<4;e++)
          ra4[e] = *reinterpret_cast<const uint4*>(Abase + (size_t)(e*32)*K + k0 + 32);
      } else {
        const float* Abase = (const float*)Ain + (size_t)(m0 + r0)*K + k4;
        #pragma unroll
        for (int e=0;e<4;e++)
          raf[e] = *reinterpret_cast<const float4*>(Abase + (size_t)(e*32)*K + k0 + 32);
      }
    }
    f16x8 a_h[4], a_l[4], w_h[4], w_l[4];
    #pragma unroll
    for (int i=0;i<4;i++){
      int row = wr*64 + i*16 + fm;
      a_h[i] = *reinterpret_cast<const f16x8*>(&Ah[row][fg*8]);
      a_l[i] = *reinterpret_cast<const f16x8*>(&Al[row][fg*8]);
    }
    #pragma unroll
    for (int j=0;j<4;j++){
      int row = wc*64 + j*16 + fm;
      w_h[j] = *reinterpret_cast<const f16x8*>(&Wh[row][fg*8]);
      w_l[j] = *reinterpret_cast<const f16x8*>(&Wl[row][fg*8]);
    }
    #pragma unroll
    for (int i=0;i<4;i++)
      #pragma unroll
      for (int j=0;j<4;j++){
        acc[i][j] = __builtin_amdgcn_mfma_f32_16x16x32_f16(a_h[i], w_h[j], acc[i][j], 0, 0, 0);
        acc[i][j] = __builtin_amdgcn_mfma_f32_16x16x32_f16(a_h[i], w_l[j], acc[i][j], 0, 0, 0);
        acc[i][j] = __builtin_amdgcn_mfma_f32_16x16x32_f16(a_l[i], w_h[j], acc[i][j], 0, 0, 0);
      }
    __syncthreads();
  }
  #pragma unroll
  for (int i=0;i<4;i++){
    #pragma unroll
    for (int r=0;r<4;r++){
      int row = m0 + wr*64 + i*16 + fg*4 + r;
      #pragma unroll
      for (int j=0;j<4;j++){
        int col = n0 + wc*64 + j*16 + fm;
        float v = acc[i][j][r] + bias[col];
        if (ACT == 1) v = 0.5f*v*(1.0f + erff(v*0.70710678118654752f));  // exact gelu
        if constexpr (OSPLIT) ((u32*)Cout)[(size_t)row*N + col] = pack2(v);
        else                  ((float*)Cout)[(size_t)row*N + col] = v;
      }
    }
  }
}

// ---------------- MFMA attention scores: sc = Qs @ K^T (128x128 tiles) ----------------
// qkv is packed split-pairs (Q pre-scaled by 0.125 via weight fold). Output packed pairs.
#define SPAD 72
__global__ __launch_bounds__(256) void k_scores_mfma(const u32* __restrict__ qkv,
                                                     u32* __restrict__ sc, int bbase){
  __shared__ _Float16 Qh[128][SPAD], Ql[128][SPAD];
  __shared__ _Float16 Kh[128][SPAD], Kl[128][SPAD];
  const int tid = threadIdx.x;
  const int kt = blockIdx.x & 7;
  const int qt = (blockIdx.x >> 3) & 7;
  const int h  = (blockIdx.x >> 6) & 7;
  const int hb = (blockIdx.x >> 9) & 1;
  const int b  = bbase + hb;
  const int q0 = qt*128, k0 = kt*128;
  #pragma unroll
  for (int e=0;e<8;e++){
    int lin = e*256 + tid;
    int rr = lin >> 4;
    int c4 = (lin & 15) << 2;
    uint4 qv = *reinterpret_cast<const uint4*>(qkv + (size_t)(b*SS + q0+rr)*1536 + h*64 + c4);
    uint4 kv = *reinterpret_cast<const uint4*>(qkv + (size_t)(b*SS + k0+rr)*1536 + DD + h*64 + c4);
    uint2 hi, lo;
    unpk4(qv, hi, lo);
    *reinterpret_cast<uint2*>(&Qh[rr][c4]) = hi;
    *reinterpret_cast<uint2*>(&Ql[rr][c4]) = lo;
    unpk4(kv, hi, lo);
    *reinterpret_cast<uint2*>(&Kh[rr][c4]) = hi;
    *reinterpret_cast<uint2*>(&Kl[rr][c4]) = lo;
  }
  __syncthreads();
  const int lane = tid & 63, wid = tid >> 6;
  const int wr = wid >> 1, wc = wid & 1;
  const int fm = lane & 15, fg = lane >> 4;
  f32x4 acc[4][4];
  #pragma unroll
  for (int i=0;i<4;i++)
    #pragma unroll
    for (int j=0;j<4;j++) acc[i][j] = (f32x4){0.0f,0.0f,0.0f,0.0f};
  #pragma unroll
  for (int ks=0; ks<2; ks++){
    f16x8 ah[4], al[4], bh[4], bl[4];
    #pragma unroll
    for (int i=0;i<4;i++){
      int row = wr*64 + i*16 + fm;
      ah[i] = *reinterpret_cast<const f16x8*>(&Qh[row][ks*32 + fg*8]);
      al[i] = *reinterpret_cast<const f16x8*>(&Ql[row][ks*32 + fg*8]);
    }
    #pragma unroll
    for (int j=0;j<4;j++){
      int row = wc*64 + j*16 + fm;
      bh[j] = *reinterpret_cast<const f16x8*>(&Kh[row][ks*32 + fg*8]);
      bl[j] = *reinterpret_cast<const f16x8*>(&Kl[row][ks*32 + fg*8]);
    }
    #pragma unroll
    for (int i=0;i<4;i++)
      #pragma unroll
      for (int j=0;j<4;j++){
        acc[i][j] = __builtin_amdgcn_mfma_f32_16x16x32_f16(ah[i], bh[j], acc[i][j], 0, 0, 0);
        acc[i][j] = __builtin_amdgcn_mfma_f32_16x16x32_f16(ah[i], bl[j], acc[i][j], 0, 0, 0);
        acc[i][j] = __builtin_amdgcn_mfma_f32_16x16x32_f16(al[i], bh[j], acc[i][j], 0, 0, 0);
      }
  }
  u32* out = sc + (size_t)(hb*HH + h)*SS*SS;
  #pragma unroll
  for (int i=0;i<4;i++){
    #pragma unroll
    for (int r=0;r<4;r++){
      int row = q0 + wr*64 + i*16 + fg*4 + r;
      #pragma unroll
      for (int j=0;j<4;j++){
        int col = k0 + wc*64 + j*16 + fm;
        out[(size_t)row*SS + col] = pack2(acc[i][j][r]);
      }
    }
  }
}

// ---------------- MFMA PV: ctx[:, h*64..] = P @ V (128q x 64d tiles, BK=64) ----------------
// P is f16 plane (written by softmax); V packed pairs. 2 MFMA per fragment pair.
__global__ __launch_bounds__(256) void k_pv_mfma(const u32* __restrict__ sc,
                                                 const u32* __restrict__ qkv,
                                                 float* __restrict__ ctx, int bbase){
  __shared__ _Float16 Ph[128][SPAD];
  __shared__ _Float16 Vh[64][SPAD],  Vl[64][SPAD];
  const int tid = threadIdx.x;
  const int qt = blockIdx.x & 7;
  const int h  = (blockIdx.x >> 3) & 7;
  const int hb = (blockIdx.x >> 6) & 1;
  const int b  = bbase + hb;
  const int q0 = qt*128;
  const u16* Pb = (const u16*)(sc + (size_t)(hb*HH + h)*SS*SS);
  const int lane = tid & 63, wid = tid >> 6;
  const int wr = wid >> 1, wc = wid & 1;      // wave tile: 64 rows x 32 cols
  const int fm = lane & 15, fg = lane >> 4;
  const int pr0 = tid >> 4;                   // P staging: rows pr0 + 16e
  const int pc4 = (tid & 15) << 2;
  const int vd  = tid & 63;                   // V staging: dim
  const int vk0 = tid >> 6;                   // V staging: k = vk0 + 4e
  const u16* Pbase = Pb + (size_t)(q0 + pr0)*2*SS + pc4;
  const u32* Vbase = qkv + (size_t)(b*SS + vk0)*1536 + 1024 + h*64 + vd;
  f32x4 acc[4][2];
  #pragma unroll
  for (int i=0;i<4;i++){ acc[i][0] = (f32x4){0,0,0,0}; acc[i][1] = (f32x4){0,0,0,0}; }

  uint2 rp[8];
  u32   rv[16];
  #pragma unroll
  for (int e=0;e<8;e++)  rp[e] = *reinterpret_cast<const uint2*>(Pbase + (size_t)(e*16)*2*SS);
  #pragma unroll
  for (int e=0;e<16;e++) rv[e] = Vbase[(size_t)(e*4)*1536];

  for (int kk0=0; kk0<SS; kk0+=64){
    #pragma unroll
    for (int e=0;e<8;e++){
      int rr = pr0 + e*16;
      *reinterpret_cast<uint2*>(&Ph[rr][pc4]) = rp[e];   // f16 bits verbatim
    }
    #pragma unroll
    for (int e=0;e<16;e++){
      int k = vk0 + e*4;
      u32 w = rv[e];
      f16u thi, tlo; thi.u = (u16)w; tlo.u = (u16)(w >> 16);
      Vh[vd][k] = thi.f;
      Vl[vd][k] = tlo.f;
    }
    __syncthreads();
    if (kk0 + 64 < SS){
      #pragma unroll
      for (int e=0;e<8;e++)
        rp[e] = *reinterpret_cast<const uint2*>(Pbase + (size_t)(e*16)*2*SS + kk0 + 64);
      #pragma unroll
      for (int e=0;e<16;e++)
        rv[e] = Vbase[(size_t)(kk0 + 64 + e*4)*1536];
    }
    #pragma unroll
    for (int ks=0; ks<2; ks++){
      f16x8 ah[4], bh[2], bl[2];
      #pragma unroll
      for (int i=0;i<4;i++){
        int row = wr*64 + i*16 + fm;
        ah[i] = *reinterpret_cast<const f16x8*>(&Ph[row][ks*32 + fg*8]);
      }
      #pragma unroll
      for (int j=0;j<2;j++){
        int row = wc*32 + j*16 + fm;
        bh[j] = *reinterpret_cast<const f16x8*>(&Vh[row][ks*32 + fg*8]);
        bl[j] = *reinterpret_cast<const f16x8*>(&Vl[row][ks*32 + fg*8]);
      }
      #pragma unroll
      for (int i=0;i<4;i++)
        #pragma unroll
        for (int j=0;j<2;j++){
          acc[i][j] = __builtin_amdgcn_mfma_f32_16x16x32_f16(ah[i], bh[j], acc[i][j], 0, 0, 0);
          acc[i][j] = __builtin_amdgcn_mfma_f32_16x16x32_f16(ah[i], bl[j], acc[i][j], 0, 0, 0);
        }
    }
    __syncthreads();
  }
  #pragma unroll
  for (int i=0;i<4;i++){
    #pragma unroll
    for (int r=0;r<4;r++){
      int row = q0 + wr*64 + i*16 + fg*4 + r;
      #pragma unroll
      for (int j=0;j<2;j++){
        int col = wc*32 + j*16 + fm;
        ctx[(size_t)(b*SS + row)*DD + h*64 + col] = acc[i][j][r];
      }
    }
  }
}

// ---------------- persistent LSTM (R4-verified protocol; no-sleep poll) ----------------
__global__ __launch_bounds__(256) void k_lstm(const float* __restrict__ gates_in,
                                              const float* __restrict__ w_hh,
                                              unsigned long long* __restrict__ hpack){
  __shared__ float hsh[DD];
  __shared__ float gl[32];
  const int b = blockIdx.x >> 6;
  const int chunk = blockIdx.x & 63;
  const int d0 = chunk*8;
  const int tid = threadIdx.x;
  const int r = tid >> 3;        // 0..31 : local row = gate*8 + di
  const int ks = tid & 7;        // interleaved k-slice
  const int gate = r >> 3;
  const int di = r & 7;
  float w[64];
  {
    const float* wrow = w_hh + (size_t)(gate*DD + d0 + di)*DD;
    #pragma unroll
    for (int j=0;j<64;j++) w[j] = wrow[j*8 + ks];
  }
  float c = 0.0f;
  const float* gbase = gates_in + (size_t)(b*SS)*(4*DD) + gate*DD + d0 + di;
  for (int t=0; t<SS; ++t){
    float gv = 0.0f;
    if (ks == 0) gv = gbase[(size_t)t*(4*DD)];
    unsigned long long* hp = hpack + (size_t)(t*BB + b)*DD;
    const unsigned long long exp_tag = (unsigned long long)t;
    unsigned long long p0 = __hip_atomic_load(hp + tid,       __ATOMIC_RELAXED, __HIP_MEMORY_SCOPE_AGENT);
    unsigned long long p1 = __hip_atomic_load(hp + tid + 256, __ATOMIC_RELAXED, __HIP_MEMORY_SCOPE_AGENT);
    while ((p0 >> 32) != exp_tag || (p1 >> 32) != exp_tag){
      if ((p0 >> 32) != exp_tag)
        p0 = __hip_atomic_load(hp + tid,       __ATOMIC_RELAXED, __HIP_MEMORY_SCOPE_AGENT);
      if ((p1 >> 32) != exp_tag)
        p1 = __hip_atomic_load(hp + tid + 256, __ATOMIC_RELAXED, __HIP_MEMORY_SCOPE_AGENT);
    }
    union { unsigned int u; float f; } u0, u1;
    u0.u = (unsigned int)p0;
    u1.u = (unsigned int)p1;
    hsh[tid]       = u0.f;
    hsh[tid + 256] = u1.f;
    __syncthreads();
    float a0=0.0f, a1=0.0f, a2=0.0f, a3=0.0f;
    #pragma unroll
    for (int j=0;j<64;j+=4){
      a0 += w[j+0]*hsh[(j+0)*8 + ks];
      a1 += w[j+1]*hsh[(j+1)*8 + ks];
      a2 += w[j+2]*hsh[(j+2)*8 + ks];
      a3 += w[j+3]*hsh[(j+3)*8 + ks];
    }
    float acc = (a0+a1)+(a2+a3);
    acc += __shfl_down(acc, 4, 8);
    acc += __shfl_down(acc, 2, 8);
    acc += __shfl_down(acc, 1, 8);
    if (ks == 0){
      float v = acc + gv;
      gl[r] = (gate == 2) ? ftanh(v) : fsig(v);   // pre-activated gate
    }
    __syncthreads();
    if (tid < 8){
      float gi = gl[tid];
      float gf = gl[8 + tid];
      float gg = gl[16 + tid];
      float go = gl[24 + tid];
      c = gf*c + gi*gg;
      float h = go*ftanh(c);
      union { float f; unsigned int u; } hu; hu.f = h;
      unsigned long long pk = ((unsigned long long)(unsigned int)(t+1) << 32)
                            | (unsigned long long)hu.u;
      __hip_atomic_store(&hpack[(size_t)((t+1)*BB + b)*DD + d0 + tid], pk,
                         __ATOMIC_RELAXED, __HIP_MEMORY_SCOPE_AGENT);
    }
  }
}

__global__ void k_resid(float* __restrict__ x, const unsigned long long* __restrict__ hpack){
  int idx = blockIdx.x*256 + threadIdx.x;
  if (idx >= NT*DD) return;
  int d = idx & (DD-1);
  int n = idx >> 9;
  int s = n & (SS-1);
  int b = n >> 10;
  union { unsigned int u; float f; } hu;
  hu.u = (unsigned int)hpack[(size_t)((s+1)*BB + b)*DD + d];
  x[idx] += hu.f;
}

// softmax: reads packed score pairs, writes P as f16 plane (in-place, half-width)
// + accumulates head-average into d_out attn region. 4 waves x 2 heads, 1 barrier.
__global__ __launch_bounds__(256) void k_softmax(u32* __restrict__ sc,
                                                 float* __restrict__ attn_out,
                                                 int l, int bbase){
  __shared__ float avgw[4][SS];   // per-wave partial head sums (16 KB)
  const int tid = threadIdx.x;
  const int q  = blockIdx.x & (SS-1);
  const int hb = blockIdx.x >> 10;
  const int b = bbase + hb;
  const int wave = tid >> 6, lane = tid & 63;
  #pragma unroll
  for (int j=0;j<16;j++) avgw[wave][j*64 + lane] = 0.0f;
  #pragma unroll
  for (int hi=0; hi<2; hi++){
    int h = wave + hi*4;
    u32* row = sc + (size_t)(hb*HH + h)*SS*SS + (size_t)q*SS;
    float v[16];
    float m = -1e30f;
    #pragma unroll
    for (int j=0;j<16;j++){ v[j] = unpack2f(row[j*64 + lane]); m = fmaxf(m, v[j]); }
    #pragma unroll
    for (int o=32;o>0;o>>=1) m = fmaxf(m, __shfl_xor(m, o));
    float s = 0.0f;
    #pragma unroll
    for (int j=0;j<16;j++){ v[j] = __expf(v[j] - m); s += v[j]; }
    #pragma unroll
    for (int o=32;o>0;o>>=1) s += __shfl_xor(s, o);
    float inv = __builtin_amdgcn_rcpf(s);
    u16* p16 = (u16*)row;
    #pragma unroll
    for (int j=0;j<16;j++){
      float p = v[j]*inv;
      p16[j*64 + lane] = f2b((_Float16)p);
      avgw[wave][j*64 + lane] += p;
    }
  }
  __syncthreads();
  float* ao = attn_out + (size_t)((l*BB + b)*SS + q)*SS;
  for (int j=tid;j<SS;j+=256)
    ao[j] = (avgw[0][j]+avgw[1][j]+avgw[2][j]+avgw[3][j])*0.125f;
}

// ---------------- LayerNorm: out = LN(x (+ y)) * g + b ----------------
__global__ __launch_bounds__(64) void k_ln(const float* __restrict__ x,
                                           const float* __restrict__ y,
                                           const float* __restrict__ g,
                                           const float* __restrict__ bta,
                                           float* __restrict__ out){
  const int n = blockIdx.x;
  const int tid = threadIdx.x;
  float v[8];
  float s = 0.0f, sq = 0.0f;
  #pragma unroll
  for (int j=0;j<8;j++){
    int d = j*64 + tid;
    float a = x[(size_t)n*DD + d];
    if (y) a += y[(size_t)n*DD + d];
    v[j] = a; s += a; sq += a*a;
  }
  #pragma unroll
  for (int o=32;o>0;o>>=1){ s += __shfl_xor(s, o); sq += __shfl_xor(sq, o); }
  float mean = s*(1.0f/DD);
  float var = sq*(1.0f/DD) - mean*mean;
  float rstd = rsqrtf(var + EPSF);
  #pragma unroll
  for (int j=0;j<8;j++){
    int d = j*64 + tid;
    out[(size_t)n*DD + d] = (v[j]-mean)*rstd*g[d] + bta[d];
  }
}

extern "C" void kernel_launch(void* const* d_in, const int* in_sizes, int n_in,
                              void* d_out, int out_size, void* d_ws, size_t ws_size,
                              hipStream_t stream){
  const int*   src    = (const int*)  d_in[0];
  const float* emb    = (const float*)d_in[1];
  const float* conv_w = (const float*)d_in[2];
  const float* conv_b = (const float*)d_in[3];
  const float* bn_g   = (const float*)d_in[4];
  const float* bn_b   = (const float*)d_in[5];
  const float* bn_m   = (const float*)d_in[6];
  const float* bn_v   = (const float*)d_in[7];
  const float* w_ih   = (const float*)d_in[8];
  const float* w_hh   = (const float*)d_in[9];
  const float* b_ih   = (const float*)d_in[10];
  const float* b_hh   = (const float*)d_in[11];
  const float* in_w   = (const float*)d_in[12];
  const float* in_b   = (const float*)d_in[13];
  const float* out_w  = (const float*)d_in[14];
  const float* out_b  = (const float*)d_in[15];
  const float* ln1_g  = (const float*)d_in[16];
  const float* ln1_b  = (const float*)d_in[17];
  const float* w1     = (const float*)d_in[18];
  const float* b1     = (const float*)d_in[19];
  const float* w2     = (const float*)d_in[20];
  const float* b2     = (const float*)d_in[21];
  const float* ln2_g  = (const float*)d_in[22];
  const float* ln2_b  = (const float*)d_in[23];
  const float* fin_g  = (const float*)d_in[24];
  const float* fin_b  = (const float*)d_in[25];

  float* ws    = (float*)d_ws;
  float* x0    = ws + O_X0;
  float* x1    = ws + O_X1;
  float* ctx   = ws + O_CTX;
  float* qkv   = ws + O_QKV;     // packed u32 pairs
  float* big   = ws + O_BIG;
  float* bsum  = ws + O_BSUM;
  unsigned long long* hpack = (unsigned long long*)(big + 8388608);

  u32*   aconv = (u32*)(ws + O_HSEQ);               // 2,097,152 packed activations
  float* qbias = ws + O_HSEQ + 2097152;             // 1536 scaled qkv bias
  u32*   qkvp  = (u32*)qkv;
  u32*   scp   = (u32*)big;                         // scores as packed pairs
  u32*   wsg   = (u32*)(big + 13000000);            // gates W scratch (1M, clear of hpack)
  u32*   wsa   = (u32*)big;                         // qkv/proj W scratch (at big+0)
  u32*   ws1   = (u32*)(big + 8500000);             // ffn1 W scratch
  u32*   ws2   = (u32*)(big + 9500000);             // ffn2 W scratch

  float* outx  = (float*)d_out;            // [B,S,D]
  float* attn  = outx + (size_t)NT*DD;     // [L,B,S,S]

  hipMemsetAsync(hpack, 0, (size_t)(SS+1)*BB*DD*sizeof(unsigned long long), stream);

  const int eb = (NT*DD)/256;
  k_embed<<<eb, 256, 0, stream>>>(src, emb, x0);
  k_conv <<<eb, 256, 0, stream>>>(x0, conv_w, conv_b, bn_g, bn_b, bn_m, bn_v, x1);
  k_bsum <<<8, 256, 0, stream>>>(b_ih, b_hh, bsum, 4*DD);

  // LSTM input precompute: gates = x1 @ w_ih^T + (b_ih + b_hh)
  k_asplit<<<2048, 256, 0, stream>>>(x1, aconv, NT*DD);
  k_wsplit<0><<<1024, 256, 0, stream>>>(w_ih, wsg, nullptr, nullptr, 2048*512, 512);
  k_gemm_mfma<0,1,0><<<(NT/128)*((4*DD)/128), 256, 0, stream>>>(
      aconv, wsg, bsum, big, NT, 4*DD, DD);
  k_lstm<<<256, 256, 0, stream>>>(big, w_hh, hpack);
  k_resid<<<eb, 256, 0, stream>>>(x1, hpack);

  float* cur = x1;
  float* tmp = x0;
  for (int l=0; l<LL; ++l){
    // qkv = cur @ in_w[l]^T + in_b[l]  (Q rows pre-scaled 0.125; packed output)
    k_asplit<<<2048, 256, 0, stream>>>(cur, aconv, NT*DD);
    k_wsplit<1><<<768, 256, 0, stream>>>(in_w + (size_t)l*1536*DD, wsa,
                                         in_b + (size_t)l*1536, qbias, 1536*512, 512);
    k_gemm_mfma<0,1,1><<<(NT/128)*(1536/128), 256, 0, stream>>>(
        aconv, wsa, qbias, qkvp, NT, 1536, DD);
    for (int bb2=0; bb2<2; ++bb2){
      int bbase = bb2*2;
      k_scores_mfma<<<1024, 256, 0, stream>>>(qkvp, scp, bbase);
      k_softmax    <<<2048, 256, 0, stream>>>(scp, attn, l, bbase);
      k_pv_mfma    <<<128,  256, 0, stream>>>(scp, qkvp, ctx, bbase);
    }
    // proj: tmp = ctx @ out_w[l]^T + out_b[l]   (A f32 path)
    k_wsplit<0><<<256, 256, 0, stream>>>(out_w + (size_t)l*DD*DD, wsa,
                                         nullptr, nullptr, 512*512, 512);
    k_gemm_mfma<0,0,0><<<(NT/128)*(DD/128), 256, 0, stream>>>(
        ctx, wsa, out_b + (size_t)l*DD, tmp, NT, DD, DD);
    k_ln<<<NT, 64, 0, stream>>>(cur, tmp, ln1_g + l*DD, ln1_b + l*DD, cur);
    // ffh = gelu(cur @ w1[l]^T + b1[l])  -> packed pairs in big[0..8.39M)
    k_asplit<<<2048, 256, 0, stream>>>(cur, aconv, NT*DD);
    k_wsplit<0><<<1024, 256, 0, stream>>>(w1 + (size_t)l*DFF*DD, ws1,
                                          nullptr, nullptr, 2048*512, 512);
    k_gemm_mfma<1,1,1><<<(NT/128)*(DFF/128), 256, 0, stream>>>(
        aconv, ws1, b1 + (size_t)l*DFF, (u32*)big, NT, DFF, DD);
    // tmp = ffh @ w2[l]^T + b2[l]   (A = packed ffh)
    k_wsplit<0><<<1024, 256, 0, stream>>>(w2 + (size_t)l*DD*DFF, ws2,
                                          nullptr, nullptr, 512*2048, 2048);
    k_gemm_mfma<0,1,0><<<(NT/128)*(DD/128), 256, 0, stream>>>(
        (u32*)big, ws2, b2 + (size_t)l*DD, tmp, NT, DD, DFF);
    k_ln<<<NT, 64, 0, stream>>>(cur, tmp, ln2_g + l*DD, ln2_b + l*DD, cur);
  }
  k_ln<<<NT, 64, 0, stream>>>(cur, nullptr, fin_g, fin_b, outx);
}

// Round 8
// 2922.306 us; speedup vs baseline: 1.2668x; 1.1026x over previous
//
#include <hip/hip_runtime.h>
#include <math.h>

#define DD 512
#define SS 1024
#define BB 4
#define HH 8
#define DFF 2048
#define LL 4
#define NT 4096           // BB*SS
#define EPSF 1e-5f

// ---------------- workspace layout (float elements) ----------------
#define O_X0    ((size_t)0)            // 2,097,152  emb+pe
#define O_X1    ((size_t)2097152)      // 2,097,152  conv out / current x
#define O_HSEQ  ((size_t)4194304)      // 2,099,200: packed activation scratch (+qbias tail)
#define O_CTX   ((size_t)6293504)      // 2,097,152 (ctx)
#define O_QKV   ((size_t)8390656)      // 6,291,456 (packed split-pairs)
#define O_BIG   ((size_t)14682112)     // 16,777,216 (gates 8.39M / hpack / scores / ffh / W-scratch)
#define O_BSUM  ((size_t)31459328)     // 2048

typedef unsigned int  u32;
typedef unsigned short u16;
typedef __attribute__((ext_vector_type(8))) _Float16 f16x8;
typedef __attribute__((ext_vector_type(4))) _Float16 f16x4;
typedef __attribute__((ext_vector_type(4))) float    f32x4;

// fast transcendentals: v_exp_f32 / v_rcp_f32 based (~1e-7 rel, saturating-safe)
__device__ __forceinline__ float fsig(float x){
  return __builtin_amdgcn_rcpf(1.0f + __expf(-x));
}
__device__ __forceinline__ float ftanh(float x){
  return 1.0f - 2.0f*__builtin_amdgcn_rcpf(1.0f + __expf(2.0f*x));
}
struct h2 { _Float16 hi, lo; };
__device__ __forceinline__ h2 split2(float v){
  h2 r; r.hi = (_Float16)v; r.lo = (_Float16)(v - (float)r.hi); return r;
}
union f16u { u16 u; _Float16 f; };
__device__ __forceinline__ float b2f(u16 b){ f16u t; t.u = b; return (float)t.f; }
__device__ __forceinline__ u16 f2b(_Float16 h){ f16u t; t.f = h; return t.u; }
// pack f32 -> {hi f16 (low16) | lo f16 (high16)}
__device__ __forceinline__ u32 pack2(float v){
  _Float16 hi = (_Float16)v;
  _Float16 lo = (_Float16)(v - (float)hi);
  return (u32)f2b(hi) | ((u32)f2b(lo) << 16);
}
__device__ __forceinline__ float unpack2f(u32 w){
  return b2f((u16)w) + b2f((u16)(w >> 16));
}

// ---------------- embedding + sinusoidal PE ----------------
__global__ void k_embed(const int* __restrict__ src, const float* __restrict__ emb,
                        float* __restrict__ x){
  int idx = blockIdx.x*256 + threadIdx.x;
  if (idx >= NT*DD) return;
  int d = idx & (DD-1);
  int n = idx >> 9;          // b*SS + s
  int s = n & (SS-1);
  int tok = src[n];
  int i2 = d & ~1;
  float div = expf(-(float)i2 * (9.210340371976184f/512.0f));  // ln(10000)/512
  float ang = (float)s * div;
  float pe = (d & 1) ? cosf(ang) : sinf(ang);
  x[idx] = emb[(size_t)tok*DD + d]*22.62741699796952f + pe;    // sqrt(512)
}

// ---------------- depthwise conv k=3 + BN(eval) + ReLU ----------------
__global__ void k_conv(const float* __restrict__ x, const float* __restrict__ cw,
                       const float* __restrict__ cb, const float* __restrict__ bg,
                       const float* __restrict__ bb, const float* __restrict__ bm,
                       const float* __restrict__ bv, float* __restrict__ y){
  int idx = blockIdx.x*256 + threadIdx.x;
  if (idx >= NT*DD) return;
  int d = idx & (DD-1);
  int n = idx >> 9;
  int s = n & (SS-1);
  float acc = cb[d];
  if (s > 0)     acc += x[idx - DD]*cw[d*3+0];
  acc += x[idx]*cw[d*3+1];
  if (s < SS-1)  acc += x[idx + DD]*cw[d*3+2];
  float v = (acc - bm[d])*rsqrtf(bv[d]+EPSF)*bg[d] + bb[d];
  y[idx] = fmaxf(v, 0.0f);
}

__global__ void k_bsum(const float* a, const float* b, float* o, int n){
  int i = blockIdx.x*256 + threadIdx.x;
  if (i < n) o[i] = a[i] + b[i];
}

// ---------------- weight pre-split: W f32 -> packed {hi|lo} u32 ----------------
// QSCALE: scale rows<512 by 0.125 (attention Q fold) and emit scaled bias copy.
template<int QSCALE>
__global__ void k_wsplit(const float* __restrict__ W, u32* __restrict__ Wp,
                         const float* __restrict__ bias_in, float* __restrict__ bias_out,
                         int total, int K){
  int i = blockIdx.x*1024 + threadIdx.x*4;
  if (i < total){
    float4 v = *reinterpret_cast<const float4*>(W + i);
    float s = 1.0f;
    if (QSCALE){ int row = i / K; if (row < 512) s = 0.125f; }
    uint4 o;
    o.x = pack2(v.x*s); o.y = pack2(v.y*s); o.z = pack2(v.z*s); o.w = pack2(v.w*s);
    *reinterpret_cast<uint4*>(Wp + i) = o;
  }
  if (QSCALE && blockIdx.x == 0){
    for (int j = threadIdx.x; j < 1536; j += 256){
      float bv = bias_in[j];
      bias_out[j] = (j < 512) ? bv*0.125f : bv;
    }
  }
}

// ---------------- activation pre-split: A f32 -> packed u32 ----------------
__global__ void k_asplit(const float* __restrict__ A, u32* __restrict__ Ap, int total){
  int i = blockIdx.x*1024 + threadIdx.x*4;
  if (i >= total) return;
  float4 v = *reinterpret_cast<const float4*>(A + i);
  uint4 o;
  o.x = pack2(v.x); o.y = pack2(v.y); o.z = pack2(v.z); o.w = pack2(v.w);
  *reinterpret_cast<uint4*>(Ap + i) = o;
}

// unpack helper for staging: 4 packed elems -> hi u32x2 + lo u32x2 (2 halves each)
__device__ __forceinline__ void unpk4(uint4 w, uint2& hi, uint2& lo){
  hi.x = (w.x & 0xffffu) | (w.y << 16);
  hi.y = (w.z & 0xffffu) | (w.w << 16);
  lo.x = (w.x >> 16) | (w.y & 0xffff0000u);
  lo.y = (w.z >> 16) | (w.w & 0xffff0000u);
}

// ---------------- MFMA split-f16 GEMM: C[M,N] = A[M,K] @ W[N,K]^T + bias ----------------
// W always pre-split packed; A either packed (APRE=1) or f32 (APRE=0).
// OSPLIT=1: C written as packed split-pairs.
#define BKP 40   // padded K stride in halves
template<int ACT, int APRE, int OSPLIT>
__global__ __launch_bounds__(256) void k_gemm_mfma(const void* __restrict__ Ain,
                                                   const u32* __restrict__ Wp,
                                                   const float* __restrict__ bias,
                                                   void* __restrict__ Cout,
                                                   int M, int N, int K){
  __shared__ _Float16 Ah[128][BKP];
  __shared__ _Float16 Al[128][BKP];
  __shared__ _Float16 Wh[128][BKP];
  __shared__ _Float16 Wl[128][BKP];
  const int tid = threadIdx.x;
  const int nbx = N >> 7;
  const int bx = blockIdx.x % nbx;
  const int by = blockIdx.x / nbx;
  const int m0 = by << 7, n0 = bx << 7;
  const int lane = tid & 63;
  const int wid  = tid >> 6;
  const int wr = wid >> 1, wc = wid & 1;
  const int fm = lane & 15, fg = lane >> 4;
  const int r0 = tid >> 3;              // staging row base (row = r0 + 32e)
  const int k4 = (tid & 7) << 2;        // staging k offset within tile
  const u32* Wbase = Wp + (size_t)(n0 + r0)*K + k4;

  f32x4 acc[4][4];
  #pragma unroll
  for (int i=0;i<4;i++)
    #pragma unroll
    for (int j=0;j<4;j++) acc[i][j] = (f32x4){0.0f,0.0f,0.0f,0.0f};

  uint4 rw[4];
  uint4 ra4[4];
  float4 raf[4];
  #pragma unroll
  for (int e=0;e<4;e++)
    rw[e] = *reinterpret_cast<const uint4*>(Wbase + (size_t)(e*32)*K);
  if constexpr (APRE){
    const u32* Abase = (const u32*)Ain + (size_t)(m0 + r0)*K + k4;
    #pragma unroll
    for (int e=0;e<4;e++)
      ra4[e] = *reinterpret_cast<const uint4*>(Abase + (size_t)(e*32)*K);
  } else {
    const float* Abase = (const float*)Ain + (size_t)(m0 + r0)*K + k4;
    #pragma unroll
    for (int e=0;e<4;e++)
      raf[e] = *reinterpret_cast<const float4*>(Abase + (size_t)(e*32)*K);
  }

  for (int k0 = 0; k0 < K; k0 += 32){
    #pragma unroll
    for (int e = 0; e < 4; ++e){
      int rr = r0 + e*32;
      uint2 hi, lo;
      unpk4(rw[e], hi, lo);
      *reinterpret_cast<uint2*>(&Wh[rr][k4]) = hi;
      *reinterpret_cast<uint2*>(&Wl[rr][k4]) = lo;
      if constexpr (APRE){
        unpk4(ra4[e], hi, lo);
        *reinterpret_cast<uint2*>(&Ah[rr][k4]) = hi;
        *reinterpret_cast<uint2*>(&Al[rr][k4]) = lo;
      } else {
        f16x4 ahv, alv;
        h2 t;
        t = split2(raf[e].x); ahv[0]=t.hi; alv[0]=t.lo;
        t = split2(raf[e].y); ahv[1]=t.hi; alv[1]=t.lo;
        t = split2(raf[e].z); ahv[2]=t.hi; alv[2]=t.lo;
        t = split2(raf[e].w); ahv[3]=t.hi; alv[3]=t.lo;
        *reinterpret_cast<f16x4*>(&Ah[rr][k4]) = ahv;
        *reinterpret_cast<f16x4*>(&Al[rr][k4]) = alv;
      }
    }
    __syncthreads();
    if (k0 + 32 < K){
      #pragma unroll
      for (int e=0;e<4;e++)
        rw[e] = *reinterpret_cast<const uint4*>(Wbase + (size_t)(e*32)*K + k0 + 32);
      if constexpr (APRE){
        const u32* Abase = (const u32*)Ain + (size_t)(m0 + r0)*K + k4;
        #pragma unroll
        for (int e=0;e<4;e++)
          ra4[e] = *reinterpret_cast<const uint4*>(Abase + (size_t)(e*32)*K + k0 + 32);
      } else {
        const float* Abase = (const float*)Ain + (size_t)(m0 + r0)*K + k4;
        #pragma unroll
        for (int e=0;e<4;e++)
          raf[e] = *reinterpret_cast<const float4*>(Abase + (size_t)(e*32)*K + k0 + 32);
      }
    }
    f16x8 a_h[4], a_l[4], w_h[4], w_l[4];
    #pragma unroll
    for (int i=0;i<4;i++){
      int row = wr*64 + i*16 + fm;
      a_h[i] = *reinterpret_cast<const f16x8*>(&Ah[row][fg*8]);
      a_l[i] = *reinterpret_cast<const f16x8*>(&Al[row][fg*8]);
    }
    #pragma unroll
    for (int j=0;j<4;j++){
      int row = wc*64 + j*16 + fm;
      w_h[j] = *reinterpret_cast<const f16x8*>(&Wh[row][fg*8]);
      w_l[j] = *reinterpret_cast<const f16x8*>(&Wl[row][fg*8]);
    }
    #pragma unroll
    for (int i=0;i<4;i++)
      #pragma unroll
      for (int j=0;j<4;j++){
        acc[i][j] = __builtin_amdgcn_mfma_f32_16x16x32_f16(a_h[i], w_h[j], acc[i][j], 0, 0, 0);
        acc[i][j] = __builtin_amdgcn_mfma_f32_16x16x32_f16(a_h[i], w_l[j], acc[i][j], 0, 0, 0);
        acc[i][j] = __builtin_amdgcn_mfma_f32_16x16x32_f16(a_l[i], w_h[j], acc[i][j], 0, 0, 0);
      }
    __syncthreads();
  }
  #pragma unroll
  for (int i=0;i<4;i++){
    #pragma unroll
    for (int r=0;r<4;r++){
      int row = m0 + wr*64 + i*16 + fg*4 + r;
      #pragma unroll
      for (int j=0;j<4;j++){
        int col = n0 + wc*64 + j*16 + fm;
        float v = acc[i][j][r] + bias[col];
        if (ACT == 1) v = 0.5f*v*(1.0f + erff(v*0.70710678118654752f));  // exact gelu
        if constexpr (OSPLIT) ((u32*)Cout)[(size_t)row*N + col] = pack2(v);
        else                  ((float*)Cout)[(size_t)row*N + col] = v;
      }
    }
  }
}

// ---------------- MFMA attention scores: sc = Qs @ K^T (128x128 tiles) ----------------
// qkv is packed split-pairs (Q pre-scaled by 0.125 via weight fold). Output packed pairs.
#define SPAD 72
__global__ __launch_bounds__(256) void k_scores_mfma(const u32* __restrict__ qkv,
                                                     u32* __restrict__ sc, int bbase){
  __shared__ _Float16 Qh[128][SPAD], Ql[128][SPAD];
  __shared__ _Float16 Kh[128][SPAD], Kl[128][SPAD];
  const int tid = threadIdx.x;
  const int kt = blockIdx.x & 7;
  const int qt = (blockIdx.x >> 3) & 7;
  const int h  = (blockIdx.x >> 6) & 7;
  const int hb = (blockIdx.x >> 9) & 1;
  const int b  = bbase + hb;
  const int q0 = qt*128, k0 = kt*128;
  #pragma unroll
  for (int e=0;e<8;e++){
    int lin = e*256 + tid;
    int rr = lin >> 4;
    int c4 = (lin & 15) << 2;
    uint4 qv = *reinterpret_cast<const uint4*>(qkv + (size_t)(b*SS + q0+rr)*1536 + h*64 + c4);
    uint4 kv = *reinterpret_cast<const uint4*>(qkv + (size_t)(b*SS + k0+rr)*1536 + DD + h*64 + c4);
    uint2 hi, lo;
    unpk4(qv, hi, lo);
    *reinterpret_cast<uint2*>(&Qh[rr][c4]) = hi;
    *reinterpret_cast<uint2*>(&Ql[rr][c4]) = lo;
    unpk4(kv, hi, lo);
    *reinterpret_cast<uint2*>(&Kh[rr][c4]) = hi;
    *reinterpret_cast<uint2*>(&Kl[rr][c4]) = lo;
  }
  __syncthreads();
  const int lane = tid & 63, wid = tid >> 6;
  const int wr = wid >> 1, wc = wid & 1;
  const int fm = lane & 15, fg = lane >> 4;
  f32x4 acc[4][4];
  #pragma unroll
  for (int i=0;i<4;i++)
    #pragma unroll
    for (int j=0;j<4;j++) acc[i][j] = (f32x4){0.0f,0.0f,0.0f,0.0f};
  #pragma unroll
  for (int ks=0; ks<2; ks++){
    f16x8 ah[4], al[4], bh[4], bl[4];
    #pragma unroll
    for (int i=0;i<4;i++){
      int row = wr*64 + i*16 + fm;
      ah[i] = *reinterpret_cast<const f16x8*>(&Qh[row][ks*32 + fg*8]);
      al[i] = *reinterpret_cast<const f16x8*>(&Ql[row][ks*32 + fg*8]);
    }
    #pragma unroll
    for (int j=0;j<4;j++){
      int row = wc*64 + j*16 + fm;
      bh[j] = *reinterpret_cast<const f16x8*>(&Kh[row][ks*32 + fg*8]);
      bl[j] = *reinterpret_cast<const f16x8*>(&Kl[row][ks*32 + fg*8]);
    }
    #pragma unroll
    for (int i=0;i<4;i++)
      #pragma unroll
      for (int j=0;j<4;j++){
        acc[i][j] = __builtin_amdgcn_mfma_f32_16x16x32_f16(ah[i], bh[j], acc[i][j], 0, 0, 0);
        acc[i][j] = __builtin_amdgcn_mfma_f32_16x16x32_f16(ah[i], bl[j], acc[i][j], 0, 0, 0);
        acc[i][j] = __builtin_amdgcn_mfma_f32_16x16x32_f16(al[i], bh[j], acc[i][j], 0, 0, 0);
      }
  }
  u32* out = sc + (size_t)(hb*HH + h)*SS*SS;
  #pragma unroll
  for (int i=0;i<4;i++){
    #pragma unroll
    for (int r=0;r<4;r++){
      int row = q0 + wr*64 + i*16 + fg*4 + r;
      #pragma unroll
      for (int j=0;j<4;j++){
        int col = k0 + wc*64 + j*16 + fm;
        out[(size_t)row*SS + col] = pack2(acc[i][j][r]);
      }
    }
  }
}

// ---------------- MFMA PV: ctx[:, h*64..] = P @ V (128q x 64d tiles, BK=64) ----------------
// P is f16 plane (written by softmax); V packed pairs. 2 MFMA per fragment pair.
__global__ __launch_bounds__(256) void k_pv_mfma(const u32* __restrict__ sc,
                                                 const u32* __restrict__ qkv,
                                                 float* __restrict__ ctx, int bbase){
  __shared__ _Float16 Ph[128][SPAD];
  __shared__ _Float16 Vh[64][SPAD],  Vl[64][SPAD];
  const int tid = threadIdx.x;
  const int qt = blockIdx.x & 7;
  const int h  = (blockIdx.x >> 3) & 7;
  const int hb = (blockIdx.x >> 6) & 1;
  const int b  = bbase + hb;
  const int q0 = qt*128;
  const u16* Pb = (const u16*)(sc + (size_t)(hb*HH + h)*SS*SS);
  const int lane = tid & 63, wid = tid >> 6;
  const int wr = wid >> 1, wc = wid & 1;      // wave tile: 64 rows x 32 cols
  const int fm = lane & 15, fg = lane >> 4;
  const int pr0 = tid >> 4;                   // P staging: rows pr0 + 16e
  const int pc4 = (tid & 15) << 2;
  const int vd  = tid & 63;                   // V staging: dim
  const int vk0 = tid >> 6;                   // V staging: k = vk0 + 4e
  const u16* Pbase = Pb + (size_t)(q0 + pr0)*2*SS + pc4;
  const u32* Vbase = qkv + (size_t)(b*SS + vk0)*1536 + 1024 + h*64 + vd;
  f32x4 acc[4][2];
  #pragma unroll
  for (int i=0;i<4;i++){ acc[i][0] = (f32x4){0,0,0,0}; acc[i][1] = (f32x4){0,0,0,0}; }

  uint2 rp[8];
  u32   rv[16];
  #pragma unroll
  for (int e=0;e<8;e++)  rp[e] = *reinterpret_cast<const uint2*>(Pbase + (size_t)(e*16)*2*SS);
  #pragma unroll
  for (int e=0;e<16;e++) rv[e] = Vbase[(size_t)(e*4)*1536];

  for (int kk0=0; kk0<SS; kk0+=64){
    #pragma unroll
    for (int e=0;e<8;e++){
      int rr = pr0 + e*16;
      *reinterpret_cast<uint2*>(&Ph[rr][pc4]) = rp[e];   // f16 bits verbatim
    }
    #pragma unroll
    for (int e=0;e<16;e++){
      int k = vk0 + e*4;
      u32 w = rv[e];
      f16u thi, tlo; thi.u = (u16)w; tlo.u = (u16)(w >> 16);
      Vh[vd][k] = thi.f;
      Vl[vd][k] = tlo.f;
    }
    __syncthreads();
    if (kk0 + 64 < SS){
      #pragma unroll
      for (int e=0;e<8;e++)
        rp[e] = *reinterpret_cast<const uint2*>(Pbase + (size_t)(e*16)*2*SS + kk0 + 64);
      #pragma unroll
      for (int e=0;e<16;e++)
        rv[e] = Vbase[(size_t)(kk0 + 64 + e*4)*1536];
    }
    #pragma unroll
    for (int ks=0; ks<2; ks++){
      f16x8 ah[4], bh[2], bl[2];
      #pragma unroll
      for (int i=0;i<4;i++){
        int row = wr*64 + i*16 + fm;
        ah[i] = *reinterpret_cast<const f16x8*>(&Ph[row][ks*32 + fg*8]);
      }
      #pragma unroll
      for (int j=0;j<2;j++){
        int row = wc*32 + j*16 + fm;
        bh[j] = *reinterpret_cast<const f16x8*>(&Vh[row][ks*32 + fg*8]);
        bl[j] = *reinterpret_cast<const f16x8*>(&Vl[row][ks*32 + fg*8]);
      }
      #pragma unroll
      for (int i=0;i<4;i++)
        #pragma unroll
        for (int j=0;j<2;j++){
          acc[i][j] = __builtin_amdgcn_mfma_f32_16x16x32_f16(ah[i], bh[j], acc[i][j], 0, 0, 0);
          acc[i][j] = __builtin_amdgcn_mfma_f32_16x16x32_f16(ah[i], bl[j], acc[i][j], 0, 0, 0);
        }
    }
    __syncthreads();
  }
  #pragma unroll
  for (int i=0;i<4;i++){
    #pragma unroll
    for (int r=0;r<4;r++){
      int row = q0 + wr*64 + i*16 + fg*4 + r;
      #pragma unroll
      for (int j=0;j<2;j++){
        int col = wc*32 + j*16 + fm;
        ctx[(size_t)(b*SS + row)*DD + h*64 + col] = acc[i][j][r];
      }
    }
  }
}

// ---------------- persistent LSTM: 256 blocks = 4 batches x 64 chunks(8 dims) ----------------
// Transport: R4-verified packed {tag|h} 64-bit relaxed agent-scope atomics.
// NEW structure: wave-local gate combine (wave w owns dims {2w,2w+1}; lane =
// {di(1b), gate(2b), ks(3b)}); 4 intra-wave shfls replace the gl-LDS + 2nd
// barrier + serial tid<8 combine. hsh double-buffered so ONE barrier/step is
// safe. Cross-step poll prefetch: t+1's poll loads issue right after the
// barrier and their latency hides under gemv+combine.
__global__ __launch_bounds__(256) void k_lstm(const float* __restrict__ gates_in,
                                              const float* __restrict__ w_hh,
                                              unsigned long long* __restrict__ hpack){
  __shared__ float hsh[2][DD];
  const int b = blockIdx.x >> 6;
  const int chunk = blockIdx.x & 63;
  const int d0 = chunk*8;
  const int tid = threadIdx.x;
  const int wave = tid >> 6;
  const int lane = tid & 63;
  const int diw = lane >> 5;          // 0..1 : which of the wave's 2 dims
  const int g   = (lane >> 3) & 3;    // gate (0=i,1=f,2=g,3=o)
  const int ks  = lane & 7;           // k-slice: k = j*8 + ks
  const int dim = wave*2 + diw;       // 0..7 within chunk
  const int src0 = diw*32;            // base lane of this dim's gate group
  float w[64];
  {
    const float* wrow = w_hh + (size_t)(g*DD + d0 + dim)*DD;
    #pragma unroll
    for (int j=0;j<64;j++) w[j] = wrow[j*8 + ks];
  }
  float c = 0.0f;
  const float* gbase = gates_in + (size_t)(b*SS)*(4*DD) + g*DD + d0 + dim;
  // prefetch step-0 entries (memset tags = 0 -> instant hit)
  unsigned long long p0 = __hip_atomic_load(hpack + (size_t)b*DD + tid,
                                            __ATOMIC_RELAXED, __HIP_MEMORY_SCOPE_AGENT);
  unsigned long long p1 = __hip_atomic_load(hpack + (size_t)b*DD + tid + 256,
                                            __ATOMIC_RELAXED, __HIP_MEMORY_SCOPE_AGENT);
  for (int t=0; t<SS; ++t){
    float gv = 0.0f;
    if (ks == 0) gv = gbase[(size_t)t*(4*DD)];
    const unsigned long long exp_tag = (unsigned long long)t;
    unsigned long long* hp = hpack + (size_t)(t*BB + b)*DD;
    while ((p0 >> 32) != exp_tag || (p1 >> 32) != exp_tag){
      if ((p0 >> 32) != exp_tag)
        p0 = __hip_atomic_load(hp + tid,       __ATOMIC_RELAXED, __HIP_MEMORY_SCOPE_AGENT);
      if ((p1 >> 32) != exp_tag)
        p1 = __hip_atomic_load(hp + tid + 256, __ATOMIC_RELAXED, __HIP_MEMORY_SCOPE_AGENT);
    }
    float* hs = hsh[t & 1];
    union { unsigned int u; float f; } u0, u1;
    u0.u = (unsigned int)p0;
    u1.u = (unsigned int)p1;
    hs[tid]       = u0.f;
    hs[tid + 256] = u1.f;
    __syncthreads();
    if (t + 1 < SS){   // cross-step poll prefetch (latency hides under compute)
      unsigned long long* hq = hpack + (size_t)((t+1)*BB + b)*DD;
      p0 = __hip_atomic_load(hq + tid,       __ATOMIC_RELAXED, __HIP_MEMORY_SCOPE_AGENT);
      p1 = __hip_atomic_load(hq + tid + 256, __ATOMIC_RELAXED, __HIP_MEMORY_SCOPE_AGENT);
    }
    float a0=0.0f, a1=0.0f, a2=0.0f, a3=0.0f;
    #pragma unroll
    for (int j=0;j<64;j+=4){
      a0 += w[j+0]*hs[(j+0)*8 + ks];
      a1 += w[j+1]*hs[(j+1)*8 + ks];
      a2 += w[j+2]*hs[(j+2)*8 + ks];
      a3 += w[j+3]*hs[(j+3)*8 + ks];
    }
    float acc = (a0+a1)+(a2+a3);
    acc += __shfl_down(acc, 4, 8);
    acc += __shfl_down(acc, 2, 8);
    acc += __shfl_down(acc, 1, 8);
    // ks==0 lanes hold the full gate pre-activation; activate (others garbage, unused)
    float v = acc + gv;
    float gval = (g == 2) ? ftanh(v) : fsig(v);
    // wave-local gather of the 4 gates for this dim
    float gi = __shfl(gval, src0 + 0);
    float gf = __shfl(gval, src0 + 8);
    float gg = __shfl(gval, src0 + 16);
    float go = __shfl(gval, src0 + 24);
    c = gf*c + gi*gg;                  // redundant across the 32-lane half (identical)
    float h = go*ftanh(c);
    if (lane == src0){                 // 2 stores per wave, issued wave-locally
      union { float f; unsigned int u; } hu; hu.f = h;
      unsigned long long pk = ((unsigned long long)(unsigned int)(t+1) << 32)
                            | (unsigned long long)hu.u;
      __hip_atomic_store(&hpack[(size_t)((t+1)*BB + b)*DD + d0 + dim], pk,
                         __ATOMIC_RELAXED, __HIP_MEMORY_SCOPE_AGENT);
    }
  }
}

__global__ void k_resid(float* __restrict__ x, const unsigned long long* __restrict__ hpack){
  int idx = blockIdx.x*256 + threadIdx.x;
  if (idx >= NT*DD) return;
  int d = idx & (DD-1);
  int n = idx >> 9;
  int s = n & (SS-1);
  int b = n >> 10;
  union { unsigned int u; float f; } hu;
  hu.u = (unsigned int)hpack[(size_t)((s+1)*BB + b)*DD + d];
  x[idx] += hu.f;
}

// softmax: reads packed score pairs, writes P as f16 plane (in-place, half-width)
// + accumulates head-average into d_out attn region. 4 waves x 2 heads, 1 barrier.
__global__ __launch_bounds__(256) void k_softmax(u32* __restrict__ sc,
                                                 float* __restrict__ attn_out,
                                                 int l, int bbase){
  __shared__ float avgw[4][SS];   // per-wave partial head sums (16 KB)
  const int tid = threadIdx.x;
  const int q  = blockIdx.x & (SS-1);
  const int hb = blockIdx.x >> 10;
  const int b = bbase + hb;
  const int wave = tid >> 6, lane = tid & 63;
  #pragma unroll
  for (int j=0;j<16;j++) avgw[wave][j*64 + lane] = 0.0f;
  #pragma unroll
  for (int hi=0; hi<2; hi++){
    int h = wave + hi*4;
    u32* row = sc + (size_t)(hb*HH + h)*SS*SS + (size_t)q*SS;
    float v[16];
    float m = -1e30f;
    #pragma unroll
    for (int j=0;j<16;j++){ v[j] = unpack2f(row[j*64 + lane]); m = fmaxf(m, v[j]); }
    #pragma unroll
    for (int o=32;o>0;o>>=1) m = fmaxf(m, __shfl_xor(m, o));
    float s = 0.0f;
    #pragma unroll
    for (int j=0;j<16;j++){ v[j] = __expf(v[j] - m); s += v[j]; }
    #pragma unroll
    for (int o=32;o>0;o>>=1) s += __shfl_xor(s, o);
    float inv = __builtin_amdgcn_rcpf(s);
    u16* p16 = (u16*)row;
    #pragma unroll
    for (int j=0;j<16;j++){
      float p = v[j]*inv;
      p16[j*64 + lane] = f2b((_Float16)p);
      avgw[wave][j*64 + lane] += p;
    }
  }
  __syncthreads();
  float* ao = attn_out + (size_t)((l*BB + b)*SS + q)*SS;
  for (int j=tid;j<SS;j+=256)
    ao[j] = (avgw[0][j]+avgw[1][j]+avgw[2][j]+avgw[3][j])*0.125f;
}

// ---------------- LayerNorm: out = LN(x (+ y)) * g + b ----------------
__global__ __launch_bounds__(64) void k_ln(const float* __restrict__ x,
                                           const float* __restrict__ y,
                                           const float* __restrict__ g,
                                           const float* __restrict__ bta,
                                           float* __restrict__ out){
  const int n = blockIdx.x;
  const int tid = threadIdx.x;
  float v[8];
  float s = 0.0f, sq = 0.0f;
  #pragma unroll
  for (int j=0;j<8;j++){
    int d = j*64 + tid;
    float a = x[(size_t)n*DD + d];
    if (y) a += y[(size_t)n*DD + d];
    v[j] = a; s += a; sq += a*a;
  }
  #pragma unroll
  for (int o=32;o>0;o>>=1){ s += __shfl_xor(s, o); sq += __shfl_xor(sq, o); }
  float mean = s*(1.0f/DD);
  float var = sq*(1.0f/DD) - mean*mean;
  float rstd = rsqrtf(var + EPSF);
  #pragma unroll
  for (int j=0;j<8;j++){
    int d = j*64 + tid;
    out[(size_t)n*DD + d] = (v[j]-mean)*rstd*g[d] + bta[d];
  }
}

extern "C" void kernel_launch(void* const* d_in, const int* in_sizes, int n_in,
                              void* d_out, int out_size, void* d_ws, size_t ws_size,
                              hipStream_t stream){
  const int*   src    = (const int*)  d_in[0];
  const float* emb    = (const float*)d_in[1];
  const float* conv_w = (const float*)d_in[2];
  const float* conv_b = (const float*)d_in[3];
  const float* bn_g   = (const float*)d_in[4];
  const float* bn_b   = (const float*)d_in[5];
  const float* bn_m   = (const float*)d_in[6];
  const float* bn_v   = (const float*)d_in[7];
  const float* w_ih   = (const float*)d_in[8];
  const float* w_hh   = (const float*)d_in[9];
  const float* b_ih   = (const float*)d_in[10];
  const float* b_hh   = (const float*)d_in[11];
  const float* in_w   = (const float*)d_in[12];
  const float* in_b   = (const float*)d_in[13];
  const float* out_w  = (const float*)d_in[14];
  const float* out_b  = (const float*)d_in[15];
  const float* ln1_g  = (const float*)d_in[16];
  const float* ln1_b  = (const float*)d_in[17];
  const float* w1     = (const float*)d_in[18];
  const float* b1     = (const float*)d_in[19];
  const float* w2     = (const float*)d_in[20];
  const float* b2     = (const float*)d_in[21];
  const float* ln2_g  = (const float*)d_in[22];
  const float* ln2_b  = (const float*)d_in[23];
  const float* fin_g  = (const float*)d_in[24];
  const float* fin_b  = (const float*)d_in[25];

  float* ws    = (float*)d_ws;
  float* x0    = ws + O_X0;
  float* x1    = ws + O_X1;
  float* ctx   = ws + O_CTX;
  float* qkv   = ws + O_QKV;     // packed u32 pairs
  float* big   = ws + O_BIG;
  float* bsum  = ws + O_BSUM;
  unsigned long long* hpack = (unsigned long long*)(big + 8388608);

  u32*   aconv = (u32*)(ws + O_HSEQ);               // 2,097,152 packed activations
  float* qbias = ws + O_HSEQ + 2097152;             // 1536 scaled qkv bias
  u32*   qkvp  = (u32*)qkv;
  u32*   scp   = (u32*)big;                         // scores as packed pairs
  u32*   wsg   = (u32*)(big + 13000000);            // gates W scratch (1M, clear of hpack)
  u32*   wsa   = (u32*)big;                         // qkv/proj W scratch (at big+0)
  u32*   ws1   = (u32*)(big + 8500000);             // ffn1 W scratch
  u32*   ws2   = (u32*)(big + 9500000);             // ffn2 W scratch

  float* outx  = (float*)d_out;            // [B,S,D]
  float* attn  = outx + (size_t)NT*DD;     // [L,B,S,S]

  hipMemsetAsync(hpack, 0, (size_t)(SS+1)*BB*DD*sizeof(unsigned long long), stream);

  const int eb = (NT*DD)/256;
  k_embed<<<eb, 256, 0, stream>>>(src, emb, x0);
  k_conv <<<eb, 256, 0, stream>>>(x0, conv_w, conv_b, bn_g, bn_b, bn_m, bn_v, x1);
  k_bsum <<<8, 256, 0, stream>>>(b_ih, b_hh, bsum, 4*DD);

  // LSTM input precompute: gates = x1 @ w_ih^T + (b_ih + b_hh)
  k_asplit<<<2048, 256, 0, stream>>>(x1, aconv, NT*DD);
  k_wsplit<0><<<1024, 256, 0, stream>>>(w_ih, wsg, nullptr, nullptr, 2048*512, 512);
  k_gemm_mfma<0,1,0><<<(NT/128)*((4*DD)/128), 256, 0, stream>>>(
      aconv, wsg, bsum, big, NT, 4*DD, DD);
  k_lstm<<<256, 256, 0, stream>>>(big, w_hh, hpack);
  k_resid<<<eb, 256, 0, stream>>>(x1, hpack);

  float* cur = x1;
  float* tmp = x0;
  for (int l=0; l<LL; ++l){
    // qkv = cur @ in_w[l]^T + in_b[l]  (Q rows pre-scaled 0.125; packed output)
    k_asplit<<<2048, 256, 0, stream>>>(cur, aconv, NT*DD);
    k_wsplit<1><<<768, 256, 0, stream>>>(in_w + (size_t)l*1536*DD, wsa,
                                         in_b + (size_t)l*1536, qbias, 1536*512, 512);
    k_gemm_mfma<0,1,1><<<(NT/128)*(1536/128), 256, 0, stream>>>(
        aconv, wsa, qbias, qkvp, NT, 1536, DD);
    for (int bb2=0; bb2<2; ++bb2){
      int bbase = bb2*2;
      k_scores_mfma<<<1024, 256, 0, stream>>>(qkvp, scp, bbase);
      k_softmax    <<<2048, 256, 0, stream>>>(scp, attn, l, bbase);
      k_pv_mfma    <<<128,  256, 0, stream>>>(scp, qkvp, ctx, bbase);
    }
    // proj: tmp = ctx @ out_w[l]^T + out_b[l]   (A f32 path)
    k_wsplit<0><<<256, 256, 0, stream>>>(out_w + (size_t)l*DD*DD, wsa,
                                         nullptr, nullptr, 512*512, 512);
    k_gemm_mfma<0,0,0><<<(NT/128)*(DD/128), 256, 0, stream>>>(
        ctx, wsa, out_b + (size_t)l*DD, tmp, NT, DD, DD);
    k_ln<<<NT, 64, 0, stream>>>(cur, tmp, ln1_g + l*DD, ln1_b + l*DD, cur);
    // ffh = gelu(cur @ w1[l]^T + b1[l])  -> packed pairs in big[0..8.39M)
    k_asplit<<<2048, 256, 0, stream>>>(cur, aconv, NT*DD);
    k_wsplit<0><<<1024, 256, 0, stream>>>(w1 + (size_t)l*DFF*DD, ws1,
                                          nullptr, nullptr, 2048*512, 512);
    k_gemm_mfma<1,1,1><<<(NT/128)*(DFF/128), 256, 0, stream>>>(
        aconv, ws1, b1 + (size_t)l*DFF, (u32*)big, NT, DFF, DD);
    // tmp = ffh @ w2[l]^T + b2[l]   (A = packed ffh)
    k_wsplit<0><<<1024, 256, 0, stream>>>(w2 + (size_t)l*DD*DFF, ws2,
                                          nullptr, nullptr, 512*2048, 2048);
    k_gemm_mfma<0,1,0><<<(NT/128)*(DD/128), 256, 0, stream>>>(
        (u32*)big, ws2, b2 + (size_t)l*DD, tmp, NT, DD, DFF);
    k_ln<<<NT, 64, 0, stream>>>(cur, tmp, ln2_g + l*DD, ln2_b + l*DD, cur);
  }
  k_ln<<<NT, 64, 0, stream>>>(cur, nullptr, fin_g, fin_b, outx);
}

// Round 9
// 2775.190 us; speedup vs baseline: 1.3339x; 1.0530x over previous
//
#include <hip/hip_runtime.h>
#include <math.h>

#define DD 512
#define SS 1024
#define BB 4
#define HH 8
#define DFF 2048
#define LL 4
#define NT 4096           // BB*SS
#define EPSF 1e-5f

// ---------------- workspace layout (float elements) ----------------
#define O_X0    ((size_t)0)            // 2,097,152  emb+pe
#define O_X1    ((size_t)2097152)      // 2,097,152  conv out / current x
#define O_HSEQ  ((size_t)4194304)      // 2,099,200: packed activation scratch (+qbias tail)
#define O_CTX   ((size_t)6293504)      // 2,097,152 (ctx)
#define O_QKV   ((size_t)8390656)      // 6,291,456 (packed split-pairs)
#define O_BIG   ((size_t)14682112)     // 16,777,216 (gates 8.39M / hpack / scores / ffh / W-scratch)
#define O_BSUM  ((size_t)31459328)     // 2048

typedef unsigned int  u32;
typedef unsigned short u16;
typedef __attribute__((ext_vector_type(8))) _Float16 f16x8;
typedef __attribute__((ext_vector_type(4))) _Float16 f16x4;
typedef __attribute__((ext_vector_type(4))) float    f32x4;

// fast transcendentals: v_exp_f32 / v_rcp_f32 based (~1e-7 rel, saturating-safe)
__device__ __forceinline__ float fsig(float x){
  return __builtin_amdgcn_rcpf(1.0f + __expf(-x));
}
__device__ __forceinline__ float ftanh(float x){
  return 1.0f - 2.0f*__builtin_amdgcn_rcpf(1.0f + __expf(2.0f*x));
}
struct h2 { _Float16 hi, lo; };
__device__ __forceinline__ h2 split2(float v){
  h2 r; r.hi = (_Float16)v; r.lo = (_Float16)(v - (float)r.hi); return r;
}
union f16u { u16 u; _Float16 f; };
__device__ __forceinline__ float b2f(u16 b){ f16u t; t.u = b; return (float)t.f; }
__device__ __forceinline__ u16 f2b(_Float16 h){ f16u t; t.f = h; return t.u; }
// pack f32 -> {hi f16 (low16) | lo f16 (high16)}
__device__ __forceinline__ u32 pack2(float v){
  _Float16 hi = (_Float16)v;
  _Float16 lo = (_Float16)(v - (float)hi);
  return (u32)f2b(hi) | ((u32)f2b(lo) << 16);
}
__device__ __forceinline__ float unpack2f(u32 w){
  return b2f((u16)w) + b2f((u16)(w >> 16));
}

// ---------------- embedding + sinusoidal PE ----------------
__global__ void k_embed(const int* __restrict__ src, const float* __restrict__ emb,
                        float* __restrict__ x){
  int idx = blockIdx.x*256 + threadIdx.x;
  if (idx >= NT*DD) return;
  int d = idx & (DD-1);
  int n = idx >> 9;          // b*SS + s
  int s = n & (SS-1);
  int tok = src[n];
  int i2 = d & ~1;
  float div = expf(-(float)i2 * (9.210340371976184f/512.0f));  // ln(10000)/512
  float ang = (float)s * div;
  float pe = (d & 1) ? cosf(ang) : sinf(ang);
  x[idx] = emb[(size_t)tok*DD + d]*22.62741699796952f + pe;    // sqrt(512)
}

// ---------------- depthwise conv k=3 + BN(eval) + ReLU (+ packed copy) ----------------
__global__ void k_conv(const float* __restrict__ x, const float* __restrict__ cw,
                       const float* __restrict__ cb, const float* __restrict__ bg,
                       const float* __restrict__ bb, const float* __restrict__ bm,
                       const float* __restrict__ bv, float* __restrict__ y,
                       u32* __restrict__ yp){
  int idx = blockIdx.x*256 + threadIdx.x;
  if (idx >= NT*DD) return;
  int d = idx & (DD-1);
  int n = idx >> 9;
  int s = n & (SS-1);
  float acc = cb[d];
  if (s > 0)     acc += x[idx - DD]*cw[d*3+0];
  acc += x[idx]*cw[d*3+1];
  if (s < SS-1)  acc += x[idx + DD]*cw[d*3+2];
  float v = (acc - bm[d])*rsqrtf(bv[d]+EPSF)*bg[d] + bb[d];
  v = fmaxf(v, 0.0f);
  y[idx] = v;
  yp[idx] = pack2(v);
}

__global__ void k_bsum(const float* a, const float* b, float* o, int n){
  int i = blockIdx.x*256 + threadIdx.x;
  if (i < n) o[i] = a[i] + b[i];
}

// ---------------- weight pre-split: W f32 -> packed {hi|lo} u32 ----------------
// QSCALE: scale rows<512 by 0.125 (attention Q fold) and emit scaled bias copy.
template<int QSCALE>
__global__ void k_wsplit(const float* __restrict__ W, u32* __restrict__ Wp,
                         const float* __restrict__ bias_in, float* __restrict__ bias_out,
                         int total, int K){
  int i = blockIdx.x*1024 + threadIdx.x*4;
  if (i < total){
    float4 v = *reinterpret_cast<const float4*>(W + i);
    float s = 1.0f;
    if (QSCALE){ int row = i / K; if (row < 512) s = 0.125f; }
    uint4 o;
    o.x = pack2(v.x*s); o.y = pack2(v.y*s); o.z = pack2(v.z*s); o.w = pack2(v.w*s);
    *reinterpret_cast<uint4*>(Wp + i) = o;
  }
  if (QSCALE && blockIdx.x == 0){
    for (int j = threadIdx.x; j < 1536; j += 256){
      float bv = bias_in[j];
      bias_out[j] = (j < 512) ? bv*0.125f : bv;
    }
  }
}

// unpack helper for staging: 4 packed elems -> hi u32x2 + lo u32x2 (2 halves each)
__device__ __forceinline__ void unpk4(uint4 w, uint2& hi, uint2& lo){
  hi.x = (w.x & 0xffffu) | (w.y << 16);
  hi.y = (w.z & 0xffffu) | (w.w << 16);
  lo.x = (w.x >> 16) | (w.y & 0xffff0000u);
  lo.y = (w.z >> 16) | (w.w & 0xffff0000u);
}

// ---------------- MFMA split-f16 GEMM: C[M,N] = A[M,K] @ W[N,K]^T + bias ----------------
// W always pre-split packed; A either packed (APRE=1) or f32 (APRE=0).
// OSPLIT=1: C written as packed split-pairs.
#define BKP 40   // padded K stride in halves
template<int ACT, int APRE, int OSPLIT>
__global__ __launch_bounds__(256) void k_gemm_mfma(const void* __restrict__ Ain,
                                                   const u32* __restrict__ Wp,
                                                   const float* __restrict__ bias,
                                                   void* __restrict__ Cout,
                                                   int M, int N, int K){
  __shared__ _Float16 Ah[128][BKP];
  __shared__ _Float16 Al[128][BKP];
  __shared__ _Float16 Wh[128][BKP];
  __shared__ _Float16 Wl[128][BKP];
  const int tid = threadIdx.x;
  const int nbx = N >> 7;
  const int bx = blockIdx.x % nbx;
  const int by = blockIdx.x / nbx;
  const int m0 = by << 7, n0 = bx << 7;
  const int lane = tid & 63;
  const int wid  = tid >> 6;
  const int wr = wid >> 1, wc = wid & 1;
  const int fm = lane & 15, fg = lane >> 4;
  const int r0 = tid >> 3;              // staging row base (row = r0 + 32e)
  const int k4 = (tid & 7) << 2;        // staging k offset within tile
  const u32* Wbase = Wp + (size_t)(n0 + r0)*K + k4;

  f32x4 acc[4][4];
  #pragma unroll
  for (int i=0;i<4;i++)
    #pragma unroll
    for (int j=0;j<4;j++) acc[i][j] = (f32x4){0.0f,0.0f,0.0f,0.0f};

  uint4 rw[4];
  uint4 ra4[4];
  float4 raf[4];
  #pragma unroll
  for (int e=0;e<4;e++)
    rw[e] = *reinterpret_cast<const uint4*>(Wbase + (size_t)(e*32)*K);
  if constexpr (APRE){
    const u32* Abase = (const u32*)Ain + (size_t)(m0 + r0)*K + k4;
    #pragma unroll
    for (int e=0;e<4;e++)
      ra4[e] = *reinterpret_cast<const uint4*>(Abase + (size_t)(e*32)*K);
  } else {
    const float* Abase = (const float*)Ain + (size_t)(m0 + r0)*K + k4;
    #pragma unroll
    for (int e=0;e<4;e++)
      raf[e] = *reinterpret_cast<const float4*>(Abase + (size_t)(e*32)*K);
  }

  for (int k0 = 0; k0 < K; k0 += 32){
    #pragma unroll
    for (int e = 0; e < 4; ++e){
      int rr = r0 + e*32;
      uint2 hi, lo;
      unpk4(rw[e], hi, lo);
      *reinterpret_cast<uint2*>(&Wh[rr][k4]) = hi;
      *reinterpret_cast<uint2*>(&Wl[rr][k4]) = lo;
      if constexpr (APRE){
        unpk4(ra4[e], hi, lo);
        *reinterpret_cast<uint2*>(&Ah[rr][k4]) = hi;
        *reinterpret_cast<uint2*>(&Al[rr][k4]) = lo;
      } else {
        f16x4 ahv, alv;
        h2 t;
        t = split2(raf[e].x); ahv[0]=t.hi; alv[0]=t.lo;
        t = split2(raf[e].y); ahv[1]=t.hi; alv[1]=t.lo;
        t = split2(raf[e].z); ahv[2]=t.hi; alv[2]=t.lo;
        t = split2(raf[e].w); ahv[3]=t.hi; alv[3]=t.lo;
        *reinterpret_cast<f16x4*>(&Ah[rr][k4]) = ahv;
        *reinterpret_cast<f16x4*>(&Al[rr][k4]) = alv;
      }
    }
    __syncthreads();
    if (k0 + 32 < K){
      #pragma unroll
      for (int e=0;e<4;e++)
        rw[e] = *reinterpret_cast<const uint4*>(Wbase + (size_t)(e*32)*K + k0 + 32);
      if constexpr (APRE){
        const u32* Abase = (const u32*)Ain + (size_t)(m0 + r0)*K + k4;
        #pragma unroll
        for (int e=0;e<4;e++)
          ra4[e] = *reinterpret_cast<const uint4*>(Abase + (size_t)(e*32)*K + k0 + 32);
      } else {
        const float* Abase = (const float*)Ain + (size_t)(m0 + r0)*K + k4;
        #pragma unroll
        for (int e=0;e<4;e++)
          raf[e] = *reinterpret_cast<const float4*>(Abase + (size_t)(e*32)*K + k0 + 32);
      }
    }
    f16x8 a_h[4], a_l[4], w_h[4], w_l[4];
    #pragma unroll
    for (int i=0;i<4;i++){
      int row = wr*64 + i*16 + fm;
      a_h[i] = *reinterpret_cast<const f16x8*>(&Ah[row][fg*8]);
      a_l[i] = *reinterpret_cast<const f16x8*>(&Al[row][fg*8]);
    }
    #pragma unroll
    for (int j=0;j<4;j++){
      int row = wc*64 + j*16 + fm;
      w_h[j] = *reinterpret_cast<const f16x8*>(&Wh[row][fg*8]);
      w_l[j] = *reinterpret_cast<const f16x8*>(&Wl[row][fg*8]);
    }
    #pragma unroll
    for (int i=0;i<4;i++)
      #pragma unroll
      for (int j=0;j<4;j++){
        acc[i][j] = __builtin_amdgcn_mfma_f32_16x16x32_f16(a_h[i], w_h[j], acc[i][j], 0, 0, 0);
        acc[i][j] = __builtin_amdgcn_mfma_f32_16x16x32_f16(a_h[i], w_l[j], acc[i][j], 0, 0, 0);
        acc[i][j] = __builtin_amdgcn_mfma_f32_16x16x32_f16(a_l[i], w_h[j], acc[i][j], 0, 0, 0);
      }
    __syncthreads();
  }
  #pragma unroll
  for (int i=0;i<4;i++){
    #pragma unroll
    for (int r=0;r<4;r++){
      int row = m0 + wr*64 + i*16 + fg*4 + r;
      #pragma unroll
      for (int j=0;j<4;j++){
        int col = n0 + wc*64 + j*16 + fm;
        float v = acc[i][j][r] + bias[col];
        if (ACT == 1) v = 0.5f*v*(1.0f + erff(v*0.70710678118654752f));  // exact gelu
        if constexpr (OSPLIT) ((u32*)Cout)[(size_t)row*N + col] = pack2(v);
        else                  ((float*)Cout)[(size_t)row*N + col] = v;
      }
    }
  }
}

// ---------------- MFMA attention scores: sc = Qs @ K^T (128x128 tiles) ----------------
// qkv is packed split-pairs (Q pre-scaled by 0.125 via weight fold). Output packed pairs.
#define SPAD 72
__global__ __launch_bounds__(256) void k_scores_mfma(const u32* __restrict__ qkv,
                                                     u32* __restrict__ sc, int bbase){
  __shared__ _Float16 Qh[128][SPAD], Ql[128][SPAD];
  __shared__ _Float16 Kh[128][SPAD], Kl[128][SPAD];
  const int tid = threadIdx.x;
  const int kt = blockIdx.x & 7;
  const int qt = (blockIdx.x >> 3) & 7;
  const int h  = (blockIdx.x >> 6) & 7;
  const int hb = (blockIdx.x >> 9) & 1;
  const int b  = bbase + hb;
  const int q0 = qt*128, k0 = kt*128;
  #pragma unroll
  for (int e=0;e<8;e++){
    int lin = e*256 + tid;
    int rr = lin >> 4;
    int c4 = (lin & 15) << 2;
    uint4 qv = *reinterpret_cast<const uint4*>(qkv + (size_t)(b*SS + q0+rr)*1536 + h*64 + c4);
    uint4 kv = *reinterpret_cast<const uint4*>(qkv + (size_t)(b*SS + k0+rr)*1536 + DD + h*64 + c4);
    uint2 hi, lo;
    unpk4(qv, hi, lo);
    *reinterpret_cast<uint2*>(&Qh[rr][c4]) = hi;
    *reinterpret_cast<uint2*>(&Ql[rr][c4]) = lo;
    unpk4(kv, hi, lo);
    *reinterpret_cast<uint2*>(&Kh[rr][c4]) = hi;
    *reinterpret_cast<uint2*>(&Kl[rr][c4]) = lo;
  }
  __syncthreads();
  const int lane = tid & 63, wid = tid >> 6;
  const int wr = wid >> 1, wc = wid & 1;
  const int fm = lane & 15, fg = lane >> 4;
  f32x4 acc[4][4];
  #pragma unroll
  for (int i=0;i<4;i++)
    #pragma unroll
    for (int j=0;j<4;j++) acc[i][j] = (f32x4){0.0f,0.0f,0.0f,0.0f};
  #pragma unroll
  for (int ks=0; ks<2; ks++){
    f16x8 ah[4], al[4], bh[4], bl[4];
    #pragma unroll
    for (int i=0;i<4;i++){
      int row = wr*64 + i*16 + fm;
      ah[i] = *reinterpret_cast<const f16x8*>(&Qh[row][ks*32 + fg*8]);
      al[i] = *reinterpret_cast<const f16x8*>(&Ql[row][ks*32 + fg*8]);
    }
    #pragma unroll
    for (int j=0;j<4;j++){
      int row = wc*64 + j*16 + fm;
      bh[j] = *reinterpret_cast<const f16x8*>(&Kh[row][ks*32 + fg*8]);
      bl[j] = *reinterpret_cast<const f16x8*>(&Kl[row][ks*32 + fg*8]);
    }
    #pragma unroll
    for (int i=0;i<4;i++)
      #pragma unroll
      for (int j=0;j<4;j++){
        acc[i][j] = __builtin_amdgcn_mfma_f32_16x16x32_f16(ah[i], bh[j], acc[i][j], 0, 0, 0);
        acc[i][j] = __builtin_amdgcn_mfma_f32_16x16x32_f16(ah[i], bl[j], acc[i][j], 0, 0, 0);
        acc[i][j] = __builtin_amdgcn_mfma_f32_16x16x32_f16(al[i], bh[j], acc[i][j], 0, 0, 0);
      }
  }
  u32* out = sc + (size_t)(hb*HH + h)*SS*SS;
  #pragma unroll
  for (int i=0;i<4;i++){
    #pragma unroll
    for (int r=0;r<4;r++){
      int row = q0 + wr*64 + i*16 + fg*4 + r;
      #pragma unroll
      for (int j=0;j<4;j++){
        int col = k0 + wc*64 + j*16 + fm;
        out[(size_t)row*SS + col] = pack2(acc[i][j][r]);
      }
    }
  }
}

// ---------------- MFMA PV: ctx[:, h*64..] = P @ V (64q x 64d tiles, BK=64) ----------------
// P is f16 plane (written by softmax); V packed pairs. 256 blocks/dispatch (full CU use).
__global__ __launch_bounds__(256) void k_pv_mfma(const u32* __restrict__ sc,
                                                 const u32* __restrict__ qkv,
                                                 float* __restrict__ ctx, int bbase){
  __shared__ _Float16 Ph[64][SPAD];
  __shared__ _Float16 Vh[64][SPAD],  Vl[64][SPAD];
  const int tid = threadIdx.x;
  const int qt = blockIdx.x & 15;
  const int h  = (blockIdx.x >> 4) & 7;
  const int hb = (blockIdx.x >> 7) & 1;
  const int b  = bbase + hb;
  const int q0 = qt*64;
  const u16* Pb = (const u16*)(sc + (size_t)(hb*HH + h)*SS*SS);
  const int lane = tid & 63, wid = tid >> 6;
  const int wr = wid >> 1, wc = wid & 1;      // wave tile: 32 rows x 32 cols
  const int fm = lane & 15, fg = lane >> 4;
  const int pr0 = tid >> 4;                   // P staging: rows pr0 + 16e (e<4)
  const int pc4 = (tid & 15) << 2;
  const int vd  = tid & 63;                   // V staging: dim
  const int vk0 = tid >> 6;                   // V staging: k = vk0 + 4e
  const u16* Pbase = Pb + (size_t)(q0 + pr0)*2*SS + pc4;
  const u32* Vbase = qkv + (size_t)(b*SS + vk0)*1536 + 1024 + h*64 + vd;
  f32x4 acc[2][2];
  #pragma unroll
  for (int i=0;i<2;i++){ acc[i][0] = (f32x4){0,0,0,0}; acc[i][1] = (f32x4){0,0,0,0}; }

  uint2 rp[4];
  u32   rv[16];
  #pragma unroll
  for (int e=0;e<4;e++)  rp[e] = *reinterpret_cast<const uint2*>(Pbase + (size_t)(e*16)*2*SS);
  #pragma unroll
  for (int e=0;e<16;e++) rv[e] = Vbase[(size_t)(e*4)*1536];

  for (int kk0=0; kk0<SS; kk0+=64){
    #pragma unroll
    for (int e=0;e<4;e++){
      int rr = pr0 + e*16;
      *reinterpret_cast<uint2*>(&Ph[rr][pc4]) = rp[e];   // f16 bits verbatim
    }
    #pragma unroll
    for (int e=0;e<16;e++){
      int k = vk0 + e*4;
      u32 w = rv[e];
      f16u thi, tlo; thi.u = (u16)w; tlo.u = (u16)(w >> 16);
      Vh[vd][k] = thi.f;
      Vl[vd][k] = tlo.f;
    }
    __syncthreads();
    if (kk0 + 64 < SS){
      #pragma unroll
      for (int e=0;e<4;e++)
        rp[e] = *reinterpret_cast<const uint2*>(Pbase + (size_t)(e*16)*2*SS + kk0 + 64);
      #pragma unroll
      for (int e=0;e<16;e++)
        rv[e] = Vbase[(size_t)(kk0 + 64 + e*4)*1536];
    }
    #pragma unroll
    for (int ks=0; ks<2; ks++){
      f16x8 ah[2], bh[2], bl[2];
      #pragma unroll
      for (int i=0;i<2;i++){
        int row = wr*32 + i*16 + fm;
        ah[i] = *reinterpret_cast<const f16x8*>(&Ph[row][ks*32 + fg*8]);
      }
      #pragma unroll
      for (int j=0;j<2;j++){
        int row = wc*32 + j*16 + fm;
        bh[j] = *reinterpret_cast<const f16x8*>(&Vh[row][ks*32 + fg*8]);
        bl[j] = *reinterpret_cast<const f16x8*>(&Vl[row][ks*32 + fg*8]);
      }
      #pragma unroll
      for (int i=0;i<2;i++)
        #pragma unroll
        for (int j=0;j<2;j++){
          acc[i][j] = __builtin_amdgcn_mfma_f32_16x16x32_f16(ah[i], bh[j], acc[i][j], 0, 0, 0);
          acc[i][j] = __builtin_amdgcn_mfma_f32_16x16x32_f16(ah[i], bl[j], acc[i][j], 0, 0, 0);
        }
    }
    __syncthreads();
  }
  #pragma unroll
  for (int i=0;i<2;i++){
    #pragma unroll
    for (int r=0;r<4;r++){
      int row = q0 + wr*32 + i*16 + fg*4 + r;
      #pragma unroll
      for (int j=0;j<2;j++){
        int col = wc*32 + j*16 + fm;
        ctx[(size_t)(b*SS + row)*DD + h*64 + col] = acc[i][j][r];
      }
    }
  }
}

// ---------------- persistent LSTM: 256 blocks = 4 batches x 64 chunks(8 dims) ----------------
// Transport: R4/R8-verified packed {tag|h} 64-bit relaxed agent-scope atomics.
// Wave-local gate combine; hsh double-buffered (1 barrier/step); cross-step poll
// prefetch. NEW: ks-major LDS layout hsh[8][68] -> gemv uses 16x ds_read_b128
// (conflict-free: 8 rows hit disjoint 4-bank groups; 8-fold lane broadcast).
__global__ __launch_bounds__(256) void k_lstm(const float* __restrict__ gates_in,
                                              const float* __restrict__ w_hh,
                                              unsigned long long* __restrict__ hpack){
  __shared__ float hsh[2][8][68];
  const int b = blockIdx.x >> 6;
  const int chunk = blockIdx.x & 63;
  const int d0 = chunk*8;
  const int tid = threadIdx.x;
  const int wave = tid >> 6;
  const int lane = tid & 63;
  const int diw = lane >> 5;          // 0..1 : which of the wave's 2 dims
  const int g   = (lane >> 3) & 3;    // gate (0=i,1=f,2=g,3=o)
  const int ks  = lane & 7;           // k-slice: k = j*8 + ks
  const int dim = wave*2 + diw;       // 0..7 within chunk
  const int src0 = diw*32;            // base lane of this dim's gate group
  float w[64];
  {
    const float* wrow = w_hh + (size_t)(g*DD + d0 + dim)*DD;
    #pragma unroll
    for (int j=0;j<64;j++) w[j] = wrow[j*8 + ks];
  }
  float c = 0.0f;
  const float* gbase = gates_in + (size_t)(b*SS)*(4*DD) + g*DD + d0 + dim;
  // prefetch step-0 entries (memset tags = 0 -> instant hit)
  unsigned long long p0 = __hip_atomic_load(hpack + (size_t)b*DD + tid,
                                            __ATOMIC_RELAXED, __HIP_MEMORY_SCOPE_AGENT);
  unsigned long long p1 = __hip_atomic_load(hpack + (size_t)b*DD + tid + 256,
                                            __ATOMIC_RELAXED, __HIP_MEMORY_SCOPE_AGENT);
  for (int t=0; t<SS; ++t){
    float gv = 0.0f;
    if (ks == 0) gv = gbase[(size_t)t*(4*DD)];
    const unsigned long long exp_tag = (unsigned long long)t;
    unsigned long long* hp = hpack + (size_t)(t*BB + b)*DD;
    while ((p0 >> 32) != exp_tag || (p1 >> 32) != exp_tag){
      if ((p0 >> 32) != exp_tag)
        p0 = __hip_atomic_load(hp + tid,       __ATOMIC_RELAXED, __HIP_MEMORY_SCOPE_AGENT);
      if ((p1 >> 32) != exp_tag)
        p1 = __hip_atomic_load(hp + tid + 256, __ATOMIC_RELAXED, __HIP_MEMORY_SCOPE_AGENT);
    }
    float (*hs)[68] = hsh[t & 1];
    union { unsigned int u; float f; } u0, u1;
    u0.u = (unsigned int)p0;
    u1.u = (unsigned int)p1;
    hs[tid & 7][tid >> 3]        = u0.f;   // dim = tid
    hs[tid & 7][(tid >> 3) + 32] = u1.f;   // dim = tid + 256
    __syncthreads();
    if (t + 1 < SS){   // cross-step poll prefetch (latency hides under compute)
      unsigned long long* hq = hpack + (size_t)((t+1)*BB + b)*DD;
      p0 = __hip_atomic_load(hq + tid,       __ATOMIC_RELAXED, __HIP_MEMORY_SCOPE_AGENT);
      p1 = __hip_atomic_load(hq + tid + 256, __ATOMIC_RELAXED, __HIP_MEMORY_SCOPE_AGENT);
    }
    float a0=0.0f, a1=0.0f, a2=0.0f, a3=0.0f;
    #pragma unroll
    for (int j=0;j<64;j+=4){
      float4 hv = *reinterpret_cast<const float4*>(&hs[ks][j]);
      a0 += w[j+0]*hv.x;
      a1 += w[j+1]*hv.y;
      a2 += w[j+2]*hv.z;
      a3 += w[j+3]*hv.w;
    }
    float acc = (a0+a1)+(a2+a3);
    acc += __shfl_down(acc, 4, 8);
    acc += __shfl_down(acc, 2, 8);
    acc += __shfl_down(acc, 1, 8);
    // ks==0 lanes hold the full gate pre-activation; activate (others garbage, unused)
    float v = acc + gv;
    float gval = (g == 2) ? ftanh(v) : fsig(v);
    // wave-local gather of the 4 gates for this dim
    float gi = __shfl(gval, src0 + 0);
    float gf = __shfl(gval, src0 + 8);
    float gg = __shfl(gval, src0 + 16);
    float go = __shfl(gval, src0 + 24);
    c = gf*c + gi*gg;                  // redundant across the 32-lane half (identical)
    float h = go*ftanh(c);
    if (lane == src0){                 // 2 stores per wave, issued wave-locally
      union { float f; unsigned int u; } hu; hu.f = h;
      unsigned long long pk = ((unsigned long long)(unsigned int)(t+1) << 32)
                            | (unsigned long long)hu.u;
      __hip_atomic_store(&hpack[(size_t)((t+1)*BB + b)*DD + d0 + dim], pk,
                         __ATOMIC_RELAXED, __HIP_MEMORY_SCOPE_AGENT);
    }
  }
}

__global__ void k_resid(float* __restrict__ x, const unsigned long long* __restrict__ hpack,
                        u32* __restrict__ xp){
  int idx = blockIdx.x*256 + threadIdx.x;
  if (idx >= NT*DD) return;
  int d = idx & (DD-1);
  int n = idx >> 9;
  int s = n & (SS-1);
  int b = n >> 10;
  union { unsigned int u; float f; } hu;
  hu.u = (unsigned int)hpack[(size_t)((s+1)*BB + b)*DD + d];
  float v = x[idx] + hu.f;
  x[idx] = v;
  xp[idx] = pack2(v);
}

// softmax: reads packed score pairs, writes P as f16 plane (in-place, half-width)
// + accumulates head-average into d_out attn region. 4 waves x 2 heads, 1 barrier.
__global__ __launch_bounds__(256) void k_softmax(u32* __restrict__ sc,
                                                 float* __restrict__ attn_out,
                                                 int l, int bbase){
  __shared__ float avgw[4][SS];   // per-wave partial head sums (16 KB)
  const int tid = threadIdx.x;
  const int q  = blockIdx.x & (SS-1);
  const int hb = blockIdx.x >> 10;
  const int b = bbase + hb;
  const int wave = tid >> 6, lane = tid & 63;
  #pragma unroll
  for (int j=0;j<16;j++) avgw[wave][j*64 + lane] = 0.0f;
  #pragma unroll
  for (int hi=0; hi<2; hi++){
    int h = wave + hi*4;
    u32* row = sc + (size_t)(hb*HH + h)*SS*SS + (size_t)q*SS;
    float v[16];
    float m = -1e30f;
    #pragma unroll
    for (int j=0;j<16;j++){ v[j] = unpack2f(row[j*64 + lane]); m = fmaxf(m, v[j]); }
    #pragma unroll
    for (int o=32;o>0;o>>=1) m = fmaxf(m, __shfl_xor(m, o));
    float s = 0.0f;
    #pragma unroll
    for (int j=0;j<16;j++){ v[j] = __expf(v[j] - m); s += v[j]; }
    #pragma unroll
    for (int o=32;o>0;o>>=1) s += __shfl_xor(s, o);
    float inv = __builtin_amdgcn_rcpf(s);
    u16* p16 = (u16*)row;
    #pragma unroll
    for (int j=0;j<16;j++){
      float p = v[j]*inv;
      p16[j*64 + lane] = f2b((_Float16)p);
      avgw[wave][j*64 + lane] += p;
    }
  }
  __syncthreads();
  float* ao = attn_out + (size_t)((l*BB + b)*SS + q)*SS;
  for (int j=tid;j<SS;j+=256)
    ao[j] = (avgw[0][j]+avgw[1][j]+avgw[2][j]+avgw[3][j])*0.125f;
}

// ---------------- LayerNorm: out = LN(x (+ y)) * g + b  (+ optional packed copy) ----------------
__global__ __launch_bounds__(64) void k_ln(const float* __restrict__ x,
                                           const float* __restrict__ y,
                                           const float* __restrict__ g,
                                           const float* __restrict__ bta,
                                           float* __restrict__ out,
                                           u32* __restrict__ outp){
  const int n = blockIdx.x;
  const int tid = threadIdx.x;
  float v[8];
  float s = 0.0f, sq = 0.0f;
  #pragma unroll
  for (int j=0;j<8;j++){
    int d = j*64 + tid;
    float a = x[(size_t)n*DD + d];
    if (y) a += y[(size_t)n*DD + d];
    v[j] = a; s += a; sq += a*a;
  }
  #pragma unroll
  for (int o=32;o>0;o>>=1){ s += __shfl_xor(s, o); sq += __shfl_xor(sq, o); }
  float mean = s*(1.0f/DD);
  float var = sq*(1.0f/DD) - mean*mean;
  float rstd = rsqrtf(var + EPSF);
  #pragma unroll
  for (int j=0;j<8;j++){
    int d = j*64 + tid;
    float r = (v[j]-mean)*rstd*g[d] + bta[d];
    out[(size_t)n*DD + d] = r;
    if (outp) outp[(size_t)n*DD + d] = pack2(r);
  }
}

extern "C" void kernel_launch(void* const* d_in, const int* in_sizes, int n_in,
                              void* d_out, int out_size, void* d_ws, size_t ws_size,
                              hipStream_t stream){
  const int*   src    = (const int*)  d_in[0];
  const float* emb    = (const float*)d_in[1];
  const float* conv_w = (const float*)d_in[2];
  const float* conv_b = (const float*)d_in[3];
  const float* bn_g   = (const float*)d_in[4];
  const float* bn_b   = (const float*)d_in[5];
  const float* bn_m   = (const float*)d_in[6];
  const float* bn_v   = (const float*)d_in[7];
  const float* w_ih   = (const float*)d_in[8];
  const float* w_hh   = (const float*)d_in[9];
  const float* b_ih   = (const float*)d_in[10];
  const float* b_hh   = (const float*)d_in[11];
  const float* in_w   = (const float*)d_in[12];
  const float* in_b   = (const float*)d_in[13];
  const float* out_w  = (const float*)d_in[14];
  const float* out_b  = (const float*)d_in[15];
  const float* ln1_g  = (const float*)d_in[16];
  const float* ln1_b  = (const float*)d_in[17];
  const float* w1     = (const float*)d_in[18];
  const float* b1     = (const float*)d_in[19];
  const float* w2     = (const float*)d_in[20];
  const float* b2     = (const float*)d_in[21];
  const float* ln2_g  = (const float*)d_in[22];
  const float* ln2_b  = (const float*)d_in[23];
  const float* fin_g  = (const float*)d_in[24];
  const float* fin_b  = (const float*)d_in[25];

  float* ws    = (float*)d_ws;
  float* x0    = ws + O_X0;
  float* x1    = ws + O_X1;
  float* ctx   = ws + O_CTX;
  float* qkv   = ws + O_QKV;     // packed u32 pairs
  float* big   = ws + O_BIG;
  float* bsum  = ws + O_BSUM;
  unsigned long long* hpack = (unsigned long long*)(big + 8388608);

  u32*   aconv = (u32*)(ws + O_HSEQ);               // 2,097,152 packed activations
  float* qbias = ws + O_HSEQ + 2097152;             // 1536 scaled qkv bias
  u32*   qkvp  = (u32*)qkv;
  u32*   scp   = (u32*)big;                         // scores as packed pairs
  u32*   wsg   = (u32*)(big + 13000000);            // gates W scratch (1M, clear of hpack)
  u32*   wsa   = (u32*)big;                         // qkv/proj W scratch (at big+0)
  u32*   ws1   = (u32*)(big + 8500000);             // ffn1 W scratch
  u32*   ws2   = (u32*)(big + 9500000);             // ffn2 W scratch

  float* outx  = (float*)d_out;            // [B,S,D]
  float* attn  = outx + (size_t)NT*DD;     // [L,B,S,S]

  hipMemsetAsync(hpack, 0, (size_t)(SS+1)*BB*DD*sizeof(unsigned long long), stream);

  const int eb = (NT*DD)/256;
  k_embed<<<eb, 256, 0, stream>>>(src, emb, x0);
  k_conv <<<eb, 256, 0, stream>>>(x0, conv_w, conv_b, bn_g, bn_b, bn_m, bn_v, x1, aconv);
  k_bsum <<<8, 256, 0, stream>>>(b_ih, b_hh, bsum, 4*DD);

  // LSTM input precompute: gates = x1 @ w_ih^T + (b_ih + b_hh)
  k_wsplit<0><<<1024, 256, 0, stream>>>(w_ih, wsg, nullptr, nullptr, 2048*512, 512);
  k_gemm_mfma<0,1,0><<<(NT/128)*((4*DD)/128), 256, 0, stream>>>(
      aconv, wsg, bsum, big, NT, 4*DD, DD);
  k_lstm<<<256, 256, 0, stream>>>(big, w_hh, hpack);
  k_resid<<<eb, 256, 0, stream>>>(x1, hpack, aconv);

  float* cur = x1;
  float* tmp = x0;
  for (int l=0; l<LL; ++l){
    // qkv = cur @ in_w[l]^T + in_b[l]  (Q rows pre-scaled 0.125; packed output)
    k_wsplit<1><<<768, 256, 0, stream>>>(in_w + (size_t)l*1536*DD, wsa,
                                         in_b + (size_t)l*1536, qbias, 1536*512, 512);
    k_gemm_mfma<0,1,1><<<(NT/128)*(1536/128), 256, 0, stream>>>(
        aconv, wsa, qbias, qkvp, NT, 1536, DD);
    for (int bb2=0; bb2<2; ++bb2){
      int bbase = bb2*2;
      k_scores_mfma<<<1024, 256, 0, stream>>>(qkvp, scp, bbase);
      k_softmax    <<<2048, 256, 0, stream>>>(scp, attn, l, bbase);
      k_pv_mfma    <<<256,  256, 0, stream>>>(scp, qkvp, ctx, bbase);
    }
    // proj: tmp = ctx @ out_w[l]^T + out_b[l]   (A f32 path)
    k_wsplit<0><<<256, 256, 0, stream>>>(out_w + (size_t)l*DD*DD, wsa,
                                         nullptr, nullptr, 512*512, 512);
    k_gemm_mfma<0,0,0><<<(NT/128)*(DD/128), 256, 0, stream>>>(
        ctx, wsa, out_b + (size_t)l*DD, tmp, NT, DD, DD);
    // ln1 -> cur (f32) + aconv (packed, consumed by ffn1)
    k_ln<<<NT, 64, 0, stream>>>(cur, tmp, ln1_g + l*DD, ln1_b + l*DD, cur, aconv);
    // ffh = gelu(cur @ w1[l]^T + b1[l])  -> packed pairs in big[0..8.39M)
    k_wsplit<0><<<1024, 256, 0, stream>>>(w1 + (size_t)l*DFF*DD, ws1,
                                          nullptr, nullptr, 2048*512, 512);
    k_gemm_mfma<1,1,1><<<(NT/128)*(DFF/128), 256, 0, stream>>>(
        aconv, ws1, b1 + (size_t)l*DFF, (u32*)big, NT, DFF, DD);
    // tmp = ffh @ w2[l]^T + b2[l]   (A = packed ffh)
    k_wsplit<0><<<1024, 256, 0, stream>>>(w2 + (size_t)l*DD*DFF, ws2,
                                          nullptr, nullptr, 512*2048, 2048);
    k_gemm_mfma<0,1,0><<<(NT/128)*(DD/128), 256, 0, stream>>>(
        (u32*)big, ws2, b2 + (size_t)l*DD, tmp, NT, DD, DFF);
    // ln2 -> cur (f32) + aconv (packed, consumed by next layer's qkv)
    k_ln<<<NT, 64, 0, stream>>>(cur, tmp, ln2_g + l*DD, ln2_b + l*DD, cur, aconv);
  }
  k_ln<<<NT, 64, 0, stream>>>(cur, nullptr, fin_g, fin_b, outx, nullptr);
}

// Round 10
// 2657.876 us; speedup vs baseline: 1.3928x; 1.0441x over previous
//
#include <hip/hip_runtime.h>
#include <math.h>

#define DD 512
#define SS 1024
#define BB 4
#define HH 8
#define DFF 2048
#define LL 4
#define NT 4096           // BB*SS
#define EPSF 1e-5f

// ---------------- workspace layout (float elements) ----------------
#define O_X0    ((size_t)0)            // 2,097,152  emb+pe
#define O_X1    ((size_t)2097152)      // 2,097,152  conv out / current x
#define O_HSEQ  ((size_t)4194304)      // 2,099,200: packed activation scratch (+qbias tail)
#define O_CTX   ((size_t)6293504)      // 2,097,152 (ctx, packed pairs)
#define O_QKV   ((size_t)8390656)      // 6,291,456 (packed split-pairs)
#define O_BIG   ((size_t)14682112)     // 16,777,216 (gates 8.39M / hpack / scores / ffh / W-scratch)
#define O_BSUM  ((size_t)31459328)     // 2048

typedef unsigned int  u32;
typedef unsigned short u16;
typedef __attribute__((ext_vector_type(8))) _Float16 f16x8;
typedef __attribute__((ext_vector_type(4))) _Float16 f16x4;
typedef __attribute__((ext_vector_type(4))) float    f32x4;

// fast transcendentals: v_exp_f32 / v_rcp_f32 based (~1e-7 rel, saturating-safe)
__device__ __forceinline__ float fsig(float x){
  return __builtin_amdgcn_rcpf(1.0f + __expf(-x));
}
__device__ __forceinline__ float ftanh(float x){
  return 1.0f - 2.0f*__builtin_amdgcn_rcpf(1.0f + __expf(2.0f*x));
}
union f16u { u16 u; _Float16 f; };
__device__ __forceinline__ float b2f(u16 b){ f16u t; t.u = b; return (float)t.f; }
__device__ __forceinline__ u16 f2b(_Float16 h){ f16u t; t.f = h; return t.u; }
// pack f32 -> {hi f16 (low16) | lo f16 (high16)}
__device__ __forceinline__ u32 pack2(float v){
  _Float16 hi = (_Float16)v;
  _Float16 lo = (_Float16)(v - (float)hi);
  return (u32)f2b(hi) | ((u32)f2b(lo) << 16);
}
__device__ __forceinline__ float unpack2f(u32 w){
  return b2f((u16)w) + b2f((u16)(w >> 16));
}

// ---------------- embedding + sinusoidal PE ----------------
__global__ void k_embed(const int* __restrict__ src, const float* __restrict__ emb,
                        float* __restrict__ x){
  int idx = blockIdx.x*256 + threadIdx.x;
  if (idx >= NT*DD) return;
  int d = idx & (DD-1);
  int n = idx >> 9;          // b*SS + s
  int s = n & (SS-1);
  int tok = src[n];
  int i2 = d & ~1;
  float div = expf(-(float)i2 * (9.210340371976184f/512.0f));  // ln(10000)/512
  float ang = (float)s * div;
  float pe = (d & 1) ? cosf(ang) : sinf(ang);
  x[idx] = emb[(size_t)tok*DD + d]*22.62741699796952f + pe;    // sqrt(512)
}

// ---------------- depthwise conv k=3 + BN(eval) + ReLU (+ packed copy) ----------------
__global__ void k_conv(const float* __restrict__ x, const float* __restrict__ cw,
                       const float* __restrict__ cb, const float* __restrict__ bg,
                       const float* __restrict__ bb, const float* __restrict__ bm,
                       const float* __restrict__ bv, float* __restrict__ y,
                       u32* __restrict__ yp){
  int idx = blockIdx.x*256 + threadIdx.x;
  if (idx >= NT*DD) return;
  int d = idx & (DD-1);
  int n = idx >> 9;
  int s = n & (SS-1);
  float acc = cb[d];
  if (s > 0)     acc += x[idx - DD]*cw[d*3+0];
  acc += x[idx]*cw[d*3+1];
  if (s < SS-1)  acc += x[idx + DD]*cw[d*3+2];
  float v = (acc - bm[d])*rsqrtf(bv[d]+EPSF)*bg[d] + bb[d];
  v = fmaxf(v, 0.0f);
  y[idx] = v;
  yp[idx] = pack2(v);
}

__global__ void k_bsum(const float* a, const float* b, float* o, int n){
  int i = blockIdx.x*256 + threadIdx.x;
  if (i < n) o[i] = a[i] + b[i];
}

// ---------------- weight pre-split: W f32 -> packed {hi|lo} u32 ----------------
// QSCALE: scale rows<512 by 0.125 (attention Q fold) and emit scaled bias copy.
template<int QSCALE>
__global__ void k_wsplit(const float* __restrict__ W, u32* __restrict__ Wp,
                         const float* __restrict__ bias_in, float* __restrict__ bias_out,
                         int total, int K){
  int i = blockIdx.x*1024 + threadIdx.x*4;
  if (i < total){
    float4 v = *reinterpret_cast<const float4*>(W + i);
    float s = 1.0f;
    if (QSCALE){ int row = i / K; if (row < 512) s = 0.125f; }
    uint4 o;
    o.x = pack2(v.x*s); o.y = pack2(v.y*s); o.z = pack2(v.z*s); o.w = pack2(v.w*s);
    *reinterpret_cast<uint4*>(Wp + i) = o;
  }
  if (QSCALE && blockIdx.x == 0){
    for (int j = threadIdx.x; j < 1536; j += 256){
      float bv = bias_in[j];
      bias_out[j] = (j < 512) ? bv*0.125f : bv;
    }
  }
}

// unpack helper for staging: 4 packed elems -> hi u32x2 + lo u32x2 (2 halves each)
__device__ __forceinline__ void unpk4(uint4 w, uint2& hi, uint2& lo){
  hi.x = (w.x & 0xffffu) | (w.y << 16);
  hi.y = (w.z & 0xffffu) | (w.w << 16);
  lo.x = (w.x >> 16) | (w.y & 0xffff0000u);
  lo.y = (w.z >> 16) | (w.w & 0xffff0000u);
}
__device__ __forceinline__ uint2 unpk4hi(uint4 w){
  uint2 hi;
  hi.x = (w.x & 0xffffu) | (w.y << 16);
  hi.y = (w.z & 0xffffu) | (w.w << 16);
  return hi;
}

// ---------------- MFMA split-f16 GEMM: C[M,N] = A[M,K] @ W[N,K]^T + bias ----------------
// A and W pre-split packed pairs. 2-pass MFMA: C = Ah*Wh + Ah*Wl (A-lo correction
// dropped: ~2^-11 relative, ~1e-3 abs on O(1) outputs -- measured-safe, R5 passed
// at absmax 0.03125). OSPLIT=1: C written as packed split-pairs.
#define BKP 40   // padded K stride in halves
template<int ACT, int OSPLIT>
__global__ __launch_bounds__(256) void k_gemm_mfma(const u32* __restrict__ Ain,
                                                   const u32* __restrict__ Wp,
                                                   const float* __restrict__ bias,
                                                   void* __restrict__ Cout,
                                                   int M, int N, int K){
  __shared__ _Float16 Ah[128][BKP];
  __shared__ _Float16 Wh[128][BKP];
  __shared__ _Float16 Wl[128][BKP];
  const int tid = threadIdx.x;
  const int nbx = N >> 7;
  const int bx = blockIdx.x % nbx;
  const int by = blockIdx.x / nbx;
  const int m0 = by << 7, n0 = bx << 7;
  const int lane = tid & 63;
  const int wid  = tid >> 6;
  const int wr = wid >> 1, wc = wid & 1;
  const int fm = lane & 15, fg = lane >> 4;
  const int r0 = tid >> 3;              // staging row base (row = r0 + 32e)
  const int k4 = (tid & 7) << 2;        // staging k offset within tile
  const u32* Wbase = Wp + (size_t)(n0 + r0)*K + k4;
  const u32* Abase = Ain + (size_t)(m0 + r0)*K + k4;

  f32x4 acc[4][4];
  #pragma unroll
  for (int i=0;i<4;i++)
    #pragma unroll
    for (int j=0;j<4;j++) acc[i][j] = (f32x4){0.0f,0.0f,0.0f,0.0f};

  uint4 rw[4], ra4[4];
  #pragma unroll
  for (int e=0;e<4;e++){
    rw[e]  = *reinterpret_cast<const uint4*>(Wbase + (size_t)(e*32)*K);
    ra4[e] = *reinterpret_cast<const uint4*>(Abase + (size_t)(e*32)*K);
  }

  for (int k0 = 0; k0 < K; k0 += 32){
    #pragma unroll
    for (int e = 0; e < 4; ++e){
      int rr = r0 + e*32;
      uint2 hi, lo;
      unpk4(rw[e], hi, lo);
      *reinterpret_cast<uint2*>(&Wh[rr][k4]) = hi;
      *reinterpret_cast<uint2*>(&Wl[rr][k4]) = lo;
      *reinterpret_cast<uint2*>(&Ah[rr][k4]) = unpk4hi(ra4[e]);
    }
    __syncthreads();
    if (k0 + 32 < K){
      #pragma unroll
      for (int e=0;e<4;e++){
        rw[e]  = *reinterpret_cast<const uint4*>(Wbase + (size_t)(e*32)*K + k0 + 32);
        ra4[e] = *reinterpret_cast<const uint4*>(Abase + (size_t)(e*32)*K + k0 + 32);
      }
    }
    f16x8 a_h[4], w_h[4], w_l[4];
    #pragma unroll
    for (int i=0;i<4;i++){
      int row = wr*64 + i*16 + fm;
      a_h[i] = *reinterpret_cast<const f16x8*>(&Ah[row][fg*8]);
    }
    #pragma unroll
    for (int j=0;j<4;j++){
      int row = wc*64 + j*16 + fm;
      w_h[j] = *reinterpret_cast<const f16x8*>(&Wh[row][fg*8]);
      w_l[j] = *reinterpret_cast<const f16x8*>(&Wl[row][fg*8]);
    }
    #pragma unroll
    for (int i=0;i<4;i++)
      #pragma unroll
      for (int j=0;j<4;j++){
        acc[i][j] = __builtin_amdgcn_mfma_f32_16x16x32_f16(a_h[i], w_h[j], acc[i][j], 0, 0, 0);
        acc[i][j] = __builtin_amdgcn_mfma_f32_16x16x32_f16(a_h[i], w_l[j], acc[i][j], 0, 0, 0);
      }
    __syncthreads();
  }
  #pragma unroll
  for (int i=0;i<4;i++){
    #pragma unroll
    for (int r=0;r<4;r++){
      int row = m0 + wr*64 + i*16 + fg*4 + r;
      #pragma unroll
      for (int j=0;j<4;j++){
        int col = n0 + wc*64 + j*16 + fm;
        float v = acc[i][j][r] + bias[col];
        if (ACT == 1) v = 0.5f*v*(1.0f + erff(v*0.70710678118654752f));  // exact gelu
        if constexpr (OSPLIT) ((u32*)Cout)[(size_t)row*N + col] = pack2(v);
        else                  ((float*)Cout)[(size_t)row*N + col] = v;
      }
    }
  }
}

// ---------------- MFMA attention scores: sc = Qs @ K^T (128x128 tiles) ----------------
// qkv packed pairs (Q pre-scaled 0.125). 2-pass: Qh*Kh + Qh*Kl. Output packed pairs.
#define SPAD 72
__global__ __launch_bounds__(256) void k_scores_mfma(const u32* __restrict__ qkv,
                                                     u32* __restrict__ sc, int bbase){
  __shared__ _Float16 Qh[128][SPAD];
  __shared__ _Float16 Kh[128][SPAD], Kl[128][SPAD];
  const int tid = threadIdx.x;
  const int kt = blockIdx.x & 7;
  const int qt = (blockIdx.x >> 3) & 7;
  const int h  = (blockIdx.x >> 6) & 7;
  const int hb = (blockIdx.x >> 9) & 1;
  const int b  = bbase + hb;
  const int q0 = qt*128, k0 = kt*128;
  #pragma unroll
  for (int e=0;e<8;e++){
    int lin = e*256 + tid;
    int rr = lin >> 4;
    int c4 = (lin & 15) << 2;
    uint4 qv = *reinterpret_cast<const uint4*>(qkv + (size_t)(b*SS + q0+rr)*1536 + h*64 + c4);
    uint4 kv = *reinterpret_cast<const uint4*>(qkv + (size_t)(b*SS + k0+rr)*1536 + DD + h*64 + c4);
    uint2 hi, lo;
    *reinterpret_cast<uint2*>(&Qh[rr][c4]) = unpk4hi(qv);
    unpk4(kv, hi, lo);
    *reinterpret_cast<uint2*>(&Kh[rr][c4]) = hi;
    *reinterpret_cast<uint2*>(&Kl[rr][c4]) = lo;
  }
  __syncthreads();
  const int lane = tid & 63, wid = tid >> 6;
  const int wr = wid >> 1, wc = wid & 1;
  const int fm = lane & 15, fg = lane >> 4;
  f32x4 acc[4][4];
  #pragma unroll
  for (int i=0;i<4;i++)
    #pragma unroll
    for (int j=0;j<4;j++) acc[i][j] = (f32x4){0.0f,0.0f,0.0f,0.0f};
  #pragma unroll
  for (int ks=0; ks<2; ks++){
    f16x8 ah[4], bh[4], bl[4];
    #pragma unroll
    for (int i=0;i<4;i++){
      int row = wr*64 + i*16 + fm;
      ah[i] = *reinterpret_cast<const f16x8*>(&Qh[row][ks*32 + fg*8]);
    }
    #pragma unroll
    for (int j=0;j<4;j++){
      int row = wc*64 + j*16 + fm;
      bh[j] = *reinterpret_cast<const f16x8*>(&Kh[row][ks*32 + fg*8]);
      bl[j] = *reinterpret_cast<const f16x8*>(&Kl[row][ks*32 + fg*8]);
    }
    #pragma unroll
    for (int i=0;i<4;i++)
      #pragma unroll
      for (int j=0;j<4;j++){
        acc[i][j] = __builtin_amdgcn_mfma_f32_16x16x32_f16(ah[i], bh[j], acc[i][j], 0, 0, 0);
        acc[i][j] = __builtin_amdgcn_mfma_f32_16x16x32_f16(ah[i], bl[j], acc[i][j], 0, 0, 0);
      }
  }
  u32* out = sc + (size_t)(hb*HH + h)*SS*SS;
  #pragma unroll
  for (int i=0;i<4;i++){
    #pragma unroll
    for (int r=0;r<4;r++){
      int row = q0 + wr*64 + i*16 + fg*4 + r;
      #pragma unroll
      for (int j=0;j<4;j++){
        int col = k0 + wc*64 + j*16 + fm;
        out[(size_t)row*SS + col] = pack2(acc[i][j][r]);
      }
    }
  }
}

// ---------------- MFMA PV: ctx[:, h*64..] = P @ V (64q x 64d tiles, BK=64) ----------------
// P f16 plane; V packed pairs; ctx written as packed pairs. 256 blocks/dispatch.
__global__ __launch_bounds__(256) void k_pv_mfma(const u32* __restrict__ sc,
                                                 const u32* __restrict__ qkv,
                                                 u32* __restrict__ ctx, int bbase){
  __shared__ _Float16 Ph[64][SPAD];
  __shared__ _Float16 Vh[64][SPAD],  Vl[64][SPAD];
  const int tid = threadIdx.x;
  const int qt = blockIdx.x & 15;
  const int h  = (blockIdx.x >> 4) & 7;
  const int hb = (blockIdx.x >> 7) & 1;
  const int b  = bbase + hb;
  const int q0 = qt*64;
  const u16* Pb = (const u16*)(sc + (size_t)(hb*HH + h)*SS*SS);
  const int lane = tid & 63, wid = tid >> 6;
  const int wr = wid >> 1, wc = wid & 1;      // wave tile: 32 rows x 32 cols
  const int fm = lane & 15, fg = lane >> 4;
  const int pr0 = tid >> 4;                   // P staging: rows pr0 + 16e (e<4)
  const int pc4 = (tid & 15) << 2;
  const int vd  = tid & 63;                   // V staging: dim
  const int vk0 = tid >> 6;                   // V staging: k = vk0 + 4e
  const u16* Pbase = Pb + (size_t)(q0 + pr0)*2*SS + pc4;
  const u32* Vbase = qkv + (size_t)(b*SS + vk0)*1536 + 1024 + h*64 + vd;
  f32x4 acc[2][2];
  #pragma unroll
  for (int i=0;i<2;i++){ acc[i][0] = (f32x4){0,0,0,0}; acc[i][1] = (f32x4){0,0,0,0}; }

  uint2 rp[4];
  u32   rv[16];
  #pragma unroll
  for (int e=0;e<4;e++)  rp[e] = *reinterpret_cast<const uint2*>(Pbase + (size_t)(e*16)*2*SS);
  #pragma unroll
  for (int e=0;e<16;e++) rv[e] = Vbase[(size_t)(e*4)*1536];

  for (int kk0=0; kk0<SS; kk0+=64){
    #pragma unroll
    for (int e=0;e<4;e++){
      int rr = pr0 + e*16;
      *reinterpret_cast<uint2*>(&Ph[rr][pc4]) = rp[e];   // f16 bits verbatim
    }
    #pragma unroll
    for (int e=0;e<16;e++){
      int k = vk0 + e*4;
      u32 w = rv[e];
      f16u thi, tlo; thi.u = (u16)w; tlo.u = (u16)(w >> 16);
      Vh[vd][k] = thi.f;
      Vl[vd][k] = tlo.f;
    }
    __syncthreads();
    if (kk0 + 64 < SS){
      #pragma unroll
      for (int e=0;e<4;e++)
        rp[e] = *reinterpret_cast<const uint2*>(Pbase + (size_t)(e*16)*2*SS + kk0 + 64);
      #pragma unroll
      for (int e=0;e<16;e++)
        rv[e] = Vbase[(size_t)(kk0 + 64 + e*4)*1536];
    }
    #pragma unroll
    for (int ks=0; ks<2; ks++){
      f16x8 ah[2], bh[2], bl[2];
      #pragma unroll
      for (int i=0;i<2;i++){
        int row = wr*32 + i*16 + fm;
        ah[i] = *reinterpret_cast<const f16x8*>(&Ph[row][ks*32 + fg*8]);
      }
      #pragma unroll
      for (int j=0;j<2;j++){
        int row = wc*32 + j*16 + fm;
        bh[j] = *reinterpret_cast<const f16x8*>(&Vh[row][ks*32 + fg*8]);
        bl[j] = *reinterpret_cast<const f16x8*>(&Vl[row][ks*32 + fg*8]);
      }
      #pragma unroll
      for (int i=0;i<2;i++)
        #pragma unroll
        for (int j=0;j<2;j++){
          acc[i][j] = __builtin_amdgcn_mfma_f32_16x16x32_f16(ah[i], bh[j], acc[i][j], 0, 0, 0);
          acc[i][j] = __builtin_amdgcn_mfma_f32_16x16x32_f16(ah[i], bl[j], acc[i][j], 0, 0, 0);
        }
    }
    __syncthreads();
  }
  #pragma unroll
  for (int i=0;i<2;i++){
    #pragma unroll
    for (int r=0;r<4;r++){
      int row = q0 + wr*32 + i*16 + fg*4 + r;
      #pragma unroll
      for (int j=0;j<2;j++){
        int col = wc*32 + j*16 + fm;
        ctx[(size_t)(b*SS + row)*DD + h*64 + col] = pack2(acc[i][j][r]);
      }
    }
  }
}

// ---------------- persistent LSTM: 256 blocks = 4 batches x 64 chunks(8 dims) ----------------
// R9-verified: packed {tag|h} 64-bit relaxed agent-scope atomics; wave-local gate
// combine; hsh double-buffered (1 barrier/step); cross-step poll prefetch;
// ks-major LDS layout -> 16x ds_read_b128 gemv.
__global__ __launch_bounds__(256) void k_lstm(const float* __restrict__ gates_in,
                                              const float* __restrict__ w_hh,
                                              unsigned long long* __restrict__ hpack){
  __shared__ float hsh[2][8][68];
  const int b = blockIdx.x >> 6;
  const int chunk = blockIdx.x & 63;
  const int d0 = chunk*8;
  const int tid = threadIdx.x;
  const int wave = tid >> 6;
  const int lane = tid & 63;
  const int diw = lane >> 5;          // 0..1 : which of the wave's 2 dims
  const int g   = (lane >> 3) & 3;    // gate (0=i,1=f,2=g,3=o)
  const int ks  = lane & 7;           // k-slice: k = j*8 + ks
  const int dim = wave*2 + diw;       // 0..7 within chunk
  const int src0 = diw*32;            // base lane of this dim's gate group
  float w[64];
  {
    const float* wrow = w_hh + (size_t)(g*DD + d0 + dim)*DD;
    #pragma unroll
    for (int j=0;j<64;j++) w[j] = wrow[j*8 + ks];
  }
  float c = 0.0f;
  const float* gbase = gates_in + (size_t)(b*SS)*(4*DD) + g*DD + d0 + dim;
  // prefetch step-0 entries (memset tags = 0 -> instant hit)
  unsigned long long p0 = __hip_atomic_load(hpack + (size_t)b*DD + tid,
                                            __ATOMIC_RELAXED, __HIP_MEMORY_SCOPE_AGENT);
  unsigned long long p1 = __hip_atomic_load(hpack + (size_t)b*DD + tid + 256,
                                            __ATOMIC_RELAXED, __HIP_MEMORY_SCOPE_AGENT);
  for (int t=0; t<SS; ++t){
    float gv = 0.0f;
    if (ks == 0) gv = gbase[(size_t)t*(4*DD)];
    const unsigned long long exp_tag = (unsigned long long)t;
    unsigned long long* hp = hpack + (size_t)(t*BB + b)*DD;
    while ((p0 >> 32) != exp_tag || (p1 >> 32) != exp_tag){
      if ((p0 >> 32) != exp_tag)
        p0 = __hip_atomic_load(hp + tid,       __ATOMIC_RELAXED, __HIP_MEMORY_SCOPE_AGENT);
      if ((p1 >> 32) != exp_tag)
        p1 = __hip_atomic_load(hp + tid + 256, __ATOMIC_RELAXED, __HIP_MEMORY_SCOPE_AGENT);
    }
    float (*hs)[68] = hsh[t & 1];
    union { unsigned int u; float f; } u0, u1;
    u0.u = (unsigned int)p0;
    u1.u = (unsigned int)p1;
    hs[tid & 7][tid >> 3]        = u0.f;   // dim = tid
    hs[tid & 7][(tid >> 3) + 32] = u1.f;   // dim = tid + 256
    __syncthreads();
    if (t + 1 < SS){   // cross-step poll prefetch (latency hides under compute)
      unsigned long long* hq = hpack + (size_t)((t+1)*BB + b)*DD;
      p0 = __hip_atomic_load(hq + tid,       __ATOMIC_RELAXED, __HIP_MEMORY_SCOPE_AGENT);
      p1 = __hip_atomic_load(hq + tid + 256, __ATOMIC_RELAXED, __HIP_MEMORY_SCOPE_AGENT);
    }
    float a0=0.0f, a1=0.0f, a2=0.0f, a3=0.0f;
    #pragma unroll
    for (int j=0;j<64;j+=4){
      float4 hv = *reinterpret_cast<const float4*>(&hs[ks][j]);
      a0 += w[j+0]*hv.x;
      a1 += w[j+1]*hv.y;
      a2 += w[j+2]*hv.z;
      a3 += w[j+3]*hv.w;
    }
    float acc = (a0+a1)+(a2+a3);
    acc += __shfl_down(acc, 4, 8);
    acc += __shfl_down(acc, 2, 8);
    acc += __shfl_down(acc, 1, 8);
    // ks==0 lanes hold the full gate pre-activation; activate (others garbage, unused)
    float v = acc + gv;
    float gval = (g == 2) ? ftanh(v) : fsig(v);
    // wave-local gather of the 4 gates for this dim
    float gi = __shfl(gval, src0 + 0);
    float gf = __shfl(gval, src0 + 8);
    float gg = __shfl(gval, src0 + 16);
    float go = __shfl(gval, src0 + 24);
    c = gf*c + gi*gg;                  // redundant across the 32-lane half (identical)
    float h = go*ftanh(c);
    if (lane == src0){                 // 2 stores per wave, issued wave-locally
      union { float f; unsigned int u; } hu; hu.f = h;
      unsigned long long pk = ((unsigned long long)(unsigned int)(t+1) << 32)
                            | (unsigned long long)hu.u;
      __hip_atomic_store(&hpack[(size_t)((t+1)*BB + b)*DD + d0 + dim], pk,
                         __ATOMIC_RELAXED, __HIP_MEMORY_SCOPE_AGENT);
    }
  }
}

__global__ void k_resid(float* __restrict__ x, const unsigned long long* __restrict__ hpack,
                        u32* __restrict__ xp){
  int idx = blockIdx.x*256 + threadIdx.x;
  if (idx >= NT*DD) return;
  int d = idx & (DD-1);
  int n = idx >> 9;
  int s = n & (SS-1);
  int b = n >> 10;
  union { unsigned int u; float f; } hu;
  hu.u = (unsigned int)hpack[(size_t)((s+1)*BB + b)*DD + d];
  float v = x[idx] + hu.f;
  x[idx] = v;
  xp[idx] = pack2(v);
}

// softmax: reads packed score pairs, writes P as f16 plane (in-place, half-width)
// + accumulates head-average into d_out attn region. 4 waves x 2 heads, 1 barrier.
__global__ __launch_bounds__(256) void k_softmax(u32* __restrict__ sc,
                                                 float* __restrict__ attn_out,
                                                 int l, int bbase){
  __shared__ float avgw[4][SS];   // per-wave partial head sums (16 KB)
  const int tid = threadIdx.x;
  const int q  = blockIdx.x & (SS-1);
  const int hb = blockIdx.x >> 10;
  const int b = bbase + hb;
  const int wave = tid >> 6, lane = tid & 63;
  #pragma unroll
  for (int j=0;j<16;j++) avgw[wave][j*64 + lane] = 0.0f;
  #pragma unroll
  for (int hi=0; hi<2; hi++){
    int h = wave + hi*4;
    u32* row = sc + (size_t)(hb*HH + h)*SS*SS + (size_t)q*SS;
    float v[16];
    float m = -1e30f;
    #pragma unroll
    for (int j=0;j<16;j++){ v[j] = unpack2f(row[j*64 + lane]); m = fmaxf(m, v[j]); }
    #pragma unroll
    for (int o=32;o>0;o>>=1) m = fmaxf(m, __shfl_xor(m, o));
    float s = 0.0f;
    #pragma unroll
    for (int j=0;j<16;j++){ v[j] = __expf(v[j] - m); s += v[j]; }
    #pragma unroll
    for (int o=32;o>0;o>>=1) s += __shfl_xor(s, o);
    float inv = __builtin_amdgcn_rcpf(s);
    u16* p16 = (u16*)row;
    #pragma unroll
    for (int j=0;j<16;j++){
      float p = v[j]*inv;
      p16[j*64 + lane] = f2b((_Float16)p);
      avgw[wave][j*64 + lane] += p;
    }
  }
  __syncthreads();
  float* ao = attn_out + (size_t)((l*BB + b)*SS + q)*SS;
  for (int j=tid;j<SS;j+=256)
    ao[j] = (avgw[0][j]+avgw[1][j]+avgw[2][j]+avgw[3][j])*0.125f;
}

// ---------------- LayerNorm: out = LN(x (+ y)) * g + b  (+ optional packed copy) ----------------
__global__ __launch_bounds__(64) void k_ln(const float* __restrict__ x,
                                           const float* __restrict__ y,
                                           const float* __restrict__ g,
                                           const float* __restrict__ bta,
                                           float* __restrict__ out,
                                           u32* __restrict__ outp){
  const int n = blockIdx.x;
  const int tid = threadIdx.x;
  float v[8];
  float s = 0.0f, sq = 0.0f;
  #pragma unroll
  for (int j=0;j<8;j++){
    int d = j*64 + tid;
    float a = x[(size_t)n*DD + d];
    if (y) a += y[(size_t)n*DD + d];
    v[j] = a; s += a; sq += a*a;
  }
  #pragma unroll
  for (int o=32;o>0;o>>=1){ s += __shfl_xor(s, o); sq += __shfl_xor(sq, o); }
  float mean = s*(1.0f/DD);
  float var = sq*(1.0f/DD) - mean*mean;
  float rstd = rsqrtf(var + EPSF);
  #pragma unroll
  for (int j=0;j<8;j++){
    int d = j*64 + tid;
    float r = (v[j]-mean)*rstd*g[d] + bta[d];
    out[(size_t)n*DD + d] = r;
    if (outp) outp[(size_t)n*DD + d] = pack2(r);
  }
}

extern "C" void kernel_launch(void* const* d_in, const int* in_sizes, int n_in,
                              void* d_out, int out_size, void* d_ws, size_t ws_size,
                              hipStream_t stream){
  const int*   src    = (const int*)  d_in[0];
  const float* emb    = (const float*)d_in[1];
  const float* conv_w = (const float*)d_in[2];
  const float* conv_b = (const float*)d_in[3];
  const float* bn_g   = (const float*)d_in[4];
  const float* bn_b   = (const float*)d_in[5];
  const float* bn_m   = (const float*)d_in[6];
  const float* bn_v   = (const float*)d_in[7];
  const float* w_ih   = (const float*)d_in[8];
  const float* w_hh   = (const float*)d_in[9];
  const float* b_ih   = (const float*)d_in[10];
  const float* b_hh   = (const float*)d_in[11];
  const float* in_w   = (const float*)d_in[12];
  const float* in_b   = (const float*)d_in[13];
  const float* out_w  = (const float*)d_in[14];
  const float* out_b  = (const float*)d_in[15];
  const float* ln1_g  = (const float*)d_in[16];
  const float* ln1_b  = (const float*)d_in[17];
  const float* w1     = (const float*)d_in[18];
  const float* b1     = (const float*)d_in[19];
  const float* w2     = (const float*)d_in[20];
  const float* b2     = (const float*)d_in[21];
  const float* ln2_g  = (const float*)d_in[22];
  const float* ln2_b  = (const float*)d_in[23];
  const float* fin_g  = (const float*)d_in[24];
  const float* fin_b  = (const float*)d_in[25];

  float* ws    = (float*)d_ws;
  float* x0    = ws + O_X0;
  float* x1    = ws + O_X1;
  float* ctx   = ws + O_CTX;
  float* qkv   = ws + O_QKV;     // packed u32 pairs
  float* big   = ws + O_BIG;
  float* bsum  = ws + O_BSUM;
  unsigned long long* hpack = (unsigned long long*)(big + 8388608);

  u32*   aconv = (u32*)(ws + O_HSEQ);               // 2,097,152 packed activations
  float* qbias = ws + O_HSEQ + 2097152;             // 1536 scaled qkv bias
  u32*   qkvp  = (u32*)qkv;
  u32*   ctxp  = (u32*)ctx;
  u32*   scp   = (u32*)big;                         // scores as packed pairs
  u32*   wsg   = (u32*)(big + 13000000);            // gates W scratch (1M, clear of hpack)
  u32*   wsa   = (u32*)big;                         // qkv/proj W scratch (at big+0)
  u32*   ws1   = (u32*)(big + 8500000);             // ffn1 W scratch
  u32*   ws2   = (u32*)(big + 9500000);             // ffn2 W scratch

  float* outx  = (float*)d_out;            // [B,S,D]
  float* attn  = outx + (size_t)NT*DD;     // [L,B,S,S]

  hipMemsetAsync(hpack, 0, (size_t)(SS+1)*BB*DD*sizeof(unsigned long long), stream);

  const int eb = (NT*DD)/256;
  k_embed<<<eb, 256, 0, stream>>>(src, emb, x0);
  k_conv <<<eb, 256, 0, stream>>>(x0, conv_w, conv_b, bn_g, bn_b, bn_m, bn_v, x1, aconv);
  k_bsum <<<8, 256, 0, stream>>>(b_ih, b_hh, bsum, 4*DD);

  // LSTM input precompute: gates = x1 @ w_ih^T + (b_ih + b_hh)
  k_wsplit<0><<<1024, 256, 0, stream>>>(w_ih, wsg, nullptr, nullptr, 2048*512, 512);
  k_gemm_mfma<0,0><<<(NT/128)*((4*DD)/128), 256, 0, stream>>>(
      aconv, wsg, bsum, big, NT, 4*DD, DD);
  k_lstm<<<256, 256, 0, stream>>>(big, w_hh, hpack);
  k_resid<<<eb, 256, 0, stream>>>(x1, hpack, aconv);

  float* cur = x1;
  float* tmp = x0;
  for (int l=0; l<LL; ++l){
    // qkv = cur @ in_w[l]^T + in_b[l]  (Q rows pre-scaled 0.125; packed output)
    k_wsplit<1><<<768, 256, 0, stream>>>(in_w + (size_t)l*1536*DD, wsa,
                                         in_b + (size_t)l*1536, qbias, 1536*512, 512);
    k_gemm_mfma<0,1><<<(NT/128)*(1536/128), 256, 0, stream>>>(
        aconv, wsa, qbias, qkvp, NT, 1536, DD);
    for (int bb2=0; bb2<2; ++bb2){
      int bbase = bb2*2;
      k_scores_mfma<<<1024, 256, 0, stream>>>(qkvp, scp, bbase);
      k_softmax    <<<2048, 256, 0, stream>>>(scp, attn, l, bbase);
      k_pv_mfma    <<<256,  256, 0, stream>>>(scp, qkvp, ctxp, bbase);
    }
    // proj: tmp = ctx @ out_w[l]^T + out_b[l]   (A = packed ctx)
    k_wsplit<0><<<256, 256, 0, stream>>>(out_w + (size_t)l*DD*DD, wsa,
                                         nullptr, nullptr, 512*512, 512);
    k_gemm_mfma<0,0><<<(NT/128)*(DD/128), 256, 0, stream>>>(
        ctxp, wsa, out_b + (size_t)l*DD, tmp, NT, DD, DD);
    // ln1 -> cur (f32) + aconv (packed, consumed by ffn1)
    k_ln<<<NT, 64, 0, stream>>>(cur, tmp, ln1_g + l*DD, ln1_b + l*DD, cur, aconv);
    // ffh = gelu(cur @ w1[l]^T + b1[l])  -> packed pairs in big[0..8.39M)
    k_wsplit<0><<<1024, 256, 0, stream>>>(w1 + (size_t)l*DFF*DD, ws1,
                                          nullptr, nullptr, 2048*512, 512);
    k_gemm_mfma<1,1><<<(NT/128)*(DFF/128), 256, 0, stream>>>(
        aconv, ws1, b1 + (size_t)l*DFF, (u32*)big, NT, DFF, DD);
    // tmp = ffh @ w2[l]^T + b2[l]   (A = packed ffh)
    k_wsplit<0><<<1024, 256, 0, stream>>>(w2 + (size_t)l*DD*DFF, ws2,
                                          nullptr, nullptr, 512*2048, 2048);
    k_gemm_mfma<0,0><<<(NT/128)*(DD/128), 256, 0, stream>>>(
        (u32*)big, ws2, b2 + (size_t)l*DD, tmp, NT, DD, DFF);
    // ln2 -> cur (f32) + aconv (packed, consumed by next layer's qkv)
    k_ln<<<NT, 64, 0, stream>>>(cur, tmp, ln2_g + l*DD, ln2_b + l*DD, cur, aconv);
  }
  k_ln<<<NT, 64, 0, stream>>>(cur, nullptr, fin_g, fin_b, outx, nullptr);
}

// Round 11
// 2535.222 us; speedup vs baseline: 1.4602x; 1.0484x over previous
//
#include <hip/hip_runtime.h>
#include <math.h>

#define DD 512
#define SS 1024
#define BB 4
#define HH 8
#define DFF 2048
#define LL 4
#define NT 4096           // BB*SS
#define EPSF 1e-5f

// ---------------- workspace layout (float elements) ----------------
#define O_X0    ((size_t)0)            // 2,097,152  emb+pe / tmp
#define O_X1    ((size_t)2097152)      // 2,097,152  conv out / current x
#define O_HSEQ  ((size_t)4194304)      // 2,099,200: packed activation scratch (+qbias tail)
#define O_CTX   ((size_t)6293504)      // 2,097,152 (ctx, packed pairs)
#define O_QKV   ((size_t)8390656)      // 6,291,456 (packed split-pairs)
#define O_BIG   ((size_t)14682112)     // 16,777,216 (gates / hpack / f16 scores(all 4b) / ffh / W)
#define O_BSUM  ((size_t)31459328)     // 2048

typedef unsigned int  u32;
typedef unsigned short u16;
typedef __attribute__((ext_vector_type(8))) _Float16 f16x8;
typedef __attribute__((ext_vector_type(4))) _Float16 f16x4;
typedef __attribute__((ext_vector_type(4))) float    f32x4;

// fast transcendentals: v_exp_f32 / v_rcp_f32 based (~1e-7 rel, saturating-safe)
__device__ __forceinline__ float fsig(float x){
  return __builtin_amdgcn_rcpf(1.0f + __expf(-x));
}
__device__ __forceinline__ float ftanh(float x){
  return 1.0f - 2.0f*__builtin_amdgcn_rcpf(1.0f + __expf(2.0f*x));
}
union f16u { u16 u; _Float16 f; };
__device__ __forceinline__ float b2f(u16 b){ f16u t; t.u = b; return (float)t.f; }
__device__ __forceinline__ u16 f2b(_Float16 h){ f16u t; t.f = h; return t.u; }
// pack f32 -> {hi f16 (low16) | lo f16 (high16)}
__device__ __forceinline__ u32 pack2(float v){
  _Float16 hi = (_Float16)v;
  _Float16 lo = (_Float16)(v - (float)hi);
  return (u32)f2b(hi) | ((u32)f2b(lo) << 16);
}
__device__ __forceinline__ float unpack2f(u32 w){
  return b2f((u16)w) + b2f((u16)(w >> 16));
}

// ---------------- embedding + sinusoidal PE ----------------
__global__ void k_embed(const int* __restrict__ src, const float* __restrict__ emb,
                        float* __restrict__ x){
  int idx = blockIdx.x*256 + threadIdx.x;
  if (idx >= NT*DD) return;
  int d = idx & (DD-1);
  int n = idx >> 9;          // b*SS + s
  int s = n & (SS-1);
  int tok = src[n];
  int i2 = d & ~1;
  float div = expf(-(float)i2 * (9.210340371976184f/512.0f));  // ln(10000)/512
  float ang = (float)s * div;
  float pe = (d & 1) ? cosf(ang) : sinf(ang);
  x[idx] = emb[(size_t)tok*DD + d]*22.62741699796952f + pe;    // sqrt(512)
}

// ---------------- depthwise conv k=3 + BN(eval) + ReLU (+ packed copy) ----------------
__global__ void k_conv(const float* __restrict__ x, const float* __restrict__ cw,
                       const float* __restrict__ cb, const float* __restrict__ bg,
                       const float* __restrict__ bb, const float* __restrict__ bm,
                       const float* __restrict__ bv, float* __restrict__ y,
                       u32* __restrict__ yp){
  int idx = blockIdx.x*256 + threadIdx.x;
  if (idx >= NT*DD) return;
  int d = idx & (DD-1);
  int n = idx >> 9;
  int s = n & (SS-1);
  float acc = cb[d];
  if (s > 0)     acc += x[idx - DD]*cw[d*3+0];
  acc += x[idx]*cw[d*3+1];
  if (s < SS-1)  acc += x[idx + DD]*cw[d*3+2];
  float v = (acc - bm[d])*rsqrtf(bv[d]+EPSF)*bg[d] + bb[d];
  v = fmaxf(v, 0.0f);
  y[idx] = v;
  yp[idx] = pack2(v);
}

__global__ void k_bsum(const float* a, const float* b, float* o, int n){
  int i = blockIdx.x*256 + threadIdx.x;
  if (i < n) o[i] = a[i] + b[i];
}

// ---------------- weight pre-split: W f32 -> packed {hi|lo} u32 ----------------
// QSCALE: scale rows<512 by 0.125 (attention Q fold) and emit scaled bias copy.
template<int QSCALE>
__global__ void k_wsplit(const float* __restrict__ W, u32* __restrict__ Wp,
                         const float* __restrict__ bias_in, float* __restrict__ bias_out,
                         int total, int K){
  int i = blockIdx.x*1024 + threadIdx.x*4;
  if (i < total){
    float4 v = *reinterpret_cast<const float4*>(W + i);
    float s = 1.0f;
    if (QSCALE){ int row = i / K; if (row < 512) s = 0.125f; }
    uint4 o;
    o.x = pack2(v.x*s); o.y = pack2(v.y*s); o.z = pack2(v.z*s); o.w = pack2(v.w*s);
    *reinterpret_cast<uint4*>(Wp + i) = o;
  }
  if (QSCALE && blockIdx.x == 0){
    for (int j = threadIdx.x; j < 1536; j += 256){
      float bv = bias_in[j];
      bias_out[j] = (j < 512) ? bv*0.125f : bv;
    }
  }
}

// unpack helper for staging: 4 packed elems -> hi u32x2 + lo u32x2 (2 halves each)
__device__ __forceinline__ void unpk4(uint4 w, uint2& hi, uint2& lo){
  hi.x = (w.x & 0xffffu) | (w.y << 16);
  hi.y = (w.z & 0xffffu) | (w.w << 16);
  lo.x = (w.x >> 16) | (w.y & 0xffff0000u);
  lo.y = (w.z >> 16) | (w.w & 0xffff0000u);
}
__device__ __forceinline__ uint2 unpk4hi(uint4 w){
  uint2 hi;
  hi.x = (w.x & 0xffffu) | (w.y << 16);
  hi.y = (w.z & 0xffffu) | (w.w << 16);
  return hi;
}

// ---------------- MFMA split-f16 GEMM: C[M,N] = A[M,K] @ W[N,K]^T + bias ----------------
// A and W pre-split packed pairs. 2-pass MFMA: C = Ah*Wh + Ah*Wl.
// OSPLIT=1: C written as packed split-pairs.
#define BKP 40   // padded K stride in halves
template<int ACT, int OSPLIT>
__global__ __launch_bounds__(256) void k_gemm_mfma(const u32* __restrict__ Ain,
                                                   const u32* __restrict__ Wp,
                                                   const float* __restrict__ bias,
                                                   void* __restrict__ Cout,
                                                   int M, int N, int K){
  __shared__ _Float16 Ah[128][BKP];
  __shared__ _Float16 Wh[128][BKP];
  __shared__ _Float16 Wl[128][BKP];
  const int tid = threadIdx.x;
  const int nbx = N >> 7;
  const int bx = blockIdx.x % nbx;
  const int by = blockIdx.x / nbx;
  const int m0 = by << 7, n0 = bx << 7;
  const int lane = tid & 63;
  const int wid  = tid >> 6;
  const int wr = wid >> 1, wc = wid & 1;
  const int fm = lane & 15, fg = lane >> 4;
  const int r0 = tid >> 3;              // staging row base (row = r0 + 32e)
  const int k4 = (tid & 7) << 2;        // staging k offset within tile
  const u32* Wbase = Wp + (size_t)(n0 + r0)*K + k4;
  const u32* Abase = Ain + (size_t)(m0 + r0)*K + k4;

  f32x4 acc[4][4];
  #pragma unroll
  for (int i=0;i<4;i++)
    #pragma unroll
    for (int j=0;j<4;j++) acc[i][j] = (f32x4){0.0f,0.0f,0.0f,0.0f};

  uint4 rw[4], ra4[4];
  #pragma unroll
  for (int e=0;e<4;e++){
    rw[e]  = *reinterpret_cast<const uint4*>(Wbase + (size_t)(e*32)*K);
    ra4[e] = *reinterpret_cast<const uint4*>(Abase + (size_t)(e*32)*K);
  }

  for (int k0 = 0; k0 < K; k0 += 32){
    #pragma unroll
    for (int e = 0; e < 4; ++e){
      int rr = r0 + e*32;
      uint2 hi, lo;
      unpk4(rw[e], hi, lo);
      *reinterpret_cast<uint2*>(&Wh[rr][k4]) = hi;
      *reinterpret_cast<uint2*>(&Wl[rr][k4]) = lo;
      *reinterpret_cast<uint2*>(&Ah[rr][k4]) = unpk4hi(ra4[e]);
    }
    __syncthreads();
    if (k0 + 32 < K){
      #pragma unroll
      for (int e=0;e<4;e++){
        rw[e]  = *reinterpret_cast<const uint4*>(Wbase + (size_t)(e*32)*K + k0 + 32);
        ra4[e] = *reinterpret_cast<const uint4*>(Abase + (size_t)(e*32)*K + k0 + 32);
      }
    }
    f16x8 a_h[4], w_h[4], w_l[4];
    #pragma unroll
    for (int i=0;i<4;i++){
      int row = wr*64 + i*16 + fm;
      a_h[i] = *reinterpret_cast<const f16x8*>(&Ah[row][fg*8]);
    }
    #pragma unroll
    for (int j=0;j<4;j++){
      int row = wc*64 + j*16 + fm;
      w_h[j] = *reinterpret_cast<const f16x8*>(&Wh[row][fg*8]);
      w_l[j] = *reinterpret_cast<const f16x8*>(&Wl[row][fg*8]);
    }
    #pragma unroll
    for (int i=0;i<4;i++)
      #pragma unroll
      for (int j=0;j<4;j++){
        acc[i][j] = __builtin_amdgcn_mfma_f32_16x16x32_f16(a_h[i], w_h[j], acc[i][j], 0, 0, 0);
        acc[i][j] = __builtin_amdgcn_mfma_f32_16x16x32_f16(a_h[i], w_l[j], acc[i][j], 0, 0, 0);
      }
    __syncthreads();
  }
  #pragma unroll
  for (int i=0;i<4;i++){
    #pragma unroll
    for (int r=0;r<4;r++){
      int row = m0 + wr*64 + i*16 + fg*4 + r;
      #pragma unroll
      for (int j=0;j<4;j++){
        int col = n0 + wc*64 + j*16 + fm;
        float v = acc[i][j][r] + bias[col];
        if (ACT == 1) v = 0.5f*v*(1.0f + erff(v*0.70710678118654752f));  // exact gelu
        if constexpr (OSPLIT) ((u32*)Cout)[(size_t)row*N + col] = pack2(v);
        else                  ((float*)Cout)[(size_t)row*N + col] = v;
      }
    }
  }
}

// ---------------- MFMA attention scores: sc = Qs @ K^T (128x128 tiles) ----------------
// qkv packed pairs (Q pre-scaled 0.125). 2-pass: Qh*Kh + Qh*Kl.
// Output: f16 plane (u16/elem), all 4 batches in one dispatch (2048 blocks).
#define SPAD 72
__global__ __launch_bounds__(256) void k_scores_mfma(const u32* __restrict__ qkv,
                                                     u16* __restrict__ sc){
  __shared__ _Float16 Qh[128][SPAD];
  __shared__ _Float16 Kh[128][SPAD], Kl[128][SPAD];
  const int tid = threadIdx.x;
  const int kt = blockIdx.x & 7;
  const int qt = (blockIdx.x >> 3) & 7;
  const int h  = (blockIdx.x >> 6) & 7;
  const int b  = (blockIdx.x >> 9) & 3;
  const int q0 = qt*128, k0 = kt*128;
  #pragma unroll
  for (int e=0;e<8;e++){
    int lin = e*256 + tid;
    int rr = lin >> 4;
    int c4 = (lin & 15) << 2;
    uint4 qv = *reinterpret_cast<const uint4*>(qkv + (size_t)(b*SS + q0+rr)*1536 + h*64 + c4);
    uint4 kv = *reinterpret_cast<const uint4*>(qkv + (size_t)(b*SS + k0+rr)*1536 + DD + h*64 + c4);
    uint2 hi, lo;
    *reinterpret_cast<uint2*>(&Qh[rr][c4]) = unpk4hi(qv);
    unpk4(kv, hi, lo);
    *reinterpret_cast<uint2*>(&Kh[rr][c4]) = hi;
    *reinterpret_cast<uint2*>(&Kl[rr][c4]) = lo;
  }
  __syncthreads();
  const int lane = tid & 63, wid = tid >> 6;
  const int wr = wid >> 1, wc = wid & 1;
  const int fm = lane & 15, fg = lane >> 4;
  f32x4 acc[4][4];
  #pragma unroll
  for (int i=0;i<4;i++)
    #pragma unroll
    for (int j=0;j<4;j++) acc[i][j] = (f32x4){0.0f,0.0f,0.0f,0.0f};
  #pragma unroll
  for (int ks=0; ks<2; ks++){
    f16x8 ah[4], bh[4], bl[4];
    #pragma unroll
    for (int i=0;i<4;i++){
      int row = wr*64 + i*16 + fm;
      ah[i] = *reinterpret_cast<const f16x8*>(&Qh[row][ks*32 + fg*8]);
    }
    #pragma unroll
    for (int j=0;j<4;j++){
      int row = wc*64 + j*16 + fm;
      bh[j] = *reinterpret_cast<const f16x8*>(&Kh[row][ks*32 + fg*8]);
      bl[j] = *reinterpret_cast<const f16x8*>(&Kl[row][ks*32 + fg*8]);
    }
    #pragma unroll
    for (int i=0;i<4;i++)
      #pragma unroll
      for (int j=0;j<4;j++){
        acc[i][j] = __builtin_amdgcn_mfma_f32_16x16x32_f16(ah[i], bh[j], acc[i][j], 0, 0, 0);
        acc[i][j] = __builtin_amdgcn_mfma_f32_16x16x32_f16(ah[i], bl[j], acc[i][j], 0, 0, 0);
      }
  }
  u16* out = sc + (size_t)(b*HH + h)*SS*SS;
  #pragma unroll
  for (int i=0;i<4;i++){
    #pragma unroll
    for (int r=0;r<4;r++){
      int row = q0 + wr*64 + i*16 + fg*4 + r;
      #pragma unroll
      for (int j=0;j<4;j++){
        int col = k0 + wc*64 + j*16 + fm;
        out[(size_t)row*SS + col] = f2b((_Float16)acc[i][j][r]);
      }
    }
  }
}

// ---------------- MFMA PV: ctx[:, h*64..] = P @ V (64q x 64d tiles, BK=64) ----------------
// P f16 plane; V packed pairs; ctx written as packed pairs. All batches: 512 blocks.
__global__ __launch_bounds__(256) void k_pv_mfma(const u16* __restrict__ sc,
                                                 const u32* __restrict__ qkv,
                                                 u32* __restrict__ ctx){
  __shared__ _Float16 Ph[64][SPAD];
  __shared__ _Float16 Vh[64][SPAD],  Vl[64][SPAD];
  const int tid = threadIdx.x;
  const int qt = blockIdx.x & 15;
  const int h  = (blockIdx.x >> 4) & 7;
  const int b  = (blockIdx.x >> 7) & 3;
  const int q0 = qt*64;
  const u16* Pb = sc + (size_t)(b*HH + h)*SS*SS;
  const int lane = tid & 63, wid = tid >> 6;
  const int wr = wid >> 1, wc = wid & 1;      // wave tile: 32 rows x 32 cols
  const int fm = lane & 15, fg = lane >> 4;
  const int pr0 = tid >> 4;                   // P staging: rows pr0 + 16e (e<4)
  const int pc4 = (tid & 15) << 2;
  const int vd  = tid & 63;                   // V staging: dim
  const int vk0 = tid >> 6;                   // V staging: k = vk0 + 4e
  const u16* Pbase = Pb + (size_t)(q0 + pr0)*SS + pc4;
  const u32* Vbase = qkv + (size_t)(b*SS + vk0)*1536 + 1024 + h*64 + vd;
  f32x4 acc[2][2];
  #pragma unroll
  for (int i=0;i<2;i++){ acc[i][0] = (f32x4){0,0,0,0}; acc[i][1] = (f32x4){0,0,0,0}; }

  uint2 rp[4];
  u32   rv[16];
  #pragma unroll
  for (int e=0;e<4;e++)  rp[e] = *reinterpret_cast<const uint2*>(Pbase + (size_t)(e*16)*SS);
  #pragma unroll
  for (int e=0;e<16;e++) rv[e] = Vbase[(size_t)(e*4)*1536];

  for (int kk0=0; kk0<SS; kk0+=64){
    #pragma unroll
    for (int e=0;e<4;e++){
      int rr = pr0 + e*16;
      *reinterpret_cast<uint2*>(&Ph[rr][pc4]) = rp[e];   // f16 bits verbatim
    }
    #pragma unroll
    for (int e=0;e<16;e++){
      int k = vk0 + e*4;
      u32 w = rv[e];
      f16u thi, tlo; thi.u = (u16)w; tlo.u = (u16)(w >> 16);
      Vh[vd][k] = thi.f;
      Vl[vd][k] = tlo.f;
    }
    __syncthreads();
    if (kk0 + 64 < SS){
      #pragma unroll
      for (int e=0;e<4;e++)
        rp[e] = *reinterpret_cast<const uint2*>(Pbase + (size_t)(e*16)*SS + kk0 + 64);
      #pragma unroll
      for (int e=0;e<16;e++)
        rv[e] = Vbase[(size_t)(kk0 + 64 + e*4)*1536];
    }
    #pragma unroll
    for (int ks=0; ks<2; ks++){
      f16x8 ah[2], bh[2], bl[2];
      #pragma unroll
      for (int i=0;i<2;i++){
        int row = wr*32 + i*16 + fm;
        ah[i] = *reinterpret_cast<const f16x8*>(&Ph[row][ks*32 + fg*8]);
      }
      #pragma unroll
      for (int j=0;j<2;j++){
        int row = wc*32 + j*16 + fm;
        bh[j] = *reinterpret_cast<const f16x8*>(&Vh[row][ks*32 + fg*8]);
        bl[j] = *reinterpret_cast<const f16x8*>(&Vl[row][ks*32 + fg*8]);
      }
      #pragma unroll
      for (int i=0;i<2;i++)
        #pragma unroll
        for (int j=0;j<2;j++){
          acc[i][j] = __builtin_amdgcn_mfma_f32_16x16x32_f16(ah[i], bh[j], acc[i][j], 0, 0, 0);
          acc[i][j] = __builtin_amdgcn_mfma_f32_16x16x32_f16(ah[i], bl[j], acc[i][j], 0, 0, 0);
        }
    }
    __syncthreads();
  }
  #pragma unroll
  for (int i=0;i<2;i++){
    #pragma unroll
    for (int r=0;r<4;r++){
      int row = q0 + wr*32 + i*16 + fg*4 + r;
      #pragma unroll
      for (int j=0;j<2;j++){
        int col = wc*32 + j*16 + fm;
        ctx[(size_t)(b*SS + row)*DD + h*64 + col] = pack2(acc[i][j][r]);
      }
    }
  }
}

// ---------------- persistent LSTM: 256 blocks = 4 batches x 64 chunks(8 dims) ----------------
// R9-verified: packed {tag|h} 64-bit relaxed agent-scope atomics; wave-local gate
// combine; hsh double-buffered (1 barrier/step); cross-step poll prefetch;
// ks-major LDS layout -> 16x ds_read_b128 gemv. FROZEN.
__global__ __launch_bounds__(256) void k_lstm(const float* __restrict__ gates_in,
                                              const float* __restrict__ w_hh,
                                              unsigned long long* __restrict__ hpack){
  __shared__ float hsh[2][8][68];
  const int b = blockIdx.x >> 6;
  const int chunk = blockIdx.x & 63;
  const int d0 = chunk*8;
  const int tid = threadIdx.x;
  const int wave = tid >> 6;
  const int lane = tid & 63;
  const int diw = lane >> 5;          // 0..1 : which of the wave's 2 dims
  const int g   = (lane >> 3) & 3;    // gate (0=i,1=f,2=g,3=o)
  const int ks  = lane & 7;           // k-slice: k = j*8 + ks
  const int dim = wave*2 + diw;       // 0..7 within chunk
  const int src0 = diw*32;            // base lane of this dim's gate group
  float w[64];
  {
    const float* wrow = w_hh + (size_t)(g*DD + d0 + dim)*DD;
    #pragma unroll
    for (int j=0;j<64;j++) w[j] = wrow[j*8 + ks];
  }
  float c = 0.0f;
  const float* gbase = gates_in + (size_t)(b*SS)*(4*DD) + g*DD + d0 + dim;
  unsigned long long p0 = __hip_atomic_load(hpack + (size_t)b*DD + tid,
                                            __ATOMIC_RELAXED, __HIP_MEMORY_SCOPE_AGENT);
  unsigned long long p1 = __hip_atomic_load(hpack + (size_t)b*DD + tid + 256,
                                            __ATOMIC_RELAXED, __HIP_MEMORY_SCOPE_AGENT);
  for (int t=0; t<SS; ++t){
    float gv = 0.0f;
    if (ks == 0) gv = gbase[(size_t)t*(4*DD)];
    const unsigned long long exp_tag = (unsigned long long)t;
    unsigned long long* hp = hpack + (size_t)(t*BB + b)*DD;
    while ((p0 >> 32) != exp_tag || (p1 >> 32) != exp_tag){
      if ((p0 >> 32) != exp_tag)
        p0 = __hip_atomic_load(hp + tid,       __ATOMIC_RELAXED, __HIP_MEMORY_SCOPE_AGENT);
      if ((p1 >> 32) != exp_tag)
        p1 = __hip_atomic_load(hp + tid + 256, __ATOMIC_RELAXED, __HIP_MEMORY_SCOPE_AGENT);
    }
    float (*hs)[68] = hsh[t & 1];
    union { unsigned int u; float f; } u0, u1;
    u0.u = (unsigned int)p0;
    u1.u = (unsigned int)p1;
    hs[tid & 7][tid >> 3]        = u0.f;   // dim = tid
    hs[tid & 7][(tid >> 3) + 32] = u1.f;   // dim = tid + 256
    __syncthreads();
    if (t + 1 < SS){   // cross-step poll prefetch (latency hides under compute)
      unsigned long long* hq = hpack + (size_t)((t+1)*BB + b)*DD;
      p0 = __hip_atomic_load(hq + tid,       __ATOMIC_RELAXED, __HIP_MEMORY_SCOPE_AGENT);
      p1 = __hip_atomic_load(hq + tid + 256, __ATOMIC_RELAXED, __HIP_MEMORY_SCOPE_AGENT);
    }
    float a0=0.0f, a1=0.0f, a2=0.0f, a3=0.0f;
    #pragma unroll
    for (int j=0;j<64;j+=4){
      float4 hv = *reinterpret_cast<const float4*>(&hs[ks][j]);
      a0 += w[j+0]*hv.x;
      a1 += w[j+1]*hv.y;
      a2 += w[j+2]*hv.z;
      a3 += w[j+3]*hv.w;
    }
    float acc = (a0+a1)+(a2+a3);
    acc += __shfl_down(acc, 4, 8);
    acc += __shfl_down(acc, 2, 8);
    acc += __shfl_down(acc, 1, 8);
    float v = acc + gv;
    float gval = (g == 2) ? ftanh(v) : fsig(v);
    float gi = __shfl(gval, src0 + 0);
    float gf = __shfl(gval, src0 + 8);
    float gg = __shfl(gval, src0 + 16);
    float go = __shfl(gval, src0 + 24);
    c = gf*c + gi*gg;
    float h = go*ftanh(c);
    if (lane == src0){
      union { float f; unsigned int u; } hu; hu.f = h;
      unsigned long long pk = ((unsigned long long)(unsigned int)(t+1) << 32)
                            | (unsigned long long)hu.u;
      __hip_atomic_store(&hpack[(size_t)((t+1)*BB + b)*DD + d0 + dim], pk,
                         __ATOMIC_RELAXED, __HIP_MEMORY_SCOPE_AGENT);
    }
  }
}

__global__ void k_resid(float* __restrict__ x, const unsigned long long* __restrict__ hpack,
                        u32* __restrict__ xp){
  int idx = blockIdx.x*256 + threadIdx.x;
  if (idx >= NT*DD) return;
  int d = idx & (DD-1);
  int n = idx >> 9;
  int s = n & (SS-1);
  int b = n >> 10;
  union { unsigned int u; float f; } hu;
  hu.u = (unsigned int)hpack[(size_t)((s+1)*BB + b)*DD + d];
  float v = x[idx] + hu.f;
  x[idx] = v;
  xp[idx] = pack2(v);
}

// softmax: reads f16 scores, writes P f16 in-place + head-average to d_out.
// All 4 batches: 4096 blocks. 4 waves x 2 heads, 1 barrier.
__global__ __launch_bounds__(256) void k_softmax(u16* __restrict__ sc,
                                                 float* __restrict__ attn_out,
                                                 int l){
  __shared__ float avgw[4][SS];   // per-wave partial head sums (16 KB)
  const int tid = threadIdx.x;
  const int q  = blockIdx.x & (SS-1);
  const int b  = blockIdx.x >> 10;
  const int wave = tid >> 6, lane = tid & 63;
  #pragma unroll
  for (int j=0;j<16;j++) avgw[wave][j*64 + lane] = 0.0f;
  #pragma unroll
  for (int hi=0; hi<2; hi++){
    int h = wave + hi*4;
    u16* row = sc + (size_t)(b*HH + h)*SS*SS + (size_t)q*SS;
    float v[16];
    float m = -1e30f;
    #pragma unroll
    for (int j=0;j<16;j++){ v[j] = b2f(row[j*64 + lane]); m = fmaxf(m, v[j]); }
    #pragma unroll
    for (int o=32;o>0;o>>=1) m = fmaxf(m, __shfl_xor(m, o));
    float s = 0.0f;
    #pragma unroll
    for (int j=0;j<16;j++){ v[j] = __expf(v[j] - m); s += v[j]; }
    #pragma unroll
    for (int o=32;o>0;o>>=1) s += __shfl_xor(s, o);
    float inv = __builtin_amdgcn_rcpf(s);
    #pragma unroll
    for (int j=0;j<16;j++){
      float p = v[j]*inv;
      row[j*64 + lane] = f2b((_Float16)p);
      avgw[wave][j*64 + lane] += p;
    }
  }
  __syncthreads();
  float* ao = attn_out + (size_t)((l*BB + b)*SS + q)*SS;
  for (int j=tid;j<SS;j+=256)
    ao[j] = (avgw[0][j]+avgw[1][j]+avgw[2][j]+avgw[3][j])*0.125f;
}

// ---------------- LayerNorm: out = LN(x (+ y)) * g + b  (+ optional packed copy) ----------------
__global__ __launch_bounds__(64) void k_ln(const float* __restrict__ x,
                                           const float* __restrict__ y,
                                           const float* __restrict__ g,
                                           const float* __restrict__ bta,
                                           float* __restrict__ out,
                                           u32* __restrict__ outp){
  const int n = blockIdx.x;
  const int tid = threadIdx.x;
  float v[8];
  float s = 0.0f, sq = 0.0f;
  #pragma unroll
  for (int j=0;j<8;j++){
    int d = j*64 + tid;
    float a = x[(size_t)n*DD + d];
    if (y) a += y[(size_t)n*DD + d];
    v[j] = a; s += a; sq += a*a;
  }
  #pragma unroll
  for (int o=32;o>0;o>>=1){ s += __shfl_xor(s, o); sq += __shfl_xor(sq, o); }
  float mean = s*(1.0f/DD);
  float var = sq*(1.0f/DD) - mean*mean;
  float rstd = rsqrtf(var + EPSF);
  #pragma unroll
  for (int j=0;j<8;j++){
    int d = j*64 + tid;
    float r = (v[j]-mean)*rstd*g[d] + bta[d];
    out[(size_t)n*DD + d] = r;
    if (outp) outp[(size_t)n*DD + d] = pack2(r);
  }
}

extern "C" void kernel_launch(void* const* d_in, const int* in_sizes, int n_in,
                              void* d_out, int out_size, void* d_ws, size_t ws_size,
                              hipStream_t stream){
  const int*   src    = (const int*)  d_in[0];
  const float* emb    = (const float*)d_in[1];
  const float* conv_w = (const float*)d_in[2];
  const float* conv_b = (const float*)d_in[3];
  const float* bn_g   = (const float*)d_in[4];
  const float* bn_b   = (const float*)d_in[5];
  const float* bn_m   = (const float*)d_in[6];
  const float* bn_v   = (const float*)d_in[7];
  const float* w_ih   = (const float*)d_in[8];
  const float* w_hh   = (const float*)d_in[9];
  const float* b_ih   = (const float*)d_in[10];
  const float* b_hh   = (const float*)d_in[11];
  const float* in_w   = (const float*)d_in[12];
  const float* in_b   = (const float*)d_in[13];
  const float* out_w  = (const float*)d_in[14];
  const float* out_b  = (const float*)d_in[15];
  const float* ln1_g  = (const float*)d_in[16];
  const float* ln1_b  = (const float*)d_in[17];
  const float* w1     = (const float*)d_in[18];
  const float* b1     = (const float*)d_in[19];
  const float* w2     = (const float*)d_in[20];
  const float* b2     = (const float*)d_in[21];
  const float* ln2_g  = (const float*)d_in[22];
  const float* ln2_b  = (const float*)d_in[23];
  const float* fin_g  = (const float*)d_in[24];
  const float* fin_b  = (const float*)d_in[25];

  float* ws    = (float*)d_ws;
  float* x0    = ws + O_X0;
  float* x1    = ws + O_X1;
  float* ctx   = ws + O_CTX;
  float* qkv   = ws + O_QKV;     // packed u32 pairs
  float* big   = ws + O_BIG;
  float* bsum  = ws + O_BSUM;
  unsigned long long* hpack = (unsigned long long*)(big + 8388608);

  u32*   aconv = (u32*)(ws + O_HSEQ);               // 2,097,152 packed activations
  float* qbias = ws + O_HSEQ + 2097152;             // 1536 scaled qkv bias
  u32*   qkvp  = (u32*)qkv;
  u32*   ctxp  = (u32*)ctx;
  u16*   sc16  = (u16*)big;                         // f16 scores/P: 32 planes, 67 MB
  u32*   wsg   = (u32*)(big + 13000000);            // gates W scratch (clear of hpack)
  u32*   wsa   = (u32*)big;                         // qkv/proj W scratch (at big+0)
  u32*   ws1   = (u32*)(big + 8500000);             // ffn1 W scratch
  u32*   ws2   = (u32*)(big + 9500000);             // ffn2 W scratch

  float* outx  = (float*)d_out;            // [B,S,D]
  float* attn  = outx + (size_t)NT*DD;     // [L,B,S,S]

  hipMemsetAsync(hpack, 0, (size_t)(SS+1)*BB*DD*sizeof(unsigned long long), stream);

  const int eb = (NT*DD)/256;
  k_embed<<<eb, 256, 0, stream>>>(src, emb, x0);
  k_conv <<<eb, 256, 0, stream>>>(x0, conv_w, conv_b, bn_g, bn_b, bn_m, bn_v, x1, aconv);
  k_bsum <<<8, 256, 0, stream>>>(b_ih, b_hh, bsum, 4*DD);

  // LSTM input precompute: gates = x1 @ w_ih^T + (b_ih + b_hh)
  k_wsplit<0><<<1024, 256, 0, stream>>>(w_ih, wsg, nullptr, nullptr, 2048*512, 512);
  k_gemm_mfma<0,0><<<(NT/128)*((4*DD)/128), 256, 0, stream>>>(
      aconv, wsg, bsum, big, NT, 4*DD, DD);
  k_lstm<<<256, 256, 0, stream>>>(big, w_hh, hpack);
  k_resid<<<eb, 256, 0, stream>>>(x1, hpack, aconv);

  float* cur = x1;
  float* tmp = x0;
  for (int l=0; l<LL; ++l){
    // qkv = cur @ in_w[l]^T + in_b[l]  (Q rows pre-scaled 0.125; packed output)
    k_wsplit<1><<<768, 256, 0, stream>>>(in_w + (size_t)l*1536*DD, wsa,
                                         in_b + (size_t)l*1536, qbias, 1536*512, 512);
    k_gemm_mfma<0,1><<<(NT/128)*(1536/128), 256, 0, stream>>>(
        aconv, wsa, qbias, qkvp, NT, 1536, DD);
    // attention, all 4 batches per dispatch
    k_scores_mfma<<<2048, 256, 0, stream>>>(qkvp, sc16);
    k_softmax    <<<4096, 256, 0, stream>>>(sc16, attn, l);
    k_pv_mfma    <<<512,  256, 0, stream>>>(sc16, qkvp, ctxp);
    // proj: tmp = ctx @ out_w[l]^T + out_b[l]   (A = packed ctx)
    k_wsplit<0><<<256, 256, 0, stream>>>(out_w + (size_t)l*DD*DD, wsa,
                                         nullptr, nullptr, 512*512, 512);
    k_gemm_mfma<0,0><<<(NT/128)*(DD/128), 256, 0, stream>>>(
        ctxp, wsa, out_b + (size_t)l*DD, tmp, NT, DD, DD);
    // ln1 -> cur (f32) + aconv (packed, consumed by ffn1)
    k_ln<<<NT, 64, 0, stream>>>(cur, tmp, ln1_g + l*DD, ln1_b + l*DD, cur, aconv);
    // ffh = gelu(cur @ w1[l]^T + b1[l])  -> packed pairs in big[0..8.39M)
    k_wsplit<0><<<1024, 256, 0, stream>>>(w1 + (size_t)l*DFF*DD, ws1,
                                          nullptr, nullptr, 2048*512, 512);
    k_gemm_mfma<1,1><<<(NT/128)*(DFF/128), 256, 0, stream>>>(
        aconv, ws1, b1 + (size_t)l*DFF, (u32*)big, NT, DFF, DD);
    // tmp = ffh @ w2[l]^T + b2[l]   (A = packed ffh)
    k_wsplit<0><<<1024, 256, 0, stream>>>(w2 + (size_t)l*DD*DFF, ws2,
                                          nullptr, nullptr, 512*2048, 2048);
    k_gemm_mfma<0,0><<<(NT/128)*(DD/128), 256, 0, stream>>>(
        (u32*)big, ws2, b2 + (size_t)l*DD, tmp, NT, DD, DFF);
    // ln2 -> cur (f32) + aconv (packed, consumed by next layer's qkv)
    k_ln<<<NT, 64, 0, stream>>>(cur, tmp, ln2_g + l*DD, ln2_b + l*DD, cur, aconv);
  }
  k_ln<<<NT, 64, 0, stream>>>(cur, nullptr, fin_g, fin_b, outx, nullptr);
}

// Round 13
// 2481.512 us; speedup vs baseline: 1.4918x; 1.0216x over previous
//
#include <hip/hip_runtime.h>
#include <math.h>

#define DD 512
#define SS 1024
#define BB 4
#define HH 8
#define DFF 2048
#define LL 4
#define NT 4096           // BB*SS
#define EPSF 1e-5f

// ---------------- workspace layout (float elements) ----------------
#define O_X0    ((size_t)0)            // 2,097,152  emb+pe / tmp
#define O_X1    ((size_t)2097152)      // 2,097,152  conv out / current x
#define O_HSEQ  ((size_t)4194304)      // 2,099,200: packed activation scratch (+qbias tail)
#define O_CTX   ((size_t)6293504)      // 2,097,152 (ctx, packed pairs)
#define O_QKV   ((size_t)8390656)      // 6,291,456 (packed split-pairs)
#define O_BIG   ((size_t)14682112)     // 16,777,216 (gates / f16 scores SPAN WHOLE REGION / ffh / W)
#define O_BSUM  ((size_t)31459328)     // 2048

typedef unsigned int  u32;
typedef unsigned short u16;
typedef __attribute__((ext_vector_type(8))) _Float16 f16x8;
typedef __attribute__((ext_vector_type(4))) _Float16 f16x4;
typedef __attribute__((ext_vector_type(4))) float    f32x4;

// fast transcendentals: v_exp_f32 / v_rcp_f32 based (~1e-7 rel, saturating-safe)
__device__ __forceinline__ float fsig(float x){
  return __builtin_amdgcn_rcpf(1.0f + __expf(-x));
}
__device__ __forceinline__ float ftanh(float x){
  return 1.0f - 2.0f*__builtin_amdgcn_rcpf(1.0f + __expf(2.0f*x));
}
union f16u { u16 u; _Float16 f; };
__device__ __forceinline__ float b2f(u16 b){ f16u t; t.u = b; return (float)t.f; }
__device__ __forceinline__ u16 f2b(_Float16 h){ f16u t; t.f = h; return t.u; }
// pack f32 -> {hi f16 (low16) | lo f16 (high16)}
__device__ __forceinline__ u32 pack2(float v){
  _Float16 hi = (_Float16)v;
  _Float16 lo = (_Float16)(v - (float)hi);
  return (u32)f2b(hi) | ((u32)f2b(lo) << 16);
}

// ---------------- embedding + sinusoidal PE ----------------
__global__ void k_embed(const int* __restrict__ src, const float* __restrict__ emb,
                        float* __restrict__ x){
  int idx = blockIdx.x*256 + threadIdx.x;
  if (idx >= NT*DD) return;
  int d = idx & (DD-1);
  int n = idx >> 9;          // b*SS + s
  int s = n & (SS-1);
  int tok = src[n];
  int i2 = d & ~1;
  float div = expf(-(float)i2 * (9.210340371976184f/512.0f));  // ln(10000)/512
  float ang = (float)s * div;
  float pe = (d & 1) ? cosf(ang) : sinf(ang);
  x[idx] = emb[(size_t)tok*DD + d]*22.62741699796952f + pe;    // sqrt(512)
}

// ---------------- depthwise conv k=3 + BN(eval) + ReLU (+ packed copy) ----------------
__global__ void k_conv(const float* __restrict__ x, const float* __restrict__ cw,
                       const float* __restrict__ cb, const float* __restrict__ bg,
                       const float* __restrict__ bb, const float* __restrict__ bm,
                       const float* __restrict__ bv, float* __restrict__ y,
                       u32* __restrict__ yp){
  int idx = blockIdx.x*256 + threadIdx.x;
  if (idx >= NT*DD) return;
  int d = idx & (DD-1);
  int n = idx >> 9;
  int s = n & (SS-1);
  float acc = cb[d];
  if (s > 0)     acc += x[idx - DD]*cw[d*3+0];
  acc += x[idx]*cw[d*3+1];
  if (s < SS-1)  acc += x[idx + DD]*cw[d*3+2];
  float v = (acc - bm[d])*rsqrtf(bv[d]+EPSF)*bg[d] + bb[d];
  v = fmaxf(v, 0.0f);
  y[idx] = v;
  yp[idx] = pack2(v);
}

__global__ void k_bsum(const float* a, const float* b, float* o, int n){
  int i = blockIdx.x*256 + threadIdx.x;
  if (i < n) o[i] = a[i] + b[i];
}

// ---------------- weight pre-split: W f32 -> packed {hi|lo} u32 ----------------
__global__ void k_wsplit(const float* __restrict__ W, u32* __restrict__ Wp, int total){
  int i = blockIdx.x*1024 + threadIdx.x*4;
  if (i >= total) return;
  float4 v = *reinterpret_cast<const float4*>(W + i);
  uint4 o;
  o.x = pack2(v.x); o.y = pack2(v.y); o.z = pack2(v.z); o.w = pack2(v.w);
  *reinterpret_cast<uint4*>(Wp + i) = o;
}

// qkv weight split (rows<512 scaled 0.125) + scaled bias. 786,432 u32 -> 768 blocks.
// MUST be consumed by the qkv GEMM before k_scores (scores clobber all of big).
__global__ void k_wsplit_qkv(const float* __restrict__ inw, const float* __restrict__ inb,
                             u32* __restrict__ Wq, float* __restrict__ qbias){
  size_t i = (size_t)blockIdx.x*1024 + threadIdx.x*4;
  float s = (i < 262144) ? 0.125f : 1.0f;
  float4 v = *reinterpret_cast<const float4*>(inw + i);
  uint4 o;
  o.x = pack2(v.x*s); o.y = pack2(v.y*s); o.z = pack2(v.z*s); o.w = pack2(v.w*s);
  *reinterpret_cast<uint4*>(Wq + i) = o;
  if (blockIdx.x == 0){
    for (int j = threadIdx.x; j < 1536; j += 256){
      float bv = inb[j];
      qbias[j] = (j < 512) ? bv*0.125f : bv;
    }
  }
}

// post-attention fused split: out_w 262,144 | w1 1,048,576 | w2 1,048,576 -> 2304 blocks.
// Launched AFTER k_pv (scores/P dead), scratches live over the dead score region.
__global__ void k_wsplit_post(const float* __restrict__ outw, const float* __restrict__ w1,
                              const float* __restrict__ w2,
                              u32* __restrict__ Wo, u32* __restrict__ W1p,
                              u32* __restrict__ W2p){
  size_t i = (size_t)blockIdx.x*1024 + threadIdx.x*4;
  const float* src; u32* dst; size_t off;
  if (i < 262144){ src = outw; dst = Wo; off = i; }
  else if (i < 1310720){ src = w1; dst = W1p; off = i - 262144; }
  else { src = w2; dst = W2p; off = i - 1310720; }
  float4 v = *reinterpret_cast<const float4*>(src + off);
  uint4 o;
  o.x = pack2(v.x); o.y = pack2(v.y); o.z = pack2(v.z); o.w = pack2(v.w);
  *reinterpret_cast<uint4*>(dst + off) = o;
}

// unpack helper for staging: 4 packed elems -> hi u32x2 + lo u32x2 (2 halves each)
__device__ __forceinline__ void unpk4(uint4 w, uint2& hi, uint2& lo){
  hi.x = (w.x & 0xffffu) | (w.y << 16);
  hi.y = (w.z & 0xffffu) | (w.w << 16);
  lo.x = (w.x >> 16) | (w.y & 0xffff0000u);
  lo.y = (w.z >> 16) | (w.w & 0xffff0000u);
}
__device__ __forceinline__ uint2 unpk4hi(uint4 w){
  uint2 hi;
  hi.x = (w.x & 0xffffu) | (w.y << 16);
  hi.y = (w.z & 0xffffu) | (w.w << 16);
  return hi;
}

// ---------------- MFMA split-f16 GEMM (128x128): C = A @ W^T + bias ----------------
// A and W pre-split packed pairs. 2-pass MFMA: C = Ah*Wh + Ah*Wl.
#define BKP 40   // padded K stride in halves
template<int ACT, int OSPLIT>
__global__ __launch_bounds__(256) void k_gemm_mfma(const u32* __restrict__ Ain,
                                                   const u32* __restrict__ Wp,
                                                   const float* __restrict__ bias,
                                                   void* __restrict__ Cout,
                                                   int M, int N, int K){
  __shared__ _Float16 Ah[128][BKP];
  __shared__ _Float16 Wh[128][BKP];
  __shared__ _Float16 Wl[128][BKP];
  const int tid = threadIdx.x;
  const int nbx = N >> 7;
  const int bx = blockIdx.x % nbx;
  const int by = blockIdx.x / nbx;
  const int m0 = by << 7, n0 = bx << 7;
  const int lane = tid & 63;
  const int wid  = tid >> 6;
  const int wr = wid >> 1, wc = wid & 1;
  const int fm = lane & 15, fg = lane >> 4;
  const int r0 = tid >> 3;              // staging row base (row = r0 + 32e)
  const int k4 = (tid & 7) << 2;        // staging k offset within tile
  const u32* Wbase = Wp + (size_t)(n0 + r0)*K + k4;
  const u32* Abase = Ain + (size_t)(m0 + r0)*K + k4;

  f32x4 acc[4][4];
  #pragma unroll
  for (int i=0;i<4;i++)
    #pragma unroll
    for (int j=0;j<4;j++) acc[i][j] = (f32x4){0.0f,0.0f,0.0f,0.0f};

  uint4 rw[4], ra4[4];
  #pragma unroll
  for (int e=0;e<4;e++){
    rw[e]  = *reinterpret_cast<const uint4*>(Wbase + (size_t)(e*32)*K);
    ra4[e] = *reinterpret_cast<const uint4*>(Abase + (size_t)(e*32)*K);
  }

  for (int k0 = 0; k0 < K; k0 += 32){
    #pragma unroll
    for (int e = 0; e < 4; ++e){
      int rr = r0 + e*32;
      uint2 hi, lo;
      unpk4(rw[e], hi, lo);
      *reinterpret_cast<uint2*>(&Wh[rr][k4]) = hi;
      *reinterpret_cast<uint2*>(&Wl[rr][k4]) = lo;
      *reinterpret_cast<uint2*>(&Ah[rr][k4]) = unpk4hi(ra4[e]);
    }
    __syncthreads();
    if (k0 + 32 < K){
      #pragma unroll
      for (int e=0;e<4;e++){
        rw[e]  = *reinterpret_cast<const uint4*>(Wbase + (size_t)(e*32)*K + k0 + 32);
        ra4[e] = *reinterpret_cast<const uint4*>(Abase + (size_t)(e*32)*K + k0 + 32);
      }
    }
    f16x8 a_h[4], w_h[4], w_l[4];
    #pragma unroll
    for (int i=0;i<4;i++){
      int row = wr*64 + i*16 + fm;
      a_h[i] = *reinterpret_cast<const f16x8*>(&Ah[row][fg*8]);
    }
    #pragma unroll
    for (int j=0;j<4;j++){
      int row = wc*64 + j*16 + fm;
      w_h[j] = *reinterpret_cast<const f16x8*>(&Wh[row][fg*8]);
      w_l[j] = *reinterpret_cast<const f16x8*>(&Wl[row][fg*8]);
    }
    #pragma unroll
    for (int i=0;i<4;i++)
      #pragma unroll
      for (int j=0;j<4;j++){
        acc[i][j] = __builtin_amdgcn_mfma_f32_16x16x32_f16(a_h[i], w_h[j], acc[i][j], 0, 0, 0);
        acc[i][j] = __builtin_amdgcn_mfma_f32_16x16x32_f16(a_h[i], w_l[j], acc[i][j], 0, 0, 0);
      }
    __syncthreads();
  }
  #pragma unroll
  for (int i=0;i<4;i++){
    #pragma unroll
    for (int r=0;r<4;r++){
      int row = m0 + wr*64 + i*16 + fg*4 + r;
      #pragma unroll
      for (int j=0;j<4;j++){
        int col = n0 + wc*64 + j*16 + fm;
        float v = acc[i][j][r] + bias[col];
        if (ACT == 1) v = 0.5f*v*(1.0f + erff(v*0.70710678118654752f));  // exact gelu
        if constexpr (OSPLIT) ((u32*)Cout)[(size_t)row*N + col] = pack2(v);
        else                  ((float*)Cout)[(size_t)row*N + col] = v;
      }
    }
  }
}

// ---------------- MFMA split-f16 GEMM (128x64) for N=512: full-chip grids ----------------
template<int ACT, int OSPLIT>
__global__ __launch_bounds__(256) void k_gemm64_mfma(const u32* __restrict__ Ain,
                                                     const u32* __restrict__ Wp,
                                                     const float* __restrict__ bias,
                                                     void* __restrict__ Cout,
                                                     int M, int N, int K){
  __shared__ _Float16 Ah[128][BKP];
  __shared__ _Float16 Wh[64][BKP];
  __shared__ _Float16 Wl[64][BKP];
  const int tid = threadIdx.x;
  const int nbx = N >> 6;
  const int bx = blockIdx.x % nbx;
  const int by = blockIdx.x / nbx;
  const int m0 = by << 7, n0 = bx << 6;
  const int lane = tid & 63;
  const int wid  = tid >> 6;
  const int wr = wid >> 1, wc = wid & 1;   // wave tile: 64 rows x 32 cols
  const int fm = lane & 15, fg = lane >> 4;
  const int r0 = tid >> 3;
  const int k4 = (tid & 7) << 2;
  const u32* Wbase = Wp + (size_t)(n0 + r0)*K + k4;   // rows r0 + 32e, e<2
  const u32* Abase = Ain + (size_t)(m0 + r0)*K + k4;  // rows r0 + 32e, e<4

  f32x4 acc[4][2];
  #pragma unroll
  for (int i=0;i<4;i++){ acc[i][0] = (f32x4){0,0,0,0}; acc[i][1] = (f32x4){0,0,0,0}; }

  uint4 rw[2], ra4[4];
  #pragma unroll
  for (int e=0;e<2;e++)
    rw[e]  = *reinterpret_cast<const uint4*>(Wbase + (size_t)(e*32)*K);
  #pragma unroll
  for (int e=0;e<4;e++)
    ra4[e] = *reinterpret_cast<const uint4*>(Abase + (size_t)(e*32)*K);

  for (int k0 = 0; k0 < K; k0 += 32){
    #pragma unroll
    for (int e = 0; e < 2; ++e){
      int rr = r0 + e*32;
      uint2 hi, lo;
      unpk4(rw[e], hi, lo);
      *reinterpret_cast<uint2*>(&Wh[rr][k4]) = hi;
      *reinterpret_cast<uint2*>(&Wl[rr][k4]) = lo;
    }
    #pragma unroll
    for (int e = 0; e < 4; ++e){
      int rr = r0 + e*32;
      *reinterpret_cast<uint2*>(&Ah[rr][k4]) = unpk4hi(ra4[e]);
    }
    __syncthreads();
    if (k0 + 32 < K){
      #pragma unroll
      for (int e=0;e<2;e++)
        rw[e]  = *reinterpret_cast<const uint4*>(Wbase + (size_t)(e*32)*K + k0 + 32);
      #pragma unroll
      for (int e=0;e<4;e++)
        ra4[e] = *reinterpret_cast<const uint4*>(Abase + (size_t)(e*32)*K + k0 + 32);
    }
    f16x8 a_h[4], w_h[2], w_l[2];
    #pragma unroll
    for (int i=0;i<4;i++){
      int row = wr*64 + i*16 + fm;
      a_h[i] = *reinterpret_cast<const f16x8*>(&Ah[row][fg*8]);
    }
    #pragma unroll
    for (int j=0;j<2;j++){
      int row = wc*32 + j*16 + fm;
      w_h[j] = *reinterpret_cast<const f16x8*>(&Wh[row][fg*8]);
      w_l[j] = *reinterpret_cast<const f16x8*>(&Wl[row][fg*8]);
    }
    #pragma unroll
    for (int i=0;i<4;i++)
      #pragma unroll
      for (int j=0;j<2;j++){
        acc[i][j] = __builtin_amdgcn_mfma_f32_16x16x32_f16(a_h[i], w_h[j], acc[i][j], 0, 0, 0);
        acc[i][j] = __builtin_amdgcn_mfma_f32_16x16x32_f16(a_h[i], w_l[j], acc[i][j], 0, 0, 0);
      }
    __syncthreads();
  }
  #pragma unroll
  for (int i=0;i<4;i++){
    #pragma unroll
    for (int r=0;r<4;r++){
      int row = m0 + wr*64 + i*16 + fg*4 + r;
      #pragma unroll
      for (int j=0;j<2;j++){
        int col = n0 + wc*32 + j*16 + fm;
        float v = acc[i][j][r] + bias[col];
        if (ACT == 1) v = 0.5f*v*(1.0f + erff(v*0.70710678118654752f));
        if constexpr (OSPLIT) ((u32*)Cout)[(size_t)row*N + col] = pack2(v);
        else                  ((float*)Cout)[(size_t)row*N + col] = v;
      }
    }
  }
}

// ---------------- MFMA attention scores: sc = Qs @ K^T (128x128 tiles) ----------------
// qkv packed pairs (Q pre-scaled 0.125). 2-pass: Qh*Kh + Qh*Kl.
// Output: f16 plane (u16/elem), all 4 batches in one dispatch (2048 blocks).
#define SPAD 72
__global__ __launch_bounds__(256) void k_scores_mfma(const u32* __restrict__ qkv,
                                                     u16* __restrict__ sc){
  __shared__ _Float16 Qh[128][SPAD];
  __shared__ _Float16 Kh[128][SPAD], Kl[128][SPAD];
  const int tid = threadIdx.x;
  const int kt = blockIdx.x & 7;
  const int qt = (blockIdx.x >> 3) & 7;
  const int h  = (blockIdx.x >> 6) & 7;
  const int b  = (blockIdx.x >> 9) & 3;
  const int q0 = qt*128, k0 = kt*128;
  #pragma unroll
  for (int e=0;e<8;e++){
    int lin = e*256 + tid;
    int rr = lin >> 4;
    int c4 = (lin & 15) << 2;
    uint4 qv = *reinterpret_cast<const uint4*>(qkv + (size_t)(b*SS + q0+rr)*1536 + h*64 + c4);
    uint4 kv = *reinterpret_cast<const uint4*>(qkv + (size_t)(b*SS + k0+rr)*1536 + DD + h*64 + c4);
    uint2 hi, lo;
    *reinterpret_cast<uint2*>(&Qh[rr][c4]) = unpk4hi(qv);
    unpk4(kv, hi, lo);
    *reinterpret_cast<uint2*>(&Kh[rr][c4]) = hi;
    *reinterpret_cast<uint2*>(&Kl[rr][c4]) = lo;
  }
  __syncthreads();
  const int lane = tid & 63, wid = tid >> 6;
  const int wr = wid >> 1, wc = wid & 1;
  const int fm = lane & 15, fg = lane >> 4;
  f32x4 acc[4][4];
  #pragma unroll
  for (int i=0;i<4;i++)
    #pragma unroll
    for (int j=0;j<4;j++) acc[i][j] = (f32x4){0.0f,0.0f,0.0f,0.0f};
  #pragma unroll
  for (int ks=0; ks<2; ks++){
    f16x8 ah[4], bh[4], bl[4];
    #pragma unroll
    for (int i=0;i<4;i++){
      int row = wr*64 + i*16 + fm;
      ah[i] = *reinterpret_cast<const f16x8*>(&Qh[row][ks*32 + fg*8]);
    }
    #pragma unroll
    for (int j=0;j<4;j++){
      int row = wc*64 + j*16 + fm;
      bh[j] = *reinterpret_cast<const f16x8*>(&Kh[row][ks*32 + fg*8]);
      bl[j] = *reinterpret_cast<const f16x8*>(&Kl[row][ks*32 + fg*8]);
    }
    #pragma unroll
    for (int i=0;i<4;i++)
      #pragma unroll
      for (int j=0;j<4;j++){
        acc[i][j] = __builtin_amdgcn_mfma_f32_16x16x32_f16(ah[i], bh[j], acc[i][j], 0, 0, 0);
        acc[i][j] = __builtin_amdgcn_mfma_f32_16x16x32_f16(ah[i], bl[j], acc[i][j], 0, 0, 0);
      }
  }
  u16* out = sc + (size_t)(b*HH + h)*SS*SS;
  #pragma unroll
  for (int i=0;i<4;i++){
    #pragma unroll
    for (int r=0;r<4;r++){
      int row = q0 + wr*64 + i*16 + fg*4 + r;
      #pragma unroll
      for (int j=0;j<4;j++){
        int col = k0 + wc*64 + j*16 + fm;
        out[(size_t)row*SS + col] = f2b((_Float16)acc[i][j][r]);
      }
    }
  }
}

// ---------------- MFMA PV: ctx[:, h*64..] = P @ V (64q x 64d tiles, BK=64) ----------------
// P f16 plane; V packed pairs; ctx written as packed pairs. All batches: 512 blocks.
__global__ __launch_bounds__(256) void k_pv_mfma(const u16* __restrict__ sc,
                                                 const u32* __restrict__ qkv,
                                                 u32* __restrict__ ctx){
  __shared__ _Float16 Ph[64][SPAD];
  __shared__ _Float16 Vh[64][SPAD],  Vl[64][SPAD];
  const int tid = threadIdx.x;
  const int qt = blockIdx.x & 15;
  const int h  = (blockIdx.x >> 4) & 7;
  const int b  = (blockIdx.x >> 7) & 3;
  const int q0 = qt*64;
  const u16* Pb = sc + (size_t)(b*HH + h)*SS*SS;
  const int lane = tid & 63, wid = tid >> 6;
  const int wr = wid >> 1, wc = wid & 1;      // wave tile: 32 rows x 32 cols
  const int fm = lane & 15, fg = lane >> 4;
  const int pr0 = tid >> 4;                   // P staging: rows pr0 + 16e (e<4)
  const int pc4 = (tid & 15) << 2;
  const int vd  = tid & 63;                   // V staging: dim
  const int vk0 = tid >> 6;                   // V staging: k = vk0 + 4e
  const u16* Pbase = Pb + (size_t)(q0 + pr0)*SS + pc4;
  const u32* Vbase = qkv + (size_t)(b*SS + vk0)*1536 + 1024 + h*64 + vd;
  f32x4 acc[2][2];
  #pragma unroll
  for (int i=0;i<2;i++){ acc[i][0] = (f32x4){0,0,0,0}; acc[i][1] = (f32x4){0,0,0,0}; }

  uint2 rp[4];
  u32   rv[16];
  #pragma unroll
  for (int e=0;e<4;e++)  rp[e] = *reinterpret_cast<const uint2*>(Pbase + (size_t)(e*16)*SS);
  #pragma unroll
  for (int e=0;e<16;e++) rv[e] = Vbase[(size_t)(e*4)*1536];

  for (int kk0=0; kk0<SS; kk0+=64){
    #pragma unroll
    for (int e=0;e<4;e++){
      int rr = pr0 + e*16;
      *reinterpret_cast<uint2*>(&Ph[rr][pc4]) = rp[e];   // f16 bits verbatim
    }
    #pragma unroll
    for (int e=0;e<16;e++){
      int k = vk0 + e*4;
      u32 w = rv[e];
      f16u thi, tlo; thi.u = (u16)w; tlo.u = (u16)(w >> 16);
      Vh[vd][k] = thi.f;
      Vl[vd][k] = tlo.f;
    }
    __syncthreads();
    if (kk0 + 64 < SS){
      #pragma unroll
      for (int e=0;e<4;e++)
        rp[e] = *reinterpret_cast<const uint2*>(Pbase + (size_t)(e*16)*SS + kk0 + 64);
      #pragma unroll
      for (int e=0;e<16;e++)
        rv[e] = Vbase[(size_t)(kk0 + 64 + e*4)*1536];
    }
    #pragma unroll
    for (int ks=0; ks<2; ks++){
      f16x8 ah[2], bh[2], bl[2];
      #pragma unroll
      for (int i=0;i<2;i++){
        int row = wr*32 + i*16 + fm;
        ah[i] = *reinterpret_cast<const f16x8*>(&Ph[row][ks*32 + fg*8]);
      }
      #pragma unroll
      for (int j=0;j<2;j++){
        int row = wc*32 + j*16 + fm;
        bh[j] = *reinterpret_cast<const f16x8*>(&Vh[row][ks*32 + fg*8]);
        bl[j] = *reinterpret_cast<const f16x8*>(&Vl[row][ks*32 + fg*8]);
      }
      #pragma unroll
      for (int i=0;i<2;i++)
        #pragma unroll
        for (int j=0;j<2;j++){
          acc[i][j] = __builtin_amdgcn_mfma_f32_16x16x32_f16(ah[i], bh[j], acc[i][j], 0, 0, 0);
          acc[i][j] = __builtin_amdgcn_mfma_f32_16x16x32_f16(ah[i], bl[j], acc[i][j], 0, 0, 0);
        }
    }
    __syncthreads();
  }
  #pragma unroll
  for (int i=0;i<2;i++){
    #pragma unroll
    for (int r=0;r<4;r++){
      int row = q0 + wr*32 + i*16 + fg*4 + r;
      #pragma unroll
      for (int j=0;j<2;j++){
        int col = wc*32 + j*16 + fm;
        ctx[(size_t)(b*SS + row)*DD + h*64 + col] = pack2(acc[i][j][r]);
      }
    }
  }
}

// ---------------- persistent LSTM: FROZEN (R9-verified) ----------------
__global__ __launch_bounds__(256) void k_lstm(const float* __restrict__ gates_in,
                                              const float* __restrict__ w_hh,
                                              unsigned long long* __restrict__ hpack){
  __shared__ float hsh[2][8][68];
  const int b = blockIdx.x >> 6;
  const int chunk = blockIdx.x & 63;
  const int d0 = chunk*8;
  const int tid = threadIdx.x;
  const int wave = tid >> 6;
  const int lane = tid & 63;
  const int diw = lane >> 5;
  const int g   = (lane >> 3) & 3;
  const int ks  = lane & 7;
  const int dim = wave*2 + diw;
  const int src0 = diw*32;
  float w[64];
  {
    const float* wrow = w_hh + (size_t)(g*DD + d0 + dim)*DD;
    #pragma unroll
    for (int j=0;j<64;j++) w[j] = wrow[j*8 + ks];
  }
  float c = 0.0f;
  const float* gbase = gates_in + (size_t)(b*SS)*(4*DD) + g*DD + d0 + dim;
  unsigned long long p0 = __hip_atomic_load(hpack + (size_t)b*DD + tid,
                                            __ATOMIC_RELAXED, __HIP_MEMORY_SCOPE_AGENT);
  unsigned long long p1 = __hip_atomic_load(hpack + (size_t)b*DD + tid + 256,
                                            __ATOMIC_RELAXED, __HIP_MEMORY_SCOPE_AGENT);
  for (int t=0; t<SS; ++t){
    float gv = 0.0f;
    if (ks == 0) gv = gbase[(size_t)t*(4*DD)];
    const unsigned long long exp_tag = (unsigned long long)t;
    unsigned long long* hp = hpack + (size_t)(t*BB + b)*DD;
    while ((p0 >> 32) != exp_tag || (p1 >> 32) != exp_tag){
      if ((p0 >> 32) != exp_tag)
        p0 = __hip_atomic_load(hp + tid,       __ATOMIC_RELAXED, __HIP_MEMORY_SCOPE_AGENT);
      if ((p1 >> 32) != exp_tag)
        p1 = __hip_atomic_load(hp + tid + 256, __ATOMIC_RELAXED, __HIP_MEMORY_SCOPE_AGENT);
    }
    float (*hs)[68] = hsh[t & 1];
    union { unsigned int u; float f; } u0, u1;
    u0.u = (unsigned int)p0;
    u1.u = (unsigned int)p1;
    hs[tid & 7][tid >> 3]        = u0.f;
    hs[tid & 7][(tid >> 3) + 32] = u1.f;
    __syncthreads();
    if (t + 1 < SS){
      unsigned long long* hq = hpack + (size_t)((t+1)*BB + b)*DD;
      p0 = __hip_atomic_load(hq + tid,       __ATOMIC_RELAXED, __HIP_MEMORY_SCOPE_AGENT);
      p1 = __hip_atomic_load(hq + tid + 256, __ATOMIC_RELAXED, __HIP_MEMORY_SCOPE_AGENT);
    }
    float a0=0.0f, a1=0.0f, a2=0.0f, a3=0.0f;
    #pragma unroll
    for (int j=0;j<64;j+=4){
      float4 hv = *reinterpret_cast<const float4*>(&hs[ks][j]);
      a0 += w[j+0]*hv.x;
      a1 += w[j+1]*hv.y;
      a2 += w[j+2]*hv.z;
      a3 += w[j+3]*hv.w;
    }
    float acc = (a0+a1)+(a2+a3);
    acc += __shfl_down(acc, 4, 8);
    acc += __shfl_down(acc, 2, 8);
    acc += __shfl_down(acc, 1, 8);
    float v = acc + gv;
    float gval = (g == 2) ? ftanh(v) : fsig(v);
    float gi = __shfl(gval, src0 + 0);
    float gf = __shfl(gval, src0 + 8);
    float gg = __shfl(gval, src0 + 16);
    float go = __shfl(gval, src0 + 24);
    c = gf*c + gi*gg;
    float h = go*ftanh(c);
    if (lane == src0){
      union { float f; unsigned int u; } hu; hu.f = h;
      unsigned long long pk = ((unsigned long long)(unsigned int)(t+1) << 32)
                            | (unsigned long long)hu.u;
      __hip_atomic_store(&hpack[(size_t)((t+1)*BB + b)*DD + d0 + dim], pk,
                         __ATOMIC_RELAXED, __HIP_MEMORY_SCOPE_AGENT);
    }
  }
}

__global__ void k_resid(float* __restrict__ x, const unsigned long long* __restrict__ hpack,
                        u32* __restrict__ xp){
  int idx = blockIdx.x*256 + threadIdx.x;
  if (idx >= NT*DD) return;
  int d = idx & (DD-1);
  int n = idx >> 9;
  int s = n & (SS-1);
  int b = n >> 10;
  union { unsigned int u; float f; } hu;
  hu.u = (unsigned int)hpack[(size_t)((s+1)*BB + b)*DD + d];
  float v = x[idx] + hu.f;
  x[idx] = v;
  xp[idx] = pack2(v);
}

// softmax: reads f16 scores, writes P f16 in-place + head-average to d_out.
// All 4 batches: 4096 blocks. 4 waves x 2 heads, 1 barrier.
__global__ __launch_bounds__(256) void k_softmax(u16* __restrict__ sc,
                                                 float* __restrict__ attn_out,
                                                 int l){
  __shared__ float avgw[4][SS];
  const int tid = threadIdx.x;
  const int q  = blockIdx.x & (SS-1);
  const int b  = blockIdx.x >> 10;
  const int wave = tid >> 6, lane = tid & 63;
  #pragma unroll
  for (int j=0;j<16;j++) avgw[wave][j*64 + lane] = 0.0f;
  #pragma unroll
  for (int hi=0; hi<2; hi++){
    int h = wave + hi*4;
    u16* row = sc + (size_t)(b*HH + h)*SS*SS + (size_t)q*SS;
    float v[16];
    float m = -1e30f;
    #pragma unroll
    for (int j=0;j<16;j++){ v[j] = b2f(row[j*64 + lane]); m = fmaxf(m, v[j]); }
    #pragma unroll
    for (int o=32;o>0;o>>=1) m = fmaxf(m, __shfl_xor(m, o));
    float s = 0.0f;
    #pragma unroll
    for (int j=0;j<16;j++){ v[j] = __expf(v[j] - m); s += v[j]; }
    #pragma unroll
    for (int o=32;o>0;o>>=1) s += __shfl_xor(s, o);
    float inv = __builtin_amdgcn_rcpf(s);
    #pragma unroll
    for (int j=0;j<16;j++){
      float p = v[j]*inv;
      row[j*64 + lane] = f2b((_Float16)p);
      avgw[wave][j*64 + lane] += p;
    }
  }
  __syncthreads();
  float* ao = attn_out + (size_t)((l*BB + b)*SS + q)*SS;
  for (int j=tid;j<SS;j+=256)
    ao[j] = (avgw[0][j]+avgw[1][j]+avgw[2][j]+avgw[3][j])*0.125f;
}

// ---------------- LayerNorm: out = LN(x (+ y)) * g + b  (+ optional packed copy) ----------------
__global__ __launch_bounds__(64) void k_ln(const float* __restrict__ x,
                                           const float* __restrict__ y,
                                           const float* __restrict__ g,
                                           const float* __restrict__ bta,
                                           float* __restrict__ out,
                                           u32* __restrict__ outp){
  const int n = blockIdx.x;
  const int tid = threadIdx.x;
  float v[8];
  float s = 0.0f, sq = 0.0f;
  #pragma unroll
  for (int j=0;j<8;j++){
    int d = j*64 + tid;
    float a = x[(size_t)n*DD + d];
    if (y) a += y[(size_t)n*DD + d];
    v[j] = a; s += a; sq += a*a;
  }
  #pragma unroll
  for (int o=32;o>0;o>>=1){ s += __shfl_xor(s, o); sq += __shfl_xor(sq, o); }
  float mean = s*(1.0f/DD);
  float var = sq*(1.0f/DD) - mean*mean;
  float rstd = rsqrtf(var + EPSF);
  #pragma unroll
  for (int j=0;j<8;j++){
    int d = j*64 + tid;
    float r = (v[j]-mean)*rstd*g[d] + bta[d];
    out[(size_t)n*DD + d] = r;
    if (outp) outp[(size_t)n*DD + d] = pack2(r);
  }
}

extern "C" void kernel_launch(void* const* d_in, const int* in_sizes, int n_in,
                              void* d_out, int out_size, void* d_ws, size_t ws_size,
                              hipStream_t stream){
  const int*   src    = (const int*)  d_in[0];
  const float* emb    = (const float*)d_in[1];
  const float* conv_w = (const float*)d_in[2];
  const float* conv_b = (const float*)d_in[3];
  const float* bn_g   = (const float*)d_in[4];
  const float* bn_b   = (const float*)d_in[5];
  const float* bn_m   = (const float*)d_in[6];
  const float* bn_v   = (const float*)d_in[7];
  const float* w_ih   = (const float*)d_in[8];
  const float* w_hh   = (const float*)d_in[9];
  const float* b_ih   = (const float*)d_in[10];
  const float* b_hh   = (const float*)d_in[11];
  const float* in_w   = (const float*)d_in[12];
  const float* in_b   = (const float*)d_in[13];
  const float* out_w  = (const float*)d_in[14];
  const float* out_b  = (const float*)d_in[15];
  const float* ln1_g  = (const float*)d_in[16];
  const float* ln1_b  = (const float*)d_in[17];
  const float* w1     = (const float*)d_in[18];
  const float* b1     = (const float*)d_in[19];
  const float* w2     = (const float*)d_in[20];
  const float* b2     = (const float*)d_in[21];
  const float* ln2_g  = (const float*)d_in[22];
  const float* ln2_b  = (const float*)d_in[23];
  const float* fin_g  = (const float*)d_in[24];
  const float* fin_b  = (const float*)d_in[25];

  float* ws    = (float*)d_ws;
  float* x0    = ws + O_X0;
  float* x1    = ws + O_X1;
  float* ctx   = ws + O_CTX;
  float* qkv   = ws + O_QKV;
  float* big   = ws + O_BIG;
  float* bsum  = ws + O_BSUM;
  unsigned long long* hpack = (unsigned long long*)(big + 8388608);

  u32*   aconv = (u32*)(ws + O_HSEQ);               // 2,097,152 packed activations
  float* qbias = ws + O_HSEQ + 2097152;             // 1536 scaled qkv bias
  u32*   qkvp  = (u32*)qkv;
  u32*   ctxp  = (u32*)ctx;
  u16*   sc16  = (u16*)big;                         // f16 scores/P: spans ALL of big (64 MB)
  u32*   wsg   = (u32*)(big + 13000000);            // gates W scratch (pre-phase only)
  // Wq: written at layer start (dead hpack region), consumed by qkv GEMM BEFORE scores.
  u32*   Wq    = (u32*)(big + 8388608);             // 786,432
  // Wo/W1p/W2p: written AFTER pv (scores dead), in big[8.39M..10.75M); ffh uses [0..8.39M).
  u32*   Wo    = (u32*)(big + 8388608);             // 262,144
  u32*   W1p   = (u32*)(big + 8650752);             // 1,048,576
  u32*   W2p   = (u32*)(big + 9699328);             // 1,048,576 (ends 10,747,904)

  float* outx  = (float*)d_out;            // [B,S,D]
  float* attn  = outx + (size_t)NT*DD;     // [L,B,S,S]

  hipMemsetAsync(hpack, 0, (size_t)(SS+1)*BB*DD*sizeof(unsigned long long), stream);

  const int eb = (NT*DD)/256;
  k_embed<<<eb, 256, 0, stream>>>(src, emb, x0);
  k_conv <<<eb, 256, 0, stream>>>(x0, conv_w, conv_b, bn_g, bn_b, bn_m, bn_v, x1, aconv);
  k_bsum <<<8, 256, 0, stream>>>(b_ih, b_hh, bsum, 4*DD);

  // LSTM input precompute: gates = x1 @ w_ih^T + (b_ih + b_hh)
  k_wsplit<<<1024, 256, 0, stream>>>(w_ih, wsg, 2048*512);
  k_gemm_mfma<0,0><<<(NT/128)*((4*DD)/128), 256, 0, stream>>>(
      aconv, wsg, bsum, big, NT, 4*DD, DD);
  k_lstm<<<256, 256, 0, stream>>>(big, w_hh, hpack);
  k_resid<<<eb, 256, 0, stream>>>(x1, hpack, aconv);

  float* cur = x1;
  float* tmp = x0;
  for (int l=0; l<LL; ++l){
    // qkv weight split (consumed before scores clobber big)
    k_wsplit_qkv<<<768, 256, 0, stream>>>(in_w + (size_t)l*1536*DD,
                                          in_b + (size_t)l*1536, Wq, qbias);
    // qkv = cur @ in_w[l]^T + in_b[l]  (packed output)
    k_gemm_mfma<0,1><<<(NT/128)*(1536/128), 256, 0, stream>>>(
        aconv, Wq, qbias, qkvp, NT, 1536, DD);
    // attention, all 4 batches per dispatch (scores span the whole big region)
    k_scores_mfma<<<2048, 256, 0, stream>>>(qkvp, sc16);
    k_softmax    <<<4096, 256, 0, stream>>>(sc16, attn, l);
    k_pv_mfma    <<<512,  256, 0, stream>>>(sc16, qkvp, ctxp);
    // post-attention weight split (scores/P now dead)
    k_wsplit_post<<<2304, 256, 0, stream>>>(out_w + (size_t)l*DD*DD,
                                            w1 + (size_t)l*DFF*DD,
                                            w2 + (size_t)l*DD*DFF, Wo, W1p, W2p);
    // proj: tmp = ctx @ out_w[l]^T + out_b[l]  (full-chip 128x64 tiles)
    k_gemm64_mfma<0,0><<<(NT/128)*(DD/64), 256, 0, stream>>>(
        ctxp, Wo, out_b + (size_t)l*DD, tmp, NT, DD, DD);
    // ln1 -> cur (f32) + aconv (packed, consumed by ffn1)
    k_ln<<<NT, 64, 0, stream>>>(cur, tmp, ln1_g + l*DD, ln1_b + l*DD, cur, aconv);
    // ffh = gelu(cur @ w1[l]^T + b1[l])  -> packed pairs in big[0..8.39M)
    k_gemm_mfma<1,1><<<(NT/128)*(DFF/128), 256, 0, stream>>>(
        aconv, W1p, b1 + (size_t)l*DFF, (u32*)big, NT, DFF, DD);
    // tmp = ffh @ w2[l]^T + b2[l]  (full-chip 128x64 tiles)
    k_gemm64_mfma<0,0><<<(NT/128)*(DD/64), 256, 0, stream>>>(
        (u32*)big, W2p, b2 + (size_t)l*DD, tmp, NT, DD, DFF);
    // ln2 -> cur (f32) + aconv (packed, consumed by next layer's qkv)
    k_ln<<<NT, 64, 0, stream>>>(cur, tmp, ln2_g + l*DD, ln2_b + l*DD, cur, aconv);
  }
  k_ln<<<NT, 64, 0, stream>>>(cur, nullptr, fin_g, fin_b, outx, nullptr);
}